// Round 21
// baseline (278.190 us; speedup 1.0000x reference)
//
#include <hip/hip_runtime.h>
#include <math.h>

#define B_ 2
#define N_ 1000
#define F_ 8
#define T_ 12
#define H_ 64
#define G_ 24      // B*T
#define NF_ 8000   // N*F
#define ER_ 2000
#define EC_ 24000

typedef short bf16x8 __attribute__((ext_vector_type(8)));
typedef short short4v __attribute__((ext_vector_type(4)));
typedef float f32x4 __attribute__((ext_vector_type(4)));
typedef unsigned int uint2v __attribute__((ext_vector_type(2)));
typedef unsigned int uint4v __attribute__((ext_vector_type(4)));
typedef int int2v __attribute__((ext_vector_type(2)));

#define LGKM0 do { asm volatile("s_waitcnt lgkmcnt(0)" ::: "memory"); __builtin_amdgcn_sched_barrier(0); } while(0)

__device__ __forceinline__ float sigf(float x){ return 1.0f/(1.0f+__expf(-x)); }

// f32 -> bf16 (RNE)
__device__ __forceinline__ unsigned short f2b(float f){
    unsigned u = __float_as_uint(f);
    unsigned r = (u + 0x7FFFu + ((u >> 16) & 1u)) >> 16;
    return (unsigned short)r;
}
__device__ __forceinline__ float b2f(unsigned short u){
    return __uint_as_float(((unsigned)u) << 16);
}
// packed 2xf32 -> 2xbf16 in one VALU op (gfx950)
__device__ __forceinline__ unsigned cpk(float lo, float hi){
    unsigned r;
    asm("v_cvt_pk_bf16_f32 %0, %1, %2" : "=v"(r) : "v"(lo), "v"(hi));
    return r;
}

// ---------------------------------------------------------------- merged: mw+histogram (blocks 0..101) + weight prep (blocks 102+)
__global__ __launch_bounds__(256) void k_prephist(
    const int* __restrict__ c_dst, const int* __restrict__ r_dst,
    const float* __restrict__ c_ew, const float* __restrict__ c_lw, const float* __restrict__ c_gate,
    const float* __restrict__ r_ew, const float* __restrict__ r_lw, const float* __restrict__ r_gate,
    float* __restrict__ mw_c, float* __restrict__ mw_r,
    int* __restrict__ cnt_c, int* __restrict__ cnt_r,
    const float* __restrict__ Wqkv, const float* __restrict__ Wo,
    const float* __restrict__ W1,   const float* __restrict__ W2,
    const float* __restrict__ csWlin, const float* __restrict__ rvWlin,
    const float* __restrict__ csWupd, const float* __restrict__ rvWupd,
    const float* __restrict__ fuW1,   const float* __restrict__ fuW2,
    unsigned short* __restrict__ wt)
{
    if (blockIdx.x < 102){
        int i = blockIdx.x*256 + threadIdx.x;
        if (i < EC_){
            float gs = sigf(c_gate[0]);
            mw_c[i] = gs*c_ew[i] + (1.f-gs)*sigf(c_lw[i]);
            atomicAdd(&cnt_c[c_dst[i]], 1);
        } else if (i < EC_+ER_){
            int e = i - EC_;
            float gs = sigf(r_gate[0]);
            mw_r[e] = gs*r_ew[e] + (1.f-gs)*sigf(r_lw[e]);
            atomicAdd(&cnt_r[r_dst[e]], 1);
        }
        return;
    }
    int i = (blockIdx.x-102)*256 + threadIdx.x;
    if      (i < 12288){ int n=i>>6, k=i&63; float v = Wqkv[k*192+n]; if (n < 64) v *= 0.25f; wt[i] = f2b(v); }
    else if (i < 16384){ int z=i-12288; int n=z>>6, k=z&63; wt[i] = f2b(Wo[k*64+n]); }
    else if (i < 32768){ int z=i-16384; int n=z>>6, k=z&63; wt[i] = f2b(W1[k*256+n]); }
    else if (i < 49152){ int z=i-32768; int n=z>>8, k=z&255; wt[i] = f2b(W2[k*64+n]); }
    else if (i < 53248){ int z=i-49152; int n=z>>6, k=z&63; wt[i] = f2b(csWlin[k*64+n]); }
    else if (i < 57344){ int z=i-53248; int n=z>>6, k=z&63; wt[i] = f2b(rvWlin[k*64+n]); }
    else if (i < 65536){ int z=i-57344; int n=z>>7, k=z&127; wt[i] = f2b(csWupd[k*64+n]); }
    else if (i < 73728){ int z=i-65536; int n=z>>7, k=z&127; wt[i] = f2b(rvWupd[k*64+n]); }
    else if (i < 81920){ int z=i-73728; int n=z>>7, k=z&127; wt[i] = f2b(fuW1[k*64+n]); }
    else if (i < 86016){ int z=i-81920; int n=z>>6, k=z&63; wt[i] = f2b(fuW2[k*64+n]); }
}

// ---------------------------------------------------------------- CSR build: exclusive scan (parallel Hillis-Steele)
__global__ __launch_bounds__(256) void k_scan(const int* __restrict__ cnt_c, int* __restrict__ off_c, int* __restrict__ cur_c,
                                              const int* __restrict__ cnt_r, int* __restrict__ off_r, int* __restrict__ cur_r){
    const int n = (blockIdx.x==0) ? NF_ : N_;
    const int* cnt = (blockIdx.x==0) ? cnt_c : cnt_r;
    int* off = (blockIdx.x==0) ? off_c : off_r;
    int* cur = (blockIdx.x==0) ? cur_c : cur_r;
    __shared__ int part[256];
    int tid = threadIdx.x;
    int tpt = (n + 255) / 256;
    int i0 = tid * tpt;
    int s = 0;
    for (int i=0;i<tpt;++i){ int idx=i0+i; if (idx<n) s += cnt[idx]; }
    part[tid] = s;
    __syncthreads();
    #pragma unroll
    for (int d=1; d<256; d<<=1){
        int v = (tid >= d) ? part[tid-d] : 0;
        __syncthreads();
        part[tid] += v;
        __syncthreads();
    }
    int run = part[tid] - s;    // exclusive prefix of this chunk
    for (int i=0;i<tpt;++i){
        int idx = i0+i;
        if (idx < n){ off[idx] = run; cur[idx] = run; run += cnt[idx]; }
    }
    if (tid == 255) off[n] = part[255];
}

// ---------------------------------------------------------------- merged: CSR fill (blocks 0..101) + node linear (blocks 102+)
__global__ __launch_bounds__(256) void k_filllin(
    const int* __restrict__ c_src, const int* __restrict__ c_dst,
    const int* __restrict__ r_src, const int* __restrict__ r_dst,
    const float* __restrict__ mw_c, const float* __restrict__ mw_r,
    int* __restrict__ cur_c, int* __restrict__ cur_r,
    int2v* __restrict__ epack_c, int2v* __restrict__ epack_r,
    const float* __restrict__ x,
    const unsigned short* __restrict__ wTc, const float* __restrict__ bc,
    const unsigned short* __restrict__ wTr, const float* __restrict__ br,
    unsigned short* __restrict__ yc, unsigned short* __restrict__ yr,
    unsigned short* __restrict__ xg, unsigned short* __restrict__ wsb)
{
    __shared__ unsigned short XBs[4][16*72];
    __shared__ unsigned short WST[16*72];     // rows 0..7 valid (block's 8 f-means)
    if (blockIdx.x < 102){
        int i = blockIdx.x*256 + threadIdx.x;
        if (i < EC_){
            int p = atomicAdd(&cur_c[c_dst[i]], 1);
            int2v ep; ep[0] = c_src[i]; ep[1] = __float_as_int(mw_c[i]);
            epack_c[p] = ep;
        } else if (i < EC_+ER_){
            int e = i - EC_;
            int p = atomicAdd(&cur_r[r_dst[e]], 1);
            int2v ep; ep[0] = r_src[e]; ep[1] = __float_as_int(mw_r[e]);
            epack_r[p] = ep;
        }
        return;
    }
    int bid = blockIdx.x - 102;               // 0..2999
    int w = threadIdx.x>>6, l = threadIdx.x&63;
    int lr = l&15, lg = l>>4;
    unsigned short* XB = XBs[w];
    int r0 = (bid*4 + w)*16;
    int g  = r0/NF_;
    int j0 = r0%NF_;
    float fsum0 = 0.f, fsum1 = 0.f;
    #pragma unroll
    for (int i=0;i<16;++i){
        int rr = r0+i;
        int j = j0+i;
        int b = g/T_, t = g%T_, n = j/F_, f = j%F_;
        float v = x[((size_t)((b*N_+n)*F_+f)*T_ + t)*64 + l];
        unsigned short us = f2b(v);
        XB[i*72 + l] = us;
        xg[(size_t)rr*64 + l] = us;
        if (i < 8) fsum0 += v; else fsum1 += v;
    }
    {
        int nb = j0/F_;
        unsigned short u0 = f2b(fsum0*0.125f);
        unsigned short u1 = f2b(fsum1*0.125f);
        WST[(w*2+0)*72 + l] = u0;
        WST[(w*2+1)*72 + l] = u1;
        wsb[((size_t)g*N_ + nb    )*64 + l] = u0;
        wsb[((size_t)g*N_ + nb + 1)*64 + l] = u1;
    }
    __syncthreads();
    // causal GEMM (per wave)
    {
        bf16x8 a0 = *(const bf16x8*)&XB[lr*72 + lg*8];
        bf16x8 a1 = *(const bf16x8*)&XB[lr*72 + 32 + lg*8];
        f32x4 acc[4];
        #pragma unroll
        for (int ct=0;ct<4;++ct) acc[ct] = (f32x4){0.f,0.f,0.f,0.f};
        #pragma unroll
        for (int ct=0;ct<4;++ct){
            bf16x8 b0 = *(const bf16x8*)&wTc[(ct*16+lr)*64 + lg*8];
            bf16x8 b1 = *(const bf16x8*)&wTc[(ct*16+lr)*64 + 32 + lg*8];
            acc[ct] = __builtin_amdgcn_mfma_f32_16x16x32_bf16(a0, b0, acc[ct], 0,0,0);
            acc[ct] = __builtin_amdgcn_mfma_f32_16x16x32_bf16(a1, b1, acc[ct], 0,0,0);
        }
        #pragma unroll
        for (int ct=0;ct<4;++ct){
            float bv = bc[ct*16+lr];
            #pragma unroll
            for (int i=0;i<4;++i)
                yc[(size_t)(r0+lg*4+i)*64 + ct*16+lr] = f2b(acc[ct][i] + bv);
        }
    }
    // river GEMM for the block's 8 n-rows (wave 0)
    if (w == 0){
        int nb0 = ((bid*64)%NF_)/F_;
        int gb  = (bid*64)/NF_;
        bf16x8 a0 = *(const bf16x8*)&WST[lr*72 + lg*8];
        bf16x8 a1 = *(const bf16x8*)&WST[lr*72 + 32 + lg*8];
        f32x4 acc[4];
        #pragma unroll
        for (int ct=0;ct<4;++ct) acc[ct] = (f32x4){0.f,0.f,0.f,0.f};
        #pragma unroll
        for (int ct=0;ct<4;++ct){
            bf16x8 b0 = *(const bf16x8*)&wTr[(ct*16+lr)*64 + lg*8];
            bf16x8 b1 = *(const bf16x8*)&wTr[(ct*16+lr)*64 + 32 + lg*8];
            acc[ct] = __builtin_amdgcn_mfma_f32_16x16x32_bf16(a0, b0, acc[ct], 0,0,0);
            acc[ct] = __builtin_amdgcn_mfma_f32_16x16x32_bf16(a1, b1, acc[ct], 0,0,0);
        }
        if (lg < 2){
            #pragma unroll
            for (int ct=0;ct<4;++ct){
                float bv = br[ct*16+lr];
                #pragma unroll
                for (int i=0;i<4;++i)
                    yr[((size_t)gb*N_ + nb0 + lg*4+i)*64 + ct*16+lr] = f2b(acc[ct][i] + bv);
            }
        }
    }
}

// ---------------------------------------------------------------- merged gather-aggregate (bf16), packed edges,
// 2 rows/wave with INTERLEAVED edge chains (4 loads in flight)
__global__ __launch_bounds__(256) void k_gaggr2(const unsigned short* __restrict__ yc,
                                                const int2v* __restrict__ epack_c,
                                                const int* __restrict__ off_c,
                                                unsigned short* __restrict__ ac,
                                                const unsigned short* __restrict__ yr,
                                                const int2v* __restrict__ epack_r,
                                                const int* __restrict__ off_r,
                                                unsigned short* __restrict__ ar){
    int l = threadIdx.x & 63;
    int w = threadIdx.x >> 6;
    const unsigned short* y; const int2v* epack; const int* off;
    unsigned short* aggr; int nseg, base;
    if (blockIdx.x < 24000){
        int wg = (blockIdx.x & 7)*3000 + (blockIdx.x >> 3);   // XCD-chunked swizzle (24000 % 8 == 0)
        y = yc; epack = epack_c; off = off_c; aggr = ac; nseg = NF_;
        base = wg*8 + w*2;
    } else {
        int pb = blockIdx.x - 24000;
        int wg = (pb & 7)*375 + (pb >> 3);                    // 3000 % 8 == 0
        y = yr; epack = epack_r; off = off_r; aggr = ar; nseg = N_;
        base = wg*8 + w*2;
    }
    int idx0 = base, idx1 = base + 1;
    int g0 = idx0 / nseg, d0 = idx0 % nseg;
    int g1 = idx1 / nseg, d1 = idx1 % nseg;
    int p0 = off[d0], e0 = off[d0+1];
    int p1 = off[d1], e1 = off[d1+1];
    const unsigned short* yg0 = y + (size_t)g0*nseg*64 + l;
    const unsigned short* yg1 = y + (size_t)g1*nseg*64 + l;
    float acc0 = 0.f, acc1 = 0.f;
    // interleaved phase: both rows advance 2 edges/iter (4 loads in flight)
    while (p0+1 < e0 && p1+1 < e1){
        int2v ea0 = epack[p0], eb0 = epack[p0+1];
        int2v ea1 = epack[p1], eb1 = epack[p1+1];
        float va0 = b2f(yg0[(size_t)ea0[0]*64]);
        float vb0 = b2f(yg0[(size_t)eb0[0]*64]);
        float va1 = b2f(yg1[(size_t)ea1[0]*64]);
        float vb1 = b2f(yg1[(size_t)eb1[0]*64]);
        acc0 += __int_as_float(ea0[1])*va0 + __int_as_float(eb0[1])*vb0;
        acc1 += __int_as_float(ea1[1])*va1 + __int_as_float(eb1[1])*vb1;
        p0 += 2; p1 += 2;
    }
    // row-0 tail
    for (; p0+1 < e0; p0 += 2){
        int2v ea = epack[p0], eb = epack[p0+1];
        float va = b2f(yg0[(size_t)ea[0]*64]);
        float vb = b2f(yg0[(size_t)eb[0]*64]);
        acc0 += __int_as_float(ea[1])*va + __int_as_float(eb[1])*vb;
    }
    if (p0 < e0){
        int2v ea = epack[p0];
        acc0 += __int_as_float(ea[1]) * b2f(yg0[(size_t)ea[0]*64]);
    }
    // row-1 tail
    for (; p1+1 < e1; p1 += 2){
        int2v ea = epack[p1], eb = epack[p1+1];
        float va = b2f(yg1[(size_t)ea[0]*64]);
        float vb = b2f(yg1[(size_t)eb[0]*64]);
        acc1 += __int_as_float(ea[1])*va + __int_as_float(eb[1])*vb;
    }
    if (p1 < e1){
        int2v ea = epack[p1];
        acc1 += __int_as_float(ea[1]) * b2f(yg1[(size_t)ea[0]*64]);
    }
    aggr[(size_t)idx0*64 + l] = f2b(acc0);
    aggr[(size_t)idx1*64 + l] = f2b(acc1);
}

// ---------------------------------------------------------------- fused river-update + causal-update + fusion MLP, 2 tiles/wave
// Each wave's 32 causal rows = exactly 4 consecutive n of one graph -> compute those 4 river-u rows inline
// (zero redundancy across waves), then stage-2 reads river-u directly from the per-wave UR tile.
__global__ __launch_bounds__(256) void k_updfus(const unsigned short* __restrict__ aggr,
                                                const unsigned short* __restrict__ xg,
                                                const unsigned short* __restrict__ wuT,  // csWupd [64][128]
                                                const float* __restrict__ bu,
                                                const unsigned short* __restrict__ raggr, // river aggr
                                                const unsigned short* __restrict__ wsb,   // ws mean bf16
                                                const unsigned short* __restrict__ rwT,   // rvWupd [64][128]
                                                const float* __restrict__ rbu,
                                                const unsigned short* __restrict__ w1T,  // [64][128]
                                                const float* __restrict__ b1,
                                                const unsigned short* __restrict__ w2T,  // [64][64]
                                                const float* __restrict__ b2,
                                                unsigned short* __restrict__ fused){
    __shared__ unsigned short XBs[4][2][16*136];
    __shared__ unsigned short X2s[4][2][16*136];
    __shared__ unsigned short RAs[4][4*136 + 8];   // river A-tile: 4 rows x [aggr|ws]
    __shared__ unsigned short URs[4][4*72 + 8];    // river u rows (4 x 64)
    int w = threadIdx.x>>6, l = threadIdx.x&63;
    int lr = l&15, lg = l>>4;
    int lq = l>>4, lc = (l&15)*4;
    unsigned short* XB[2] = { XBs[w][0], XBs[w][1] };
    unsigned short* X2[2] = { X2s[w][0], X2s[w][1] };
    unsigned short* RA = RAs[w];
    unsigned short* UR = URs[w];
    int tb = (blockIdx.x*4 + w)*32;      // 32 rows per wave, 32 | 8000 -> no g straddle
    int g  = tb/NF_;
    int n0 = (tb%NF_)/F_;                // wave owns n0..n0+3
    // stage causal tiles (aggr | xg)
    #pragma unroll
    for (int tt=0;tt<2;++tt){
        int r0 = tb + tt*16;
        #pragma unroll
        for (int v=0; v<4; ++v){
            int row = v*4 + lq;
            int rr = r0 + row;
            *(short4v*)&XB[tt][row*136 + lc]      = *(const short4v*)&aggr[(size_t)rr*64 + lc];
            *(short4v*)&XB[tt][row*136 + 64 + lc] = *(const short4v*)&xg[(size_t)rr*64 + lc];
        }
    }
    // stage river tile: 4 rows x [raggr | ws]
    #pragma unroll
    for (int r=0;r<4;++r){
        RA[r*136 + l]      = raggr[((size_t)g*N_ + n0 + r)*64 + l];
        RA[r*136 + 64 + l] = wsb[((size_t)g*N_ + n0 + r)*64 + l];
    }
    LGKM0;
    // river update GEMM: rows 0..3 valid (rows >=4 zeroed A -> outputs discarded)
    {
        const bf16x8 bz = (bf16x8){0,0,0,0,0,0,0,0};
        bf16x8 a[4];
        #pragma unroll
        for (int kk=0;kk<4;++kk){
            a[kk] = bz;
            if (lr < 4) a[kk] = *(const bf16x8*)&RA[lr*136 + kk*32 + lg*8];
        }
        f32x4 acc[4];
        #pragma unroll
        for (int ct=0;ct<4;++ct) acc[ct] = (f32x4){0.f,0.f,0.f,0.f};
        #pragma unroll
        for (int ct=0;ct<4;++ct){
            #pragma unroll
            for (int kk=0;kk<4;++kk){
                bf16x8 b0 = *(const bf16x8*)&rwT[(ct*16+lr)*128 + kk*32 + lg*8];
                acc[ct] = __builtin_amdgcn_mfma_f32_16x16x32_bf16(a[kk], b0, acc[ct], 0,0,0);
            }
        }
        if (lg == 0){
            #pragma unroll
            for (int ct=0;ct<4;++ct){
                float bv = rbu[ct*16+lr];
                #pragma unroll
                for (int i=0;i<4;++i)
                    UR[i*72 + ct*16+lr] = f2b(fmaxf(acc[ct][i] + bv, 0.f));
            }
        }
    }
    // stage 1: causal update GEMM k=128 -> relu -> X2 cols 0..63 (both tiles)
    {
        bf16x8 a[2][4];
        #pragma unroll
        for (int tt=0;tt<2;++tt)
            #pragma unroll
            for (int kk=0;kk<4;++kk) a[tt][kk] = *(const bf16x8*)&XB[tt][lr*136 + kk*32 + lg*8];
        f32x4 acc[2][4];
        #pragma unroll
        for (int tt=0;tt<2;++tt)
            #pragma unroll
            for (int ct=0;ct<4;++ct) acc[tt][ct] = (f32x4){0.f,0.f,0.f,0.f};
        #pragma unroll
        for (int ct=0;ct<4;++ct){
            #pragma unroll
            for (int kk=0;kk<4;++kk){
                bf16x8 b0 = *(const bf16x8*)&wuT[(ct*16+lr)*128 + kk*32 + lg*8];
                #pragma unroll
                for (int tt=0;tt<2;++tt)
                    acc[tt][ct] = __builtin_amdgcn_mfma_f32_16x16x32_bf16(a[tt][kk], b0, acc[tt][ct], 0,0,0);
            }
        }
        #pragma unroll
        for (int ct=0;ct<4;++ct){
            float bv = bu[ct*16+lr];
            #pragma unroll
            for (int tt=0;tt<2;++tt)
                #pragma unroll
                for (int i=0;i<4;++i)
                    X2[tt][(lg*4+i)*136 + ct*16+lr] = f2b(fmaxf(acc[tt][ct][i] + bv, 0.f));
        }
    }
    LGKM0;
    // stage 2: fusion GEMM1 k=128 -> relu -> XB cols 0..63 (both tiles)
    // A-fragments: kk=0,1 from X2 (causal u), kk=2,3 from UR (river u, row tt*2 + (lr>>3))
    {
        bf16x8 a[2][4];
        #pragma unroll
        for (int tt=0;tt<2;++tt){
            a[tt][0] = *(const bf16x8*)&X2[tt][lr*136 + 0*32 + lg*8];
            a[tt][1] = *(const bf16x8*)&X2[tt][lr*136 + 1*32 + lg*8];
            int urow = tt*2 + (lr>>3);
            a[tt][2] = *(const bf16x8*)&UR[urow*72 + 0*32 + lg*8];
            a[tt][3] = *(const bf16x8*)&UR[urow*72 + 1*32 + lg*8];
        }
        f32x4 acc[2][4];
        #pragma unroll
        for (int tt=0;tt<2;++tt)
            #pragma unroll
            for (int ct=0;ct<4;++ct) acc[tt][ct] = (f32x4){0.f,0.f,0.f,0.f};
        #pragma unroll
        for (int ct=0;ct<4;++ct){
            #pragma unroll
            for (int kk=0;kk<4;++kk){
                bf16x8 b0 = *(const bf16x8*)&w1T[(ct*16+lr)*128 + kk*32 + lg*8];
                #pragma unroll
                for (int tt=0;tt<2;++tt)
                    acc[tt][ct] = __builtin_amdgcn_mfma_f32_16x16x32_bf16(a[tt][kk], b0, acc[tt][ct], 0,0,0);
            }
        }
        #pragma unroll
        for (int ct=0;ct<4;++ct){
            float bv = b1[ct*16+lr];
            #pragma unroll
            for (int tt=0;tt<2;++tt)
                #pragma unroll
                for (int i=0;i<4;++i)
                    XB[tt][(lg*4+i)*136 + ct*16+lr] = f2b(fmaxf(acc[tt][ct][i] + bv, 0.f));
        }
    }
    LGKM0;
    // stage 3: fusion GEMM2 k=64 -> fused (both tiles)
    {
        bf16x8 h0[2], h1[2];
        #pragma unroll
        for (int tt=0;tt<2;++tt){
            h0[tt] = *(const bf16x8*)&XB[tt][lr*136 + lg*8];
            h1[tt] = *(const bf16x8*)&XB[tt][lr*136 + 32 + lg*8];
        }
        f32x4 acc[2][4];
        #pragma unroll
        for (int tt=0;tt<2;++tt)
            #pragma unroll
            for (int ct=0;ct<4;++ct) acc[tt][ct] = (f32x4){0.f,0.f,0.f,0.f};
        #pragma unroll
        for (int ct=0;ct<4;++ct){
            bf16x8 b0 = *(const bf16x8*)&w2T[(ct*16+lr)*64 + lg*8];
            bf16x8 b1v= *(const bf16x8*)&w2T[(ct*16+lr)*64 + 32 + lg*8];
            #pragma unroll
            for (int tt=0;tt<2;++tt){
                acc[tt][ct] = __builtin_amdgcn_mfma_f32_16x16x32_bf16(h0[tt], b0, acc[tt][ct], 0,0,0);
                acc[tt][ct] = __builtin_amdgcn_mfma_f32_16x16x32_bf16(h1[tt], b1v, acc[tt][ct], 0,0,0);
            }
        }
        #pragma unroll
        for (int ct=0;ct<4;++ct){
            float bv = b2[ct*16+lr];
            #pragma unroll
            for (int tt=0;tt<2;++tt)
                #pragma unroll
                for (int i=0;i<4;++i)
                    fused[(size_t)(tb + tt*16 + lg*4+i)*64 + ct*16+lr] = f2b(acc[tt][ct][i] + bv);
        }
    }
}

// ---------------------------------------------------------------- MFMA temporal transformer: 4 waves, 2 seqs/wave, 12-row SC
// Vectorized staging + cvt_pk conversions (no setprio — measured neutral/negative).
#define XSTR 72    // XB stride (shorts); LN-out / V^T / O staging (16 rows)
#define SSTR 136   // SC stride (shorts): Q 0-63, K 64-127; 12 rows/seq + tail pad; aliased as HID
#define SCSZ (12*SSTR)

__global__ __launch_bounds__(256) void k_xformer(
    const unsigned short* __restrict__ fused,
    const unsigned short* __restrict__ wtq,   // [192][64], Q-part pre-scaled 0.25
    const unsigned short* __restrict__ wto,   // [64][64]
    const unsigned short* __restrict__ wt1,   // [256][64]
    const unsigned short* __restrict__ wt2,   // [64][256]
    const float* __restrict__ bqkv, const float* __restrict__ bo,
    const float* __restrict__ fb1,  const float* __restrict__ fb2,
    const float* __restrict__ ln1g, const float* __restrict__ ln1b,
    const float* __restrict__ ln2g, const float* __restrict__ ln2b,
    float* __restrict__ out)
{
    __shared__ unsigned short XBs[4][2][16*XSTR];
    __shared__ unsigned short SCmem[8*SCSZ + 544];   // 12-row slices + tail pad for benign row-12..15 reads

    int w  = threadIdx.x >> 6;
    int l  = threadIdx.x & 63;
    int lr = l & 15;
    int lg = l >> 4;

    unsigned short* XBp[2] = { XBs[w][0], XBs[w][1] };
    unsigned short* SCp[2] = { &SCmem[(w*2+0)*SCSZ], &SCmem[(w*2+1)*SCSZ] };

    int gbase = (blockIdx.x*4 + w)*2;

    // ---- stage fused rows into SC (vectorized: 3 x 128B row-loads per seq) ----
    #pragma unroll
    for (int sq=0;sq<2;++sq){
        int gs = gbase + sq;
        int bb = gs / NF_, j = gs % NF_;
        const unsigned short* fp = fused + ((size_t)bb*T_*NF_ + j)*64;
        #pragma unroll
        for (int ps=0; ps<3; ++ps){
            int t = ps*4 + lg;
            *(short4v*)&SCp[sq][t*SSTR + lr*4] = *(const short4v*)&fp[(size_t)t*NF_*64 + lr*4];
        }
    }
    LGKM0;

    // ---- read C-layout fragments from LDS ----
    float res[2][4][4];
    #pragma unroll
    for (int sq=0;sq<2;++sq)
        #pragma unroll
        for (int nt=0;nt<4;++nt)
            #pragma unroll
            for (int i=0;i<4;++i){
                int t = lg*4+i;
                res[sq][nt][i] = (t < 12) ? b2f(SCp[sq][t*SSTR + nt*16 + lr]) : 0.f;
            }

    // LN1 -> XB (both seqs), packed conversions
    #pragma unroll
    for (int sq=0;sq<2;++sq){
        float sm[4], sqr[4];
        #pragma unroll
        for (int i=0;i<4;++i){
            sm[i]  = res[sq][0][i]+res[sq][1][i]+res[sq][2][i]+res[sq][3][i];
            sqr[i] = res[sq][0][i]*res[sq][0][i]+res[sq][1][i]*res[sq][1][i]
                   + res[sq][2][i]*res[sq][2][i]+res[sq][3][i]*res[sq][3][i];
        }
        #pragma unroll
        for (int m=1;m<16;m<<=1){
            #pragma unroll
            for (int i=0;i<4;++i){
                sm[i]  += __shfl_xor(sm[i], m, 64);
                sqr[i] += __shfl_xor(sqr[i], m, 64);
            }
        }
        float mnv[4], rsv[4];
        #pragma unroll
        for (int i=0;i<4;++i){
            mnv[i] = sm[i]*(1.0f/64.0f);
            float var = sqr[i]*(1.0f/64.0f) - mnv[i]*mnv[i];
            rsv[i] = rsqrtf(var + 1e-5f);
        }
        #pragma unroll
        for (int nt=0;nt<4;++nt){
            float gg = ln1g[nt*16+lr], oo = ln1b[nt*16+lr];
            float w0 = (res[sq][nt][0]-mnv[0])*rsv[0]*gg + oo;
            float w1 = (res[sq][nt][1]-mnv[1])*rsv[1]*gg + oo;
            float w2 = (res[sq][nt][2]-mnv[2])*rsv[2]*gg + oo;
            float w3 = (res[sq][nt][3]-mnv[3])*rsv[3]*gg + oo;
            unsigned u01 = cpk(w0,w1), u23 = cpk(w2,w3);
            XBp[sq][(lg*4+0)*XSTR + nt*16 + lr] = (unsigned short)u01;
            XBp[sq][(lg*4+1)*XSTR + nt*16 + lr] = (unsigned short)(u01>>16);
            XBp[sq][(lg*4+2)*XSTR + nt*16 + lr] = (unsigned short)u23;
            XBp[sq][(lg*4+3)*XSTR + nt*16 + lr] = (unsigned short)(u23>>16);
        }
    }
    LGKM0;

    // QKV GEMM: Q,K -> SC (rows<12); V^T -> XB (shared weight frags), packed conversions
    {
        bf16x8 a0[2], a1[2];
        #pragma unroll
        for (int sq=0;sq<2;++sq){
            a0[sq] = *(const bf16x8*)&XBp[sq][lr*XSTR + 0*32 + lg*8];
            a1[sq] = *(const bf16x8*)&XBp[sq][lr*XSTR + 1*32 + lg*8];
        }
        LGKM0;   // a-frags in regs before V overwrites XB
        #pragma unroll
        for (int p=0;p<3;++p){
            f32x4 acc[2][4];
            #pragma unroll
            for (int sq=0;sq<2;++sq)
                #pragma unroll
                for (int c=0;c<4;++c) acc[sq][c] = (f32x4){0.f,0.f,0.f,0.f};
            #pragma unroll
            for (int c=0;c<4;++c){
                int ct = p*4 + c;
                bf16x8 b0 = *(const bf16x8*)&wtq[(ct*16+lr)*64 + 0*32 + lg*8];
                bf16x8 b1v= *(const bf16x8*)&wtq[(ct*16+lr)*64 + 1*32 + lg*8];
                #pragma unroll
                for (int sq=0;sq<2;++sq){
                    acc[sq][c] = __builtin_amdgcn_mfma_f32_16x16x32_bf16(a0[sq], b0, acc[sq][c], 0,0,0);
                    acc[sq][c] = __builtin_amdgcn_mfma_f32_16x16x32_bf16(a1[sq], b1v, acc[sq][c], 0,0,0);
                }
            }
            if (p < 2){
                if (lg < 3){
                    #pragma unroll
                    for (int c=0;c<4;++c){
                        int ct = p*4 + c;
                        float bv = bqkv[ct*16+lr];
                        if (p == 0) bv *= 0.25f;
                        #pragma unroll
                        for (int sq=0;sq<2;++sq){
                            unsigned u01 = cpk(acc[sq][c][0]+bv, acc[sq][c][1]+bv);
                            unsigned u23 = cpk(acc[sq][c][2]+bv, acc[sq][c][3]+bv);
                            SCp[sq][(lg*4+0)*SSTR + p*64 + c*16 + lr] = (unsigned short)u01;
                            SCp[sq][(lg*4+1)*SSTR + p*64 + c*16 + lr] = (unsigned short)(u01>>16);
                            SCp[sq][(lg*4+2)*SSTR + p*64 + c*16 + lr] = (unsigned short)u23;
                            SCp[sq][(lg*4+3)*SSTR + p*64 + c*16 + lr] = (unsigned short)(u23>>16);
                        }
                    }
                }
            } else {
                #pragma unroll
                for (int c=0;c<4;++c){
                    float bv = bqkv[128 + c*16 + lr];
                    #pragma unroll
                    for (int sq=0;sq<2;++sq){
                        uint2v vv2;
                        vv2[0] = cpk(acc[sq][c][0]+bv, acc[sq][c][1]+bv);
                        vv2[1] = cpk(acc[sq][c][2]+bv, acc[sq][c][3]+bv);
                        *(uint2v*)&XBp[sq][lr*XSTR + c*16 + lg*4] = vv2;   // VT'[d=c*16+lr][t=lg*4..+3]
                    }
                }
            }
        }
    }
    LGKM0;

    // MFMA attention per head, both seqs (packed P and O conversions)
    {
        const bf16x8 bz = (bf16x8){0,0,0,0,0,0,0,0};
        #pragma unroll
        for (int hd=0; hd<4; ++hd){
            #pragma unroll
            for (int sq=0;sq<2;++sq){
                bf16x8 ak = bz, bq = bz;
                if (lg < 2){
                    ak = *(const bf16x8*)&SCp[sq][lr*SSTR + 64 + hd*16 + lg*8];
                    bq = *(const bf16x8*)&SCp[sq][lr*SSTR +      hd*16 + lg*8];
                }
                f32x4 st = __builtin_amdgcn_mfma_f32_16x16x32_bf16(ak, bq, (f32x4){0.f,0.f,0.f,0.f}, 0,0,0);
                float s0=st[0], s1v=st[1], s2=st[2], s3=st[3];
                if (lg == 3){ s0=s1v=s2=s3=-1e30f; }
                float mx = fmaxf(fmaxf(s0,s1v), fmaxf(s2,s3));
                mx = fmaxf(mx, __shfl_xor(mx, 16, 64));
                mx = fmaxf(mx, __shfl_xor(mx, 32, 64));
                float p0 = __expf(s0-mx), p1 = __expf(s1v-mx), p2 = __expf(s2-mx), p3 = __expf(s3-mx);
                float den = p0+p1+p2+p3;
                den += __shfl_xor(den, 16, 64);
                den += __shfl_xor(den, 32, 64);
                float inv = __builtin_amdgcn_rcpf(den);
                float q0 = __shfl_down(p0, 16, 64), q1 = __shfl_down(p1, 16, 64);
                float q2 = __shfl_down(p2, 16, 64), q3 = __shfl_down(p3, 16, 64);
                union { uint4v u; bf16x8 b; } pu;
                {
                    float lo0 = (lg==0)? p0 : (lg==1)? q0 : 0.f;
                    float lo1 = (lg==0)? p1 : (lg==1)? q1 : 0.f;
                    float lo2 = (lg==0)? p2 : (lg==1)? q2 : 0.f;
                    float lo3 = (lg==0)? p3 : (lg==1)? q3 : 0.f;
                    float hi0 = (lg==0)? q0 : 0.f;
                    float hi1 = (lg==0)? q1 : 0.f;
                    float hi2 = (lg==0)? q2 : 0.f;
                    float hi3 = (lg==0)? q3 : 0.f;
                    pu.u[0] = cpk(lo0, lo1);
                    pu.u[1] = cpk(lo2, lo3);
                    pu.u[2] = cpk(hi0, hi1);
                    pu.u[3] = cpk(hi2, hi3);
                }
                bf16x8 pb = pu.b;
                bf16x8 av = bz;
                if (lg < 2) av = *(const bf16x8*)&XBp[sq][lr*XSTR + hd*16 + lg*8];
                f32x4 ot = __builtin_amdgcn_mfma_f32_16x16x32_bf16(av, pb, (f32x4){0.f,0.f,0.f,0.f}, 0,0,0);
                uint2v ow2;
                ow2[0] = cpk(ot[0]*inv, ot[1]*inv);
                ow2[1] = cpk(ot[2]*inv, ot[3]*inv);
                *(uint2v*)&XBp[sq][lr*XSTR + hd*16 + lg*4] = ow2;
            }
        }
    }
    LGKM0;

    // proj + residual -> s1 (shared weight frags)
    float s1[2][4][4];
    {
        bf16x8 a0[2], a1[2];
        #pragma unroll
        for (int sq=0;sq<2;++sq){
            a0[sq] = *(const bf16x8*)&XBp[sq][lr*XSTR + 0*32 + lg*8];
            a1[sq] = *(const bf16x8*)&XBp[sq][lr*XSTR + 1*32 + lg*8];
        }
        f32x4 pacc[2][4];
        #pragma unroll
        for (int sq=0;sq<2;++sq)
            #pragma unroll
            for (int ct=0;ct<4;++ct) pacc[sq][ct] = (f32x4){0.f,0.f,0.f,0.f};
        #pragma unroll
        for (int ct=0;ct<4;++ct){
            bf16x8 b0 = *(const bf16x8*)&wto[(ct*16+lr)*64 + 0*32 + lg*8];
            bf16x8 b1v= *(const bf16x8*)&wto[(ct*16+lr)*64 + 1*32 + lg*8];
            #pragma unroll
            for (int sq=0;sq<2;++sq){
                pacc[sq][ct] = __builtin_amdgcn_mfma_f32_16x16x32_bf16(a0[sq], b0, pacc[sq][ct], 0,0,0);
                pacc[sq][ct] = __builtin_amdgcn_mfma_f32_16x16x32_bf16(a1[sq], b1v, pacc[sq][ct], 0,0,0);
            }
        }
        #pragma unroll
        for (int sq=0;sq<2;++sq)
            #pragma unroll
            for (int ct=0;ct<4;++ct){
                float bv = bo[ct*16+lr];
                #pragma unroll
                for (int i=0;i<4;++i)
                    s1[sq][ct][i] = res[sq][ct][i] + pacc[sq][ct][i] + bv;
            }
    }

    // LN2 -> XB (both seqs), packed conversions
    #pragma unroll
    for (int sq=0;sq<2;++sq){
        float sm[4], sqr[4];
        #pragma unroll
        for (int i=0;i<4;++i){
            sm[i]  = s1[sq][0][i]+s1[sq][1][i]+s1[sq][2][i]+s1[sq][3][i];
            sqr[i] = s1[sq][0][i]*s1[sq][0][i]+s1[sq][1][i]*s1[sq][1][i]
                   + s1[sq][2][i]*s1[sq][2][i]+s1[sq][3][i]*s1[sq][3][i];
        }
        #pragma unroll
        for (int m=1;m<16;m<<=1){
            #pragma unroll
            for (int i=0;i<4;++i){
                sm[i]  += __shfl_xor(sm[i], m, 64);
                sqr[i] += __shfl_xor(sqr[i], m, 64);
            }
        }
        float mnv[4], rsv[4];
        #pragma unroll
        for (int i=0;i<4;++i){
            mnv[i] = sm[i]*(1.0f/64.0f);
            float var = sqr[i]*(1.0f/64.0f) - mnv[i]*mnv[i];
            rsv[i] = rsqrtf(var + 1e-5f);
        }
        #pragma unroll
        for (int nt=0;nt<4;++nt){
            float gg = ln2g[nt*16+lr], oo = ln2b[nt*16+lr];
            float w0 = (s1[sq][nt][0]-mnv[0])*rsv[0]*gg + oo;
            float w1 = (s1[sq][nt][1]-mnv[1])*rsv[1]*gg + oo;
            float w2 = (s1[sq][nt][2]-mnv[2])*rsv[2]*gg + oo;
            float w3 = (s1[sq][nt][3]-mnv[3])*rsv[3]*gg + oo;
            unsigned u01 = cpk(w0,w1), u23 = cpk(w2,w3);
            XBp[sq][(lg*4+0)*XSTR + nt*16 + lr] = (unsigned short)u01;
            XBp[sq][(lg*4+1)*XSTR + nt*16 + lr] = (unsigned short)(u01>>16);
            XBp[sq][(lg*4+2)*XSTR + nt*16 + lr] = (unsigned short)u23;
            XBp[sq][(lg*4+3)*XSTR + nt*16 + lr] = (unsigned short)(u23>>16);
        }
    }
    LGKM0;

    // FFN: two 128-wide halves; HID stores guarded rows<12; packed conversions
    f32x4 oacc[2][4];
    #pragma unroll
    for (int sq=0;sq<2;++sq)
        #pragma unroll
        for (int ct=0;ct<4;++ct) oacc[sq][ct] = (f32x4){0.f,0.f,0.f,0.f};
    {
        bf16x8 a0[2], a1[2];
        #pragma unroll
        for (int sq=0;sq<2;++sq){
            a0[sq] = *(const bf16x8*)&XBp[sq][lr*XSTR + 0*32 + lg*8];
            a1[sq] = *(const bf16x8*)&XBp[sq][lr*XSTR + 1*32 + lg*8];
        }
        #pragma unroll
        for (int half=0; half<2; ++half){
            LGKM0;   // HID region reuse guard
            #pragma unroll
            for (int q=0; q<2; ++q){
                f32x4 facc[2][4];
                #pragma unroll
                for (int sq=0;sq<2;++sq)
                    #pragma unroll
                    for (int c=0;c<4;++c) facc[sq][c] = (f32x4){0.f,0.f,0.f,0.f};
                #pragma unroll
                for (int c=0;c<4;++c){
                    int ct = half*8 + q*4 + c;
                    bf16x8 b0 = *(const bf16x8*)&wt1[(ct*16+lr)*64 + 0*32 + lg*8];
                    bf16x8 b1v= *(const bf16x8*)&wt1[(ct*16+lr)*64 + 1*32 + lg*8];
                    #pragma unroll
                    for (int sq=0;sq<2;++sq){
                        facc[sq][c] = __builtin_amdgcn_mfma_f32_16x16x32_bf16(a0[sq], b0, facc[sq][c], 0,0,0);
                        facc[sq][c] = __builtin_amdgcn_mfma_f32_16x16x32_bf16(a1[sq], b1v, facc[sq][c], 0,0,0);
                    }
                }
                if (lg < 3){
                    #pragma unroll
                    for (int c=0;c<4;++c){
                        int ct = half*8 + q*4 + c;
                        float bv = fb1[ct*16+lr];
                        #pragma unroll
                        for (int sq=0;sq<2;++sq){
                            float hv[4];
                            #pragma unroll
                            for (int i=0;i<4;++i){
                                float xv = facc[sq][c][i] + bv;
                                float x2 = xv*xv;
                                float z  = xv*(1.5957691216f + 0.0713548162f*x2);
                                float ez = __expf(-z);
                                hv[i] = xv * __builtin_amdgcn_rcpf(1.0f + ez);
                            }
                            unsigned u01 = cpk(hv[0],hv[1]), u23 = cpk(hv[2],hv[3]);
                            SCp[sq][(lg*4+0)*SSTR + (q*4+c)*16 + lr] = (unsigned short)u01;
                            SCp[sq][(lg*4+1)*SSTR + (q*4+c)*16 + lr] = (unsigned short)(u01>>16);
                            SCp[sq][(lg*4+2)*SSTR + (q*4+c)*16 + lr] = (unsigned short)u23;
                            SCp[sq][(lg*4+3)*SSTR + (q*4+c)*16 + lr] = (unsigned short)(u23>>16);
                        }
                    }
                }
            }
            LGKM0;
            #pragma unroll
            for (int ks=0;ks<4;++ks){
                bf16x8 af[2];
                #pragma unroll
                for (int sq=0;sq<2;++sq)
                    af[sq] = *(const bf16x8*)&SCp[sq][lr*SSTR + ks*32 + lg*8];
                #pragma unroll
                for (int ct=0;ct<4;++ct){
                    bf16x8 bfr = *(const bf16x8*)&wt2[(ct*16+lr)*256 + half*128 + ks*32 + lg*8];
                    #pragma unroll
                    for (int sq=0;sq<2;++sq)
                        oacc[sq][ct] = __builtin_amdgcn_mfma_f32_16x16x32_bf16(af[sq], bfr, oacc[sq][ct], 0,0,0);
                }
            }
        }
    }

    // residual + mean over t (both seqs)
    #pragma unroll
    for (int sq=0;sq<2;++sq)
        #pragma unroll
        for (int ct=0;ct<4;++ct){
            float bv = fb2[ct*16+lr];
            float part = 0.f;
            #pragma unroll
            for (int i=0;i<4;++i){
                if (lg*4+i < 12) part += s1[sq][ct][i] + oacc[sq][ct][i] + bv;
            }
            part += __shfl_xor(part, 16, 64);
            part += __shfl_xor(part, 32, 64);
            if (lg == 0) out[(size_t)(gbase+sq)*64 + ct*16 + lr] = part*(1.0f/12.0f);
        }
}

// ----------------------------------------------------------------
extern "C" void kernel_launch(void* const* d_in, const int* in_sizes, int n_in,
                              void* d_out, int out_size, void* d_ws, size_t ws_size,
                              hipStream_t stream) {
    const float* x      = (const float*)d_in[0];
    const int*   r_ei   = (const int*)  d_in[1];
    const float* r_ea   = (const float*)d_in[2];
    const int*   c_ei   = (const int*)  d_in[3];
    const float* c_ew   = (const float*)d_in[4];
    const float* rvWlin = (const float*)d_in[5];
    const float* rvblin = (const float*)d_in[6];
    const float* rvWupd = (const float*)d_in[7];
    const float* rvbupd = (const float*)d_in[8];
    const float* rvgate = (const float*)d_in[9];
    const float* rvlw   = (const float*)d_in[10];
    const float* csWlin = (const float*)d_in[11];
    const float* csblin = (const float*)d_in[12];
    const float* csWupd = (const float*)d_in[13];
    const float* csbupd = (const float*)d_in[14];
    const float* csgate = (const float*)d_in[15];
    const float* cslw   = (const float*)d_in[16];
    const float* fuW1   = (const float*)d_in[17];
    const float* fub1   = (const float*)d_in[18];
    const float* fuW2   = (const float*)d_in[19];
    const float* fub2   = (const float*)d_in[20];
    const float* ln1g   = (const float*)d_in[21];
    const float* ln1b   = (const float*)d_in[22];
    const float* ln2g   = (const float*)d_in[23];
    const float* ln2b   = (const float*)d_in[24];
    const float* Wqkv   = (const float*)d_in[25];
    const float* bqkv   = (const float*)d_in[26];
    const float* Wo     = (const float*)d_in[27];
    const float* bo     = (const float*)d_in[28];
    const float* ffW1   = (const float*)d_in[29];
    const float* ffb1   = (const float*)d_in[30];
    const float* ffW2   = (const float*)d_in[31];
    const float* ffb2   = (const float*)d_in[32];

    float* wsp  = (float*)d_ws;
    unsigned short* FNY_b = (unsigned short*)wsp;                    // causal y bf16, then FUSED bf16
    unsigned short* FNA_b = (unsigned short*)(wsp + 12288000);       // causal aggr bf16
    unsigned short* XG_b  = (unsigned short*)(wsp + 12288000 + 6144000); // gathered x bf16
    unsigned short* WS_b  = (unsigned short*)(wsp + 24576000);       // watershed mean bf16
    unsigned short* WSY_b = (unsigned short*)(wsp + 26112000);       // river y bf16
    unsigned short* WSA_b = (unsigned short*)(wsp + 27648000);       // river aggr bf16
    float* WSU  = wsp + 29184000;                                    // CSR scratch
    unsigned short* wt = (unsigned short*)(wsp + 30720000);
    float* outp = (float*)d_out;

    int* ibase  = (int*)WSU;
    int* cnt_c  = ibase;
    int* cnt_r  = ibase + 8000;
    int* off_c  = ibase + 9000;
    int* off_r  = ibase + 17001;
    int* cur_c  = ibase + 18002;
    int* cur_r  = ibase + 26002;
    float* mw_c = (float*)(ibase + 53002);
    float* mw_r = (float*)(ibase + 77002);
    int2v* epack_c = (int2v*)(ibase + 80000);   // 24000 x 8B
    int2v* epack_r = (int2v*)(ibase + 128000);  //  2000 x 8B

    const int* c_src = c_ei;
    const int* c_dst = c_ei + EC_;
    const int* r_src = r_ei;
    const int* r_dst = r_ei + ER_;

    hipMemsetAsync(cnt_c, 0, 9000*sizeof(int), stream);

    // merged: mw+histogram (102 blocks) + bf16 weight panels (336 blocks)
    k_prephist<<<438, 256, 0, stream>>>(c_dst, r_dst, c_ew, cslw, csgate,
                                        r_ea, rvlw, rvgate, mw_c, mw_r, cnt_c, cnt_r,
                                        Wqkv, Wo, ffW1, ffW2, csWlin, rvWlin, csWupd, rvWupd,
                                        fuW1, fuW2, wt);
    k_scan<<<2, 256, 0, stream>>>(cnt_c, off_c, cur_c, cnt_r, off_r, cur_r);

    // merged: CSR fill (102 blocks) + node linear (3000 blocks)
    k_filllin<<<3102, 256, 0, stream>>>(c_src, c_dst, r_src, r_dst, mw_c, mw_r,
                                        cur_c, cur_r, epack_c, epack_r,
                                        x, wt+49152, csblin, wt+53248, rvblin,
                                        FNY_b, WSY_b, XG_b, WS_b);

    // merged gather-aggregation (packed edges, interleaved 2-row chains, no atomics)
    k_gaggr2<<<27000, 256, 0, stream>>>(FNY_b, epack_c, off_c, FNA_b,
                                        WSY_b, epack_r, off_r, WSA_b);

    // fused river-update + causal-update + fusion MLP -> FUSED bf16 (into FNY region)
    k_updfus<<<1500, 256, 0, stream>>>(FNA_b, XG_b, wt+57344, csbupd,
                                       WSA_b, WS_b, wt+65536, rvbupd,
                                       wt+73728, fub1, wt+81920, fub2, FNY_b);

    // 2-seq-per-wave MFMA transformer (cvt_pk, no setprio)
    k_xformer<<<2000, 256, 0, stream>>>(FNY_b,
                                        wt, wt+12288, wt+16384, wt+32768,
                                        bqkv, bo, ffb1, ffb2,
                                        ln1g, ln1b, ln2g, ln2b,
                                        outp);
}

// Round 22
// 275.584 us; speedup vs baseline: 1.0095x; 1.0095x over previous
//
#include <hip/hip_runtime.h>
#include <math.h>

#define B_ 2
#define N_ 1000
#define F_ 8
#define T_ 12
#define H_ 64
#define G_ 24      // B*T
#define NF_ 8000   // N*F
#define ER_ 2000
#define EC_ 24000

typedef short bf16x8 __attribute__((ext_vector_type(8)));
typedef short short4v __attribute__((ext_vector_type(4)));
typedef float f32x4 __attribute__((ext_vector_type(4)));
typedef unsigned int uint2v __attribute__((ext_vector_type(2)));
typedef unsigned int uint4v __attribute__((ext_vector_type(4)));
typedef int int2v __attribute__((ext_vector_type(2)));

#define LGKM0 do { asm volatile("s_waitcnt lgkmcnt(0)" ::: "memory"); __builtin_amdgcn_sched_barrier(0); } while(0)

__device__ __forceinline__ float sigf(float x){ return 1.0f/(1.0f+__expf(-x)); }

// f32 -> bf16 (RNE)
__device__ __forceinline__ unsigned short f2b(float f){
    unsigned u = __float_as_uint(f);
    unsigned r = (u + 0x7FFFu + ((u >> 16) & 1u)) >> 16;
    return (unsigned short)r;
}
__device__ __forceinline__ float b2f(unsigned short u){
    return __uint_as_float(((unsigned)u) << 16);
}
// packed 2xf32 -> 2xbf16 in one VALU op (gfx950)
__device__ __forceinline__ unsigned cpk(float lo, float hi){
    unsigned r;
    asm("v_cvt_pk_bf16_f32 %0, %1, %2" : "=v"(r) : "v"(lo), "v"(hi));
    return r;
}

// ---------------------------------------------------------------- merged: mw+histogram (blocks 0..101) + weight prep (blocks 102+)
__global__ __launch_bounds__(256) void k_prephist(
    const int* __restrict__ c_dst, const int* __restrict__ r_dst,
    const float* __restrict__ c_ew, const float* __restrict__ c_lw, const float* __restrict__ c_gate,
    const float* __restrict__ r_ew, const float* __restrict__ r_lw, const float* __restrict__ r_gate,
    float* __restrict__ mw_c, float* __restrict__ mw_r,
    int* __restrict__ cnt_c, int* __restrict__ cnt_r,
    const float* __restrict__ Wqkv, const float* __restrict__ Wo,
    const float* __restrict__ W1,   const float* __restrict__ W2,
    const float* __restrict__ csWlin, const float* __restrict__ rvWlin,
    const float* __restrict__ csWupd, const float* __restrict__ rvWupd,
    const float* __restrict__ fuW1,   const float* __restrict__ fuW2,
    unsigned short* __restrict__ wt)
{
    if (blockIdx.x < 102){
        int i = blockIdx.x*256 + threadIdx.x;
        if (i < EC_){
            float gs = sigf(c_gate[0]);
            mw_c[i] = gs*c_ew[i] + (1.f-gs)*sigf(c_lw[i]);
            atomicAdd(&cnt_c[c_dst[i]], 1);
        } else if (i < EC_+ER_){
            int e = i - EC_;
            float gs = sigf(r_gate[0]);
            mw_r[e] = gs*r_ew[e] + (1.f-gs)*sigf(r_lw[e]);
            atomicAdd(&cnt_r[r_dst[e]], 1);
        }
        return;
    }
    int i = (blockIdx.x-102)*256 + threadIdx.x;
    if      (i < 12288){ int n=i>>6, k=i&63; float v = Wqkv[k*192+n]; if (n < 64) v *= 0.25f; wt[i] = f2b(v); }
    else if (i < 16384){ int z=i-12288; int n=z>>6, k=z&63; wt[i] = f2b(Wo[k*64+n]); }
    else if (i < 32768){ int z=i-16384; int n=z>>6, k=z&63; wt[i] = f2b(W1[k*256+n]); }
    else if (i < 49152){ int z=i-32768; int n=z>>8, k=z&255; wt[i] = f2b(W2[k*64+n]); }
    else if (i < 53248){ int z=i-49152; int n=z>>6, k=z&63; wt[i] = f2b(csWlin[k*64+n]); }
    else if (i < 57344){ int z=i-53248; int n=z>>6, k=z&63; wt[i] = f2b(rvWlin[k*64+n]); }
    else if (i < 65536){ int z=i-57344; int n=z>>7, k=z&127; wt[i] = f2b(csWupd[k*64+n]); }
    else if (i < 73728){ int z=i-65536; int n=z>>7, k=z&127; wt[i] = f2b(rvWupd[k*64+n]); }
    else if (i < 81920){ int z=i-73728; int n=z>>7, k=z&127; wt[i] = f2b(fuW1[k*64+n]); }
    else if (i < 86016){ int z=i-81920; int n=z>>6, k=z&63; wt[i] = f2b(fuW2[k*64+n]); }
}

// ---------------------------------------------------------------- CSR build: exclusive scan (parallel Hillis-Steele)
__global__ __launch_bounds__(256) void k_scan(const int* __restrict__ cnt_c, int* __restrict__ off_c, int* __restrict__ cur_c,
                                              const int* __restrict__ cnt_r, int* __restrict__ off_r, int* __restrict__ cur_r){
    const int n = (blockIdx.x==0) ? NF_ : N_;
    const int* cnt = (blockIdx.x==0) ? cnt_c : cnt_r;
    int* off = (blockIdx.x==0) ? off_c : off_r;
    int* cur = (blockIdx.x==0) ? cur_c : cur_r;
    __shared__ int part[256];
    int tid = threadIdx.x;
    int tpt = (n + 255) / 256;
    int i0 = tid * tpt;
    int s = 0;
    for (int i=0;i<tpt;++i){ int idx=i0+i; if (idx<n) s += cnt[idx]; }
    part[tid] = s;
    __syncthreads();
    #pragma unroll
    for (int d=1; d<256; d<<=1){
        int v = (tid >= d) ? part[tid-d] : 0;
        __syncthreads();
        part[tid] += v;
        __syncthreads();
    }
    int run = part[tid] - s;    // exclusive prefix of this chunk
    for (int i=0;i<tpt;++i){
        int idx = i0+i;
        if (idx < n){ off[idx] = run; cur[idx] = run; run += cnt[idx]; }
    }
    if (tid == 255) off[n] = part[255];
}

// ---------------------------------------------------------------- merged: CSR fill (blocks 0..101) + node linear (blocks 102+)
__global__ __launch_bounds__(256) void k_filllin(
    const int* __restrict__ c_src, const int* __restrict__ c_dst,
    const int* __restrict__ r_src, const int* __restrict__ r_dst,
    const float* __restrict__ mw_c, const float* __restrict__ mw_r,
    int* __restrict__ cur_c, int* __restrict__ cur_r,
    int2v* __restrict__ epack_c, int2v* __restrict__ epack_r,
    const float* __restrict__ x,
    const unsigned short* __restrict__ wTc, const float* __restrict__ bc,
    const unsigned short* __restrict__ wTr, const float* __restrict__ br,
    unsigned short* __restrict__ yc, unsigned short* __restrict__ yr,
    unsigned short* __restrict__ xg, unsigned short* __restrict__ wsb)
{
    __shared__ unsigned short XBs[4][16*72];
    __shared__ unsigned short WST[16*72];     // rows 0..7 valid (block's 8 f-means)
    if (blockIdx.x < 102){
        int i = blockIdx.x*256 + threadIdx.x;
        if (i < EC_){
            int p = atomicAdd(&cur_c[c_dst[i]], 1);
            int2v ep; ep[0] = c_src[i]; ep[1] = __float_as_int(mw_c[i]);
            epack_c[p] = ep;
        } else if (i < EC_+ER_){
            int e = i - EC_;
            int p = atomicAdd(&cur_r[r_dst[e]], 1);
            int2v ep; ep[0] = r_src[e]; ep[1] = __float_as_int(mw_r[e]);
            epack_r[p] = ep;
        }
        return;
    }
    int bid = blockIdx.x - 102;               // 0..2999
    int w = threadIdx.x>>6, l = threadIdx.x&63;
    int lr = l&15, lg = l>>4;
    unsigned short* XB = XBs[w];
    int r0 = (bid*4 + w)*16;
    int g  = r0/NF_;
    int j0 = r0%NF_;
    float fsum0 = 0.f, fsum1 = 0.f;
    #pragma unroll
    for (int i=0;i<16;++i){
        int rr = r0+i;
        int j = j0+i;
        int b = g/T_, t = g%T_, n = j/F_, f = j%F_;
        float v = x[((size_t)((b*N_+n)*F_+f)*T_ + t)*64 + l];
        unsigned short us = f2b(v);
        XB[i*72 + l] = us;
        xg[(size_t)rr*64 + l] = us;
        if (i < 8) fsum0 += v; else fsum1 += v;
    }
    {
        int nb = j0/F_;
        unsigned short u0 = f2b(fsum0*0.125f);
        unsigned short u1 = f2b(fsum1*0.125f);
        WST[(w*2+0)*72 + l] = u0;
        WST[(w*2+1)*72 + l] = u1;
        wsb[((size_t)g*N_ + nb    )*64 + l] = u0;
        wsb[((size_t)g*N_ + nb + 1)*64 + l] = u1;
    }
    __syncthreads();
    // causal GEMM (per wave)
    {
        bf16x8 a0 = *(const bf16x8*)&XB[lr*72 + lg*8];
        bf16x8 a1 = *(const bf16x8*)&XB[lr*72 + 32 + lg*8];
        f32x4 acc[4];
        #pragma unroll
        for (int ct=0;ct<4;++ct) acc[ct] = (f32x4){0.f,0.f,0.f,0.f};
        #pragma unroll
        for (int ct=0;ct<4;++ct){
            bf16x8 b0 = *(const bf16x8*)&wTc[(ct*16+lr)*64 + lg*8];
            bf16x8 b1 = *(const bf16x8*)&wTc[(ct*16+lr)*64 + 32 + lg*8];
            acc[ct] = __builtin_amdgcn_mfma_f32_16x16x32_bf16(a0, b0, acc[ct], 0,0,0);
            acc[ct] = __builtin_amdgcn_mfma_f32_16x16x32_bf16(a1, b1, acc[ct], 0,0,0);
        }
        #pragma unroll
        for (int ct=0;ct<4;++ct){
            float bv = bc[ct*16+lr];
            #pragma unroll
            for (int i=0;i<4;++i)
                yc[(size_t)(r0+lg*4+i)*64 + ct*16+lr] = f2b(acc[ct][i] + bv);
        }
    }
    // river GEMM for the block's 8 n-rows (wave 0)
    if (w == 0){
        int nb0 = ((bid*64)%NF_)/F_;
        int gb  = (bid*64)/NF_;
        bf16x8 a0 = *(const bf16x8*)&WST[lr*72 + lg*8];
        bf16x8 a1 = *(const bf16x8*)&WST[lr*72 + 32 + lg*8];
        f32x4 acc[4];
        #pragma unroll
        for (int ct=0;ct<4;++ct) acc[ct] = (f32x4){0.f,0.f,0.f,0.f};
        #pragma unroll
        for (int ct=0;ct<4;++ct){
            bf16x8 b0 = *(const bf16x8*)&wTr[(ct*16+lr)*64 + lg*8];
            bf16x8 b1 = *(const bf16x8*)&wTr[(ct*16+lr)*64 + 32 + lg*8];
            acc[ct] = __builtin_amdgcn_mfma_f32_16x16x32_bf16(a0, b0, acc[ct], 0,0,0);
            acc[ct] = __builtin_amdgcn_mfma_f32_16x16x32_bf16(a1, b1, acc[ct], 0,0,0);
        }
        if (lg < 2){
            #pragma unroll
            for (int ct=0;ct<4;++ct){
                float bv = br[ct*16+lr];
                #pragma unroll
                for (int i=0;i<4;++i)
                    yr[((size_t)gb*N_ + nb0 + lg*4+i)*64 + ct*16+lr] = f2b(acc[ct][i] + bv);
            }
        }
    }
}

// ---------------------------------------------------------------- merged gather-aggregate (bf16), packed edges,
// 2 rows/wave with INTERLEAVED edge chains (4 loads in flight)
__global__ __launch_bounds__(256) void k_gaggr2(const unsigned short* __restrict__ yc,
                                                const int2v* __restrict__ epack_c,
                                                const int* __restrict__ off_c,
                                                unsigned short* __restrict__ ac,
                                                const unsigned short* __restrict__ yr,
                                                const int2v* __restrict__ epack_r,
                                                const int* __restrict__ off_r,
                                                unsigned short* __restrict__ ar){
    int l = threadIdx.x & 63;
    int w = threadIdx.x >> 6;
    const unsigned short* y; const int2v* epack; const int* off;
    unsigned short* aggr; int nseg, base;
    if (blockIdx.x < 24000){
        int wg = (blockIdx.x & 7)*3000 + (blockIdx.x >> 3);   // XCD-chunked swizzle (24000 % 8 == 0)
        y = yc; epack = epack_c; off = off_c; aggr = ac; nseg = NF_;
        base = wg*8 + w*2;
    } else {
        int pb = blockIdx.x - 24000;
        int wg = (pb & 7)*375 + (pb >> 3);                    // 3000 % 8 == 0
        y = yr; epack = epack_r; off = off_r; aggr = ar; nseg = N_;
        base = wg*8 + w*2;
    }
    int idx0 = base, idx1 = base + 1;
    int g0 = idx0 / nseg, d0 = idx0 % nseg;
    int g1 = idx1 / nseg, d1 = idx1 % nseg;
    int p0 = off[d0], e0 = off[d0+1];
    int p1 = off[d1], e1 = off[d1+1];
    const unsigned short* yg0 = y + (size_t)g0*nseg*64 + l;
    const unsigned short* yg1 = y + (size_t)g1*nseg*64 + l;
    float acc0 = 0.f, acc1 = 0.f;
    // interleaved phase: both rows advance 2 edges/iter (4 loads in flight)
    while (p0+1 < e0 && p1+1 < e1){
        int2v ea0 = epack[p0], eb0 = epack[p0+1];
        int2v ea1 = epack[p1], eb1 = epack[p1+1];
        float va0 = b2f(yg0[(size_t)ea0[0]*64]);
        float vb0 = b2f(yg0[(size_t)eb0[0]*64]);
        float va1 = b2f(yg1[(size_t)ea1[0]*64]);
        float vb1 = b2f(yg1[(size_t)eb1[0]*64]);
        acc0 += __int_as_float(ea0[1])*va0 + __int_as_float(eb0[1])*vb0;
        acc1 += __int_as_float(ea1[1])*va1 + __int_as_float(eb1[1])*vb1;
        p0 += 2; p1 += 2;
    }
    // row-0 tail
    for (; p0+1 < e0; p0 += 2){
        int2v ea = epack[p0], eb = epack[p0+1];
        float va = b2f(yg0[(size_t)ea[0]*64]);
        float vb = b2f(yg0[(size_t)eb[0]*64]);
        acc0 += __int_as_float(ea[1])*va + __int_as_float(eb[1])*vb;
    }
    if (p0 < e0){
        int2v ea = epack[p0];
        acc0 += __int_as_float(ea[1]) * b2f(yg0[(size_t)ea[0]*64]);
    }
    // row-1 tail
    for (; p1+1 < e1; p1 += 2){
        int2v ea = epack[p1], eb = epack[p1+1];
        float va = b2f(yg1[(size_t)ea[0]*64]);
        float vb = b2f(yg1[(size_t)eb[0]*64]);
        acc1 += __int_as_float(ea[1])*va + __int_as_float(eb[1])*vb;
    }
    if (p1 < e1){
        int2v ea = epack[p1];
        acc1 += __int_as_float(ea[1]) * b2f(yg1[(size_t)ea[0]*64]);
    }
    aggr[(size_t)idx0*64 + l] = f2b(acc0);
    aggr[(size_t)idx1*64 + l] = f2b(acc1);
}

// ---------------------------------------------------------------- river update: u = relu([aggr|ws] @ Wu + b)  (all bf16)
__global__ __launch_bounds__(256) void k_upd16(const unsigned short* __restrict__ aggr,
                                               const unsigned short* __restrict__ xin,
                                               const unsigned short* __restrict__ wT,  // [64 n][128 k]
                                               const float* __restrict__ bu,
                                               unsigned short* __restrict__ u){
    __shared__ unsigned short XBs[4][16*136];
    int w = threadIdx.x>>6, l = threadIdx.x&63;
    int lr = l&15, lg = l>>4;
    int lq = l>>4, lc = (l&15)*4;
    unsigned short* XB = XBs[w];
    int r0 = (blockIdx.x*4 + w)*16;
    #pragma unroll
    for (int v=0; v<4; ++v){
        int row = v*4 + lq;
        int rr = r0 + row;
        *(short4v*)&XB[row*136 + lc]      = *(const short4v*)&aggr[(size_t)rr*64 + lc];
        *(short4v*)&XB[row*136 + 64 + lc] = *(const short4v*)&xin[(size_t)rr*64 + lc];
    }
    LGKM0;
    bf16x8 a[4];
    #pragma unroll
    for (int kk=0;kk<4;++kk) a[kk] = *(const bf16x8*)&XB[lr*136 + kk*32 + lg*8];
    f32x4 acc[4];
    #pragma unroll
    for (int ct=0;ct<4;++ct) acc[ct] = (f32x4){0.f,0.f,0.f,0.f};
    #pragma unroll
    for (int ct=0;ct<4;++ct){
        #pragma unroll
        for (int kk=0;kk<4;++kk){
            bf16x8 b0 = *(const bf16x8*)&wT[(ct*16+lr)*128 + kk*32 + lg*8];
            acc[ct] = __builtin_amdgcn_mfma_f32_16x16x32_bf16(a[kk], b0, acc[ct], 0,0,0);
        }
    }
    #pragma unroll
    for (int ct=0;ct<4;++ct){
        float bv = bu[ct*16+lr];
        #pragma unroll
        for (int i=0;i<4;++i)
            u[(size_t)(r0+lg*4+i)*64 + ct*16+lr] = f2b(fmaxf(acc[ct][i] + bv, 0.f));
    }
}

// ---------------------------------------------------------------- fused causal-update + fusion MLP, 2 tiles/wave (all bf16)
__global__ __launch_bounds__(256) void k_updfus(const unsigned short* __restrict__ aggr,
                                                const unsigned short* __restrict__ xg,
                                                const unsigned short* __restrict__ wuT,  // [64][128]
                                                const float* __restrict__ bu,
                                                const unsigned short* __restrict__ wsu,
                                                const unsigned short* __restrict__ w1T,  // [64][128]
                                                const float* __restrict__ b1,
                                                const unsigned short* __restrict__ w2T,  // [64][64]
                                                const float* __restrict__ b2,
                                                unsigned short* __restrict__ fused){
    __shared__ unsigned short XBs[4][2][16*136];
    __shared__ unsigned short X2s[4][2][16*136];
    int w = threadIdx.x>>6, l = threadIdx.x&63;
    int lr = l&15, lg = l>>4;
    int lq = l>>4, lc = (l&15)*4;
    unsigned short* XB[2] = { XBs[w][0], XBs[w][1] };
    unsigned short* X2[2] = { X2s[w][0], X2s[w][1] };
    int tb = (blockIdx.x*4 + w)*32;      // 32 rows per wave, 32 | 8000 -> no g straddle
    int g  = tb/NF_;
    int n0 = (tb%NF_)/F_;                // octets: tile tt rows 0-7 -> n0+tt*2, rows 8-15 -> n0+tt*2+1
    #pragma unroll
    for (int tt=0;tt<2;++tt){
        int r0 = tb + tt*16;
        #pragma unroll
        for (int v=0; v<4; ++v){
            int row = v*4 + lq;
            int rr = r0 + row;
            *(short4v*)&XB[tt][row*136 + lc]      = *(const short4v*)&aggr[(size_t)rr*64 + lc];
            *(short4v*)&XB[tt][row*136 + 64 + lc] = *(const short4v*)&xg[(size_t)rr*64 + lc];
        }
        unsigned short wv0 = wsu[((size_t)g*N_ + n0 + tt*2    )*64 + l];
        unsigned short wv1 = wsu[((size_t)g*N_ + n0 + tt*2 + 1)*64 + l];
        #pragma unroll
        for (int i=0;i<8;++i){
            X2[tt][i*136 + 64 + l]     = wv0;
            X2[tt][(i+8)*136 + 64 + l] = wv1;
        }
    }
    LGKM0;
    // stage 1: update GEMM k=128 -> relu -> X2 cols 0..63 (both tiles)
    {
        bf16x8 a[2][4];
        #pragma unroll
        for (int tt=0;tt<2;++tt)
            #pragma unroll
            for (int kk=0;kk<4;++kk) a[tt][kk] = *(const bf16x8*)&XB[tt][lr*136 + kk*32 + lg*8];
        f32x4 acc[2][4];
        #pragma unroll
        for (int tt=0;tt<2;++tt)
            #pragma unroll
            for (int ct=0;ct<4;++ct) acc[tt][ct] = (f32x4){0.f,0.f,0.f,0.f};
        #pragma unroll
        for (int ct=0;ct<4;++ct){
            #pragma unroll
            for (int kk=0;kk<4;++kk){
                bf16x8 b0 = *(const bf16x8*)&wuT[(ct*16+lr)*128 + kk*32 + lg*8];
                #pragma unroll
                for (int tt=0;tt<2;++tt)
                    acc[tt][ct] = __builtin_amdgcn_mfma_f32_16x16x32_bf16(a[tt][kk], b0, acc[tt][ct], 0,0,0);
            }
        }
        #pragma unroll
        for (int ct=0;ct<4;++ct){
            float bv = bu[ct*16+lr];
            #pragma unroll
            for (int tt=0;tt<2;++tt)
                #pragma unroll
                for (int i=0;i<4;++i)
                    X2[tt][(lg*4+i)*136 + ct*16+lr] = f2b(fmaxf(acc[tt][ct][i] + bv, 0.f));
        }
    }
    LGKM0;
    // stage 2: fusion GEMM1 k=128 -> relu -> XB cols 0..63 (both tiles)
    {
        bf16x8 a[2][4];
        #pragma unroll
        for (int tt=0;tt<2;++tt)
            #pragma unroll
            for (int kk=0;kk<4;++kk) a[tt][kk] = *(const bf16x8*)&X2[tt][lr*136 + kk*32 + lg*8];
        f32x4 acc[2][4];
        #pragma unroll
        for (int tt=0;tt<2;++tt)
            #pragma unroll
            for (int ct=0;ct<4;++ct) acc[tt][ct] = (f32x4){0.f,0.f,0.f,0.f};
        #pragma unroll
        for (int ct=0;ct<4;++ct){
            #pragma unroll
            for (int kk=0;kk<4;++kk){
                bf16x8 b0 = *(const bf16x8*)&w1T[(ct*16+lr)*128 + kk*32 + lg*8];
                #pragma unroll
                for (int tt=0;tt<2;++tt)
                    acc[tt][ct] = __builtin_amdgcn_mfma_f32_16x16x32_bf16(a[tt][kk], b0, acc[tt][ct], 0,0,0);
            }
        }
        #pragma unroll
        for (int ct=0;ct<4;++ct){
            float bv = b1[ct*16+lr];
            #pragma unroll
            for (int tt=0;tt<2;++tt)
                #pragma unroll
                for (int i=0;i<4;++i)
                    XB[tt][(lg*4+i)*136 + ct*16+lr] = f2b(fmaxf(acc[tt][ct][i] + bv, 0.f));
        }
    }
    LGKM0;
    // stage 3: fusion GEMM2 k=64 -> fused (both tiles)
    {
        bf16x8 h0[2], h1[2];
        #pragma unroll
        for (int tt=0;tt<2;++tt){
            h0[tt] = *(const bf16x8*)&XB[tt][lr*136 + lg*8];
            h1[tt] = *(const bf16x8*)&XB[tt][lr*136 + 32 + lg*8];
        }
        f32x4 acc[2][4];
        #pragma unroll
        for (int tt=0;tt<2;++tt)
            #pragma unroll
            for (int ct=0;ct<4;++ct) acc[tt][ct] = (f32x4){0.f,0.f,0.f,0.f};
        #pragma unroll
        for (int ct=0;ct<4;++ct){
            bf16x8 b0 = *(const bf16x8*)&w2T[(ct*16+lr)*64 + lg*8];
            bf16x8 b1v= *(const bf16x8*)&w2T[(ct*16+lr)*64 + 32 + lg*8];
            #pragma unroll
            for (int tt=0;tt<2;++tt){
                acc[tt][ct] = __builtin_amdgcn_mfma_f32_16x16x32_bf16(h0[tt], b0, acc[tt][ct], 0,0,0);
                acc[tt][ct] = __builtin_amdgcn_mfma_f32_16x16x32_bf16(h1[tt], b1v, acc[tt][ct], 0,0,0);
            }
        }
        #pragma unroll
        for (int ct=0;ct<4;++ct){
            float bv = b2[ct*16+lr];
            #pragma unroll
            for (int tt=0;tt<2;++tt)
                #pragma unroll
                for (int i=0;i<4;++i)
                    fused[(size_t)(tb + tt*16 + lg*4+i)*64 + ct*16+lr] = f2b(acc[tt][ct][i] + bv);
        }
    }
}

// ---------------------------------------------------------------- MFMA temporal transformer: 4 waves, 2 seqs/wave, 12-row SC
// Vectorized staging + cvt_pk conversions (no setprio — measured neutral/negative).
#define XSTR 72    // XB stride (shorts); LN-out / V^T / O staging (16 rows)
#define SSTR 136   // SC stride (shorts): Q 0-63, K 64-127; 12 rows/seq + tail pad; aliased as HID
#define SCSZ (12*SSTR)

__global__ __launch_bounds__(256) void k_xformer(
    const unsigned short* __restrict__ fused,
    const unsigned short* __restrict__ wtq,   // [192][64], Q-part pre-scaled 0.25
    const unsigned short* __restrict__ wto,   // [64][64]
    const unsigned short* __restrict__ wt1,   // [256][64]
    const unsigned short* __restrict__ wt2,   // [64][256]
    const float* __restrict__ bqkv, const float* __restrict__ bo,
    const float* __restrict__ fb1,  const float* __restrict__ fb2,
    const float* __restrict__ ln1g, const float* __restrict__ ln1b,
    const float* __restrict__ ln2g, const float* __restrict__ ln2b,
    float* __restrict__ out)
{
    __shared__ unsigned short XBs[4][2][16*XSTR];
    __shared__ unsigned short SCmem[8*SCSZ + 544];   // 12-row slices + tail pad for benign row-12..15 reads

    int w  = threadIdx.x >> 6;
    int l  = threadIdx.x & 63;
    int lr = l & 15;
    int lg = l >> 4;

    unsigned short* XBp[2] = { XBs[w][0], XBs[w][1] };
    unsigned short* SCp[2] = { &SCmem[(w*2+0)*SCSZ], &SCmem[(w*2+1)*SCSZ] };

    int gbase = (blockIdx.x*4 + w)*2;

    // ---- stage fused rows into SC (vectorized: 3 x 128B row-loads per seq) ----
    #pragma unroll
    for (int sq=0;sq<2;++sq){
        int gs = gbase + sq;
        int bb = gs / NF_, j = gs % NF_;
        const unsigned short* fp = fused + ((size_t)bb*T_*NF_ + j)*64;
        #pragma unroll
        for (int ps=0; ps<3; ++ps){
            int t = ps*4 + lg;
            *(short4v*)&SCp[sq][t*SSTR + lr*4] = *(const short4v*)&fp[(size_t)t*NF_*64 + lr*4];
        }
    }
    LGKM0;

    // ---- read C-layout fragments from LDS ----
    float res[2][4][4];
    #pragma unroll
    for (int sq=0;sq<2;++sq)
        #pragma unroll
        for (int nt=0;nt<4;++nt)
            #pragma unroll
            for (int i=0;i<4;++i){
                int t = lg*4+i;
                res[sq][nt][i] = (t < 12) ? b2f(SCp[sq][t*SSTR + nt*16 + lr]) : 0.f;
            }

    // LN1 -> XB (both seqs), packed conversions
    #pragma unroll
    for (int sq=0;sq<2;++sq){
        float sm[4], sqr[4];
        #pragma unroll
        for (int i=0;i<4;++i){
            sm[i]  = res[sq][0][i]+res[sq][1][i]+res[sq][2][i]+res[sq][3][i];
            sqr[i] = res[sq][0][i]*res[sq][0][i]+res[sq][1][i]*res[sq][1][i]
                   + res[sq][2][i]*res[sq][2][i]+res[sq][3][i]*res[sq][3][i];
        }
        #pragma unroll
        for (int m=1;m<16;m<<=1){
            #pragma unroll
            for (int i=0;i<4;++i){
                sm[i]  += __shfl_xor(sm[i], m, 64);
                sqr[i] += __shfl_xor(sqr[i], m, 64);
            }
        }
        float mnv[4], rsv[4];
        #pragma unroll
        for (int i=0;i<4;++i){
            mnv[i] = sm[i]*(1.0f/64.0f);
            float var = sqr[i]*(1.0f/64.0f) - mnv[i]*mnv[i];
            rsv[i] = rsqrtf(var + 1e-5f);
        }
        #pragma unroll
        for (int nt=0;nt<4;++nt){
            float gg = ln1g[nt*16+lr], oo = ln1b[nt*16+lr];
            float w0 = (res[sq][nt][0]-mnv[0])*rsv[0]*gg + oo;
            float w1 = (res[sq][nt][1]-mnv[1])*rsv[1]*gg + oo;
            float w2 = (res[sq][nt][2]-mnv[2])*rsv[2]*gg + oo;
            float w3 = (res[sq][nt][3]-mnv[3])*rsv[3]*gg + oo;
            unsigned u01 = cpk(w0,w1), u23 = cpk(w2,w3);
            XBp[sq][(lg*4+0)*XSTR + nt*16 + lr] = (unsigned short)u01;
            XBp[sq][(lg*4+1)*XSTR + nt*16 + lr] = (unsigned short)(u01>>16);
            XBp[sq][(lg*4+2)*XSTR + nt*16 + lr] = (unsigned short)u23;
            XBp[sq][(lg*4+3)*XSTR + nt*16 + lr] = (unsigned short)(u23>>16);
        }
    }
    LGKM0;

    // QKV GEMM: Q,K -> SC (rows<12); V^T -> XB (shared weight frags), packed conversions
    {
        bf16x8 a0[2], a1[2];
        #pragma unroll
        for (int sq=0;sq<2;++sq){
            a0[sq] = *(const bf16x8*)&XBp[sq][lr*XSTR + 0*32 + lg*8];
            a1[sq] = *(const bf16x8*)&XBp[sq][lr*XSTR + 1*32 + lg*8];
        }
        LGKM0;   // a-frags in regs before V overwrites XB
        #pragma unroll
        for (int p=0;p<3;++p){
            f32x4 acc[2][4];
            #pragma unroll
            for (int sq=0;sq<2;++sq)
                #pragma unroll
                for (int c=0;c<4;++c) acc[sq][c] = (f32x4){0.f,0.f,0.f,0.f};
            #pragma unroll
            for (int c=0;c<4;++c){
                int ct = p*4 + c;
                bf16x8 b0 = *(const bf16x8*)&wtq[(ct*16+lr)*64 + 0*32 + lg*8];
                bf16x8 b1v= *(const bf16x8*)&wtq[(ct*16+lr)*64 + 1*32 + lg*8];
                #pragma unroll
                for (int sq=0;sq<2;++sq){
                    acc[sq][c] = __builtin_amdgcn_mfma_f32_16x16x32_bf16(a0[sq], b0, acc[sq][c], 0,0,0);
                    acc[sq][c] = __builtin_amdgcn_mfma_f32_16x16x32_bf16(a1[sq], b1v, acc[sq][c], 0,0,0);
                }
            }
            if (p < 2){
                if (lg < 3){
                    #pragma unroll
                    for (int c=0;c<4;++c){
                        int ct = p*4 + c;
                        float bv = bqkv[ct*16+lr];
                        if (p == 0) bv *= 0.25f;
                        #pragma unroll
                        for (int sq=0;sq<2;++sq){
                            unsigned u01 = cpk(acc[sq][c][0]+bv, acc[sq][c][1]+bv);
                            unsigned u23 = cpk(acc[sq][c][2]+bv, acc[sq][c][3]+bv);
                            SCp[sq][(lg*4+0)*SSTR + p*64 + c*16 + lr] = (unsigned short)u01;
                            SCp[sq][(lg*4+1)*SSTR + p*64 + c*16 + lr] = (unsigned short)(u01>>16);
                            SCp[sq][(lg*4+2)*SSTR + p*64 + c*16 + lr] = (unsigned short)u23;
                            SCp[sq][(lg*4+3)*SSTR + p*64 + c*16 + lr] = (unsigned short)(u23>>16);
                        }
                    }
                }
            } else {
                #pragma unroll
                for (int c=0;c<4;++c){
                    float bv = bqkv[128 + c*16 + lr];
                    #pragma unroll
                    for (int sq=0;sq<2;++sq){
                        uint2v vv2;
                        vv2[0] = cpk(acc[sq][c][0]+bv, acc[sq][c][1]+bv);
                        vv2[1] = cpk(acc[sq][c][2]+bv, acc[sq][c][3]+bv);
                        *(uint2v*)&XBp[sq][lr*XSTR + c*16 + lg*4] = vv2;   // VT'[d=c*16+lr][t=lg*4..+3]
                    }
                }
            }
        }
    }
    LGKM0;

    // MFMA attention per head, both seqs (packed P and O conversions)
    {
        const bf16x8 bz = (bf16x8){0,0,0,0,0,0,0,0};
        #pragma unroll
        for (int hd=0; hd<4; ++hd){
            #pragma unroll
            for (int sq=0;sq<2;++sq){
                bf16x8 ak = bz, bq = bz;
                if (lg < 2){
                    ak = *(const bf16x8*)&SCp[sq][lr*SSTR + 64 + hd*16 + lg*8];
                    bq = *(const bf16x8*)&SCp[sq][lr*SSTR +      hd*16 + lg*8];
                }
                f32x4 st = __builtin_amdgcn_mfma_f32_16x16x32_bf16(ak, bq, (f32x4){0.f,0.f,0.f,0.f}, 0,0,0);
                float s0=st[0], s1v=st[1], s2=st[2], s3=st[3];
                if (lg == 3){ s0=s1v=s2=s3=-1e30f; }
                float mx = fmaxf(fmaxf(s0,s1v), fmaxf(s2,s3));
                mx = fmaxf(mx, __shfl_xor(mx, 16, 64));
                mx = fmaxf(mx, __shfl_xor(mx, 32, 64));
                float p0 = __expf(s0-mx), p1 = __expf(s1v-mx), p2 = __expf(s2-mx), p3 = __expf(s3-mx);
                float den = p0+p1+p2+p3;
                den += __shfl_xor(den, 16, 64);
                den += __shfl_xor(den, 32, 64);
                float inv = __builtin_amdgcn_rcpf(den);
                float q0 = __shfl_down(p0, 16, 64), q1 = __shfl_down(p1, 16, 64);
                float q2 = __shfl_down(p2, 16, 64), q3 = __shfl_down(p3, 16, 64);
                union { uint4v u; bf16x8 b; } pu;
                {
                    float lo0 = (lg==0)? p0 : (lg==1)? q0 : 0.f;
                    float lo1 = (lg==0)? p1 : (lg==1)? q1 : 0.f;
                    float lo2 = (lg==0)? p2 : (lg==1)? q2 : 0.f;
                    float lo3 = (lg==0)? p3 : (lg==1)? q3 : 0.f;
                    float hi0 = (lg==0)? q0 : 0.f;
                    float hi1 = (lg==0)? q1 : 0.f;
                    float hi2 = (lg==0)? q2 : 0.f;
                    float hi3 = (lg==0)? q3 : 0.f;
                    pu.u[0] = cpk(lo0, lo1);
                    pu.u[1] = cpk(lo2, lo3);
                    pu.u[2] = cpk(hi0, hi1);
                    pu.u[3] = cpk(hi2, hi3);
                }
                bf16x8 pb = pu.b;
                bf16x8 av = bz;
                if (lg < 2) av = *(const bf16x8*)&XBp[sq][lr*XSTR + hd*16 + lg*8];
                f32x4 ot = __builtin_amdgcn_mfma_f32_16x16x32_bf16(av, pb, (f32x4){0.f,0.f,0.f,0.f}, 0,0,0);
                uint2v ow2;
                ow2[0] = cpk(ot[0]*inv, ot[1]*inv);
                ow2[1] = cpk(ot[2]*inv, ot[3]*inv);
                *(uint2v*)&XBp[sq][lr*XSTR + hd*16 + lg*4] = ow2;
            }
        }
    }
    LGKM0;

    // proj + residual -> s1 (shared weight frags)
    float s1[2][4][4];
    {
        bf16x8 a0[2], a1[2];
        #pragma unroll
        for (int sq=0;sq<2;++sq){
            a0[sq] = *(const bf16x8*)&XBp[sq][lr*XSTR + 0*32 + lg*8];
            a1[sq] = *(const bf16x8*)&XBp[sq][lr*XSTR + 1*32 + lg*8];
        }
        f32x4 pacc[2][4];
        #pragma unroll
        for (int sq=0;sq<2;++sq)
            #pragma unroll
            for (int ct=0;ct<4;++ct) pacc[sq][ct] = (f32x4){0.f,0.f,0.f,0.f};
        #pragma unroll
        for (int ct=0;ct<4;++ct){
            bf16x8 b0 = *(const bf16x8*)&wto[(ct*16+lr)*64 + 0*32 + lg*8];
            bf16x8 b1v= *(const bf16x8*)&wto[(ct*16+lr)*64 + 1*32 + lg*8];
            #pragma unroll
            for (int sq=0;sq<2;++sq){
                pacc[sq][ct] = __builtin_amdgcn_mfma_f32_16x16x32_bf16(a0[sq], b0, pacc[sq][ct], 0,0,0);
                pacc[sq][ct] = __builtin_amdgcn_mfma_f32_16x16x32_bf16(a1[sq], b1v, pacc[sq][ct], 0,0,0);
            }
        }
        #pragma unroll
        for (int sq=0;sq<2;++sq)
            #pragma unroll
            for (int ct=0;ct<4;++ct){
                float bv = bo[ct*16+lr];
                #pragma unroll
                for (int i=0;i<4;++i)
                    s1[sq][ct][i] = res[sq][ct][i] + pacc[sq][ct][i] + bv;
            }
    }

    // LN2 -> XB (both seqs), packed conversions
    #pragma unroll
    for (int sq=0;sq<2;++sq){
        float sm[4], sqr[4];
        #pragma unroll
        for (int i=0;i<4;++i){
            sm[i]  = s1[sq][0][i]+s1[sq][1][i]+s1[sq][2][i]+s1[sq][3][i];
            sqr[i] = s1[sq][0][i]*s1[sq][0][i]+s1[sq][1][i]*s1[sq][1][i]
                   + s1[sq][2][i]*s1[sq][2][i]+s1[sq][3][i]*s1[sq][3][i];
        }
        #pragma unroll
        for (int m=1;m<16;m<<=1){
            #pragma unroll
            for (int i=0;i<4;++i){
                sm[i]  += __shfl_xor(sm[i], m, 64);
                sqr[i] += __shfl_xor(sqr[i], m, 64);
            }
        }
        float mnv[4], rsv[4];
        #pragma unroll
        for (int i=0;i<4;++i){
            mnv[i] = sm[i]*(1.0f/64.0f);
            float var = sqr[i]*(1.0f/64.0f) - mnv[i]*mnv[i];
            rsv[i] = rsqrtf(var + 1e-5f);
        }
        #pragma unroll
        for (int nt=0;nt<4;++nt){
            float gg = ln2g[nt*16+lr], oo = ln2b[nt*16+lr];
            float w0 = (s1[sq][nt][0]-mnv[0])*rsv[0]*gg + oo;
            float w1 = (s1[sq][nt][1]-mnv[1])*rsv[1]*gg + oo;
            float w2 = (s1[sq][nt][2]-mnv[2])*rsv[2]*gg + oo;
            float w3 = (s1[sq][nt][3]-mnv[3])*rsv[3]*gg + oo;
            unsigned u01 = cpk(w0,w1), u23 = cpk(w2,w3);
            XBp[sq][(lg*4+0)*XSTR + nt*16 + lr] = (unsigned short)u01;
            XBp[sq][(lg*4+1)*XSTR + nt*16 + lr] = (unsigned short)(u01>>16);
            XBp[sq][(lg*4+2)*XSTR + nt*16 + lr] = (unsigned short)u23;
            XBp[sq][(lg*4+3)*XSTR + nt*16 + lr] = (unsigned short)(u23>>16);
        }
    }
    LGKM0;

    // FFN: two 128-wide halves; HID stores guarded rows<12; packed conversions
    f32x4 oacc[2][4];
    #pragma unroll
    for (int sq=0;sq<2;++sq)
        #pragma unroll
        for (int ct=0;ct<4;++ct) oacc[sq][ct] = (f32x4){0.f,0.f,0.f,0.f};
    {
        bf16x8 a0[2], a1[2];
        #pragma unroll
        for (int sq=0;sq<2;++sq){
            a0[sq] = *(const bf16x8*)&XBp[sq][lr*XSTR + 0*32 + lg*8];
            a1[sq] = *(const bf16x8*)&XBp[sq][lr*XSTR + 1*32 + lg*8];
        }
        #pragma unroll
        for (int half=0; half<2; ++half){
            LGKM0;   // HID region reuse guard
            #pragma unroll
            for (int q=0; q<2; ++q){
                f32x4 facc[2][4];
                #pragma unroll
                for (int sq=0;sq<2;++sq)
                    #pragma unroll
                    for (int c=0;c<4;++c) facc[sq][c] = (f32x4){0.f,0.f,0.f,0.f};
                #pragma unroll
                for (int c=0;c<4;++c){
                    int ct = half*8 + q*4 + c;
                    bf16x8 b0 = *(const bf16x8*)&wt1[(ct*16+lr)*64 + 0*32 + lg*8];
                    bf16x8 b1v= *(const bf16x8*)&wt1[(ct*16+lr)*64 + 1*32 + lg*8];
                    #pragma unroll
                    for (int sq=0;sq<2;++sq){
                        facc[sq][c] = __builtin_amdgcn_mfma_f32_16x16x32_bf16(a0[sq], b0, facc[sq][c], 0,0,0);
                        facc[sq][c] = __builtin_amdgcn_mfma_f32_16x16x32_bf16(a1[sq], b1v, facc[sq][c], 0,0,0);
                    }
                }
                if (lg < 3){
                    #pragma unroll
                    for (int c=0;c<4;++c){
                        int ct = half*8 + q*4 + c;
                        float bv = fb1[ct*16+lr];
                        #pragma unroll
                        for (int sq=0;sq<2;++sq){
                            float hv[4];
                            #pragma unroll
                            for (int i=0;i<4;++i){
                                float xv = facc[sq][c][i] + bv;
                                float x2 = xv*xv;
                                float z  = xv*(1.5957691216f + 0.0713548162f*x2);
                                float ez = __expf(-z);
                                hv[i] = xv * __builtin_amdgcn_rcpf(1.0f + ez);
                            }
                            unsigned u01 = cpk(hv[0],hv[1]), u23 = cpk(hv[2],hv[3]);
                            SCp[sq][(lg*4+0)*SSTR + (q*4+c)*16 + lr] = (unsigned short)u01;
                            SCp[sq][(lg*4+1)*SSTR + (q*4+c)*16 + lr] = (unsigned short)(u01>>16);
                            SCp[sq][(lg*4+2)*SSTR + (q*4+c)*16 + lr] = (unsigned short)u23;
                            SCp[sq][(lg*4+3)*SSTR + (q*4+c)*16 + lr] = (unsigned short)(u23>>16);
                        }
                    }
                }
            }
            LGKM0;
            #pragma unroll
            for (int ks=0;ks<4;++ks){
                bf16x8 af[2];
                #pragma unroll
                for (int sq=0;sq<2;++sq)
                    af[sq] = *(const bf16x8*)&SCp[sq][lr*SSTR + ks*32 + lg*8];
                #pragma unroll
                for (int ct=0;ct<4;++ct){
                    bf16x8 bfr = *(const bf16x8*)&wt2[(ct*16+lr)*256 + half*128 + ks*32 + lg*8];
                    #pragma unroll
                    for (int sq=0;sq<2;++sq)
                        oacc[sq][ct] = __builtin_amdgcn_mfma_f32_16x16x32_bf16(af[sq], bfr, oacc[sq][ct], 0,0,0);
                }
            }
        }
    }

    // residual + mean over t (both seqs)
    #pragma unroll
    for (int sq=0;sq<2;++sq)
        #pragma unroll
        for (int ct=0;ct<4;++ct){
            float bv = fb2[ct*16+lr];
            float part = 0.f;
            #pragma unroll
            for (int i=0;i<4;++i){
                if (lg*4+i < 12) part += s1[sq][ct][i] + oacc[sq][ct][i] + bv;
            }
            part += __shfl_xor(part, 16, 64);
            part += __shfl_xor(part, 32, 64);
            if (lg == 0) out[(size_t)(gbase+sq)*64 + ct*16 + lr] = part*(1.0f/12.0f);
        }
}

// ----------------------------------------------------------------
extern "C" void kernel_launch(void* const* d_in, const int* in_sizes, int n_in,
                              void* d_out, int out_size, void* d_ws, size_t ws_size,
                              hipStream_t stream) {
    const float* x      = (const float*)d_in[0];
    const int*   r_ei   = (const int*)  d_in[1];
    const float* r_ea   = (const float*)d_in[2];
    const int*   c_ei   = (const int*)  d_in[3];
    const float* c_ew   = (const float*)d_in[4];
    const float* rvWlin = (const float*)d_in[5];
    const float* rvblin = (const float*)d_in[6];
    const float* rvWupd = (const float*)d_in[7];
    const float* rvbupd = (const float*)d_in[8];
    const float* rvgate = (const float*)d_in[9];
    const float* rvlw   = (const float*)d_in[10];
    const float* csWlin = (const float*)d_in[11];
    const float* csblin = (const float*)d_in[12];
    const float* csWupd = (const float*)d_in[13];
    const float* csbupd = (const float*)d_in[14];
    const float* csgate = (const float*)d_in[15];
    const float* cslw   = (const float*)d_in[16];
    const float* fuW1   = (const float*)d_in[17];
    const float* fub1   = (const float*)d_in[18];
    const float* fuW2   = (const float*)d_in[19];
    const float* fub2   = (const float*)d_in[20];
    const float* ln1g   = (const float*)d_in[21];
    const float* ln1b   = (const float*)d_in[22];
    const float* ln2g   = (const float*)d_in[23];
    const float* ln2b   = (const float*)d_in[24];
    const float* Wqkv   = (const float*)d_in[25];
    const float* bqkv   = (const float*)d_in[26];
    const float* Wo     = (const float*)d_in[27];
    const float* bo     = (const float*)d_in[28];
    const float* ffW1   = (const float*)d_in[29];
    const float* ffb1   = (const float*)d_in[30];
    const float* ffW2   = (const float*)d_in[31];
    const float* ffb2   = (const float*)d_in[32];

    float* wsp  = (float*)d_ws;
    unsigned short* FNY_b = (unsigned short*)wsp;                    // causal y bf16, then FUSED bf16
    unsigned short* FNA_b = (unsigned short*)(wsp + 12288000);       // causal aggr bf16
    unsigned short* XG_b  = (unsigned short*)(wsp + 12288000 + 6144000); // gathered x bf16
    unsigned short* WS_b  = (unsigned short*)(wsp + 24576000);       // watershed mean bf16
    unsigned short* WSY_b = (unsigned short*)(wsp + 26112000);       // river y bf16
    unsigned short* WSA_b = (unsigned short*)(wsp + 27648000);       // river aggr bf16
    float* WSU  = wsp + 29184000;                                    // CSR scratch, then river u bf16
    unsigned short* WSU_b = (unsigned short*)WSU;
    unsigned short* wt = (unsigned short*)(wsp + 30720000);
    float* outp = (float*)d_out;

    int* ibase  = (int*)WSU;
    int* cnt_c  = ibase;
    int* cnt_r  = ibase + 8000;
    int* off_c  = ibase + 9000;
    int* off_r  = ibase + 17001;
    int* cur_c  = ibase + 18002;
    int* cur_r  = ibase + 26002;
    float* mw_c = (float*)(ibase + 53002);
    float* mw_r = (float*)(ibase + 77002);
    int2v* epack_c = (int2v*)(ibase + 80000);   // 24000 x 8B
    int2v* epack_r = (int2v*)(ibase + 128000);  //  2000 x 8B (clobbered later by river u -> OK, consumers done)

    const int* c_src = c_ei;
    const int* c_dst = c_ei + EC_;
    const int* r_src = r_ei;
    const int* r_dst = r_ei + ER_;

    hipMemsetAsync(cnt_c, 0, 9000*sizeof(int), stream);

    // merged: mw+histogram (102 blocks) + bf16 weight panels (336 blocks)
    k_prephist<<<438, 256, 0, stream>>>(c_dst, r_dst, c_ew, cslw, csgate,
                                        r_ea, rvlw, rvgate, mw_c, mw_r, cnt_c, cnt_r,
                                        Wqkv, Wo, ffW1, ffW2, csWlin, rvWlin, csWupd, rvWupd,
                                        fuW1, fuW2, wt);
    k_scan<<<2, 256, 0, stream>>>(cnt_c, off_c, cur_c, cnt_r, off_r, cur_r);

    // merged: CSR fill (102 blocks) + node linear (3000 blocks)
    k_filllin<<<3102, 256, 0, stream>>>(c_src, c_dst, r_src, r_dst, mw_c, mw_r,
                                        cur_c, cur_r, epack_c, epack_r,
                                        x, wt+49152, csblin, wt+53248, rvblin,
                                        FNY_b, WSY_b, XG_b, WS_b);

    // merged gather-aggregation (packed edges, interleaved 2-row chains, no atomics)
    k_gaggr2<<<27000, 256, 0, stream>>>(FNY_b, epack_c, off_c, FNA_b,
                                        WSY_b, epack_r, off_r, WSA_b);

    // river update (clobbers CSR scratch -> OK, consumers done)
    k_upd16<<<375, 256, 0, stream>>>(WSA_b, WS_b, wt+65536, rvbupd, WSU_b);

    // fused causal update + fusion MLP, 2 tiles/wave -> FUSED bf16 (into FNY region)
    k_updfus<<<1500, 256, 0, stream>>>(FNA_b, XG_b, wt+57344, csbupd, WSU_b,
                                       wt+73728, fub1, wt+81920, fub2, FNY_b);

    // 2-seq-per-wave MFMA transformer (cvt_pk, no setprio)
    k_xformer<<<2000, 256, 0, stream>>>(FNY_b,
                                        wt, wt+12288, wt+16384, wt+32768,
                                        bqkv, bo, ffb1, ffb2,
                                        ln1g, ln1b, ln2g, ln2b,
                                        outp);
}

// Round 23
// 265.150 us; speedup vs baseline: 1.0492x; 1.0394x over previous
//
#include <hip/hip_runtime.h>
#include <math.h>

#define B_ 2
#define N_ 1000
#define F_ 8
#define T_ 12
#define H_ 64
#define G_ 24      // B*T
#define NF_ 8000   // N*F
#define ER_ 2000
#define EC_ 24000

typedef short bf16x8 __attribute__((ext_vector_type(8)));
typedef short short4v __attribute__((ext_vector_type(4)));
typedef float f32x4 __attribute__((ext_vector_type(4)));
typedef unsigned int uint2v __attribute__((ext_vector_type(2)));
typedef unsigned int uint4v __attribute__((ext_vector_type(4)));
typedef int int2v __attribute__((ext_vector_type(2)));

#define LGKM0 do { asm volatile("s_waitcnt lgkmcnt(0)" ::: "memory"); __builtin_amdgcn_sched_barrier(0); } while(0)

__device__ __forceinline__ float sigf(float x){ return 1.0f/(1.0f+__expf(-x)); }

// f32 -> bf16 (RNE)
__device__ __forceinline__ unsigned short f2b(float f){
    unsigned u = __float_as_uint(f);
    unsigned r = (u + 0x7FFFu + ((u >> 16) & 1u)) >> 16;
    return (unsigned short)r;
}
__device__ __forceinline__ float b2f(unsigned short u){
    return __uint_as_float(((unsigned)u) << 16);
}
// packed 2xf32 -> 2xbf16 in one VALU op (gfx950)
__device__ __forceinline__ unsigned cpk(float lo, float hi){
    unsigned r;
    asm("v_cvt_pk_bf16_f32 %0, %1, %2" : "=v"(r) : "v"(lo), "v"(hi));
    return r;
}

// ---------------------------------------------------------------- merged: mw+histogram (blocks 0..101) + weight prep (blocks 102+)
__global__ __launch_bounds__(256) void k_prephist(
    const int* __restrict__ c_dst, const int* __restrict__ r_dst,
    const float* __restrict__ c_ew, const float* __restrict__ c_lw, const float* __restrict__ c_gate,
    const float* __restrict__ r_ew, const float* __restrict__ r_lw, const float* __restrict__ r_gate,
    float* __restrict__ mw_c, float* __restrict__ mw_r,
    int* __restrict__ cnt_c, int* __restrict__ cnt_r,
    const float* __restrict__ Wqkv, const float* __restrict__ Wo,
    const float* __restrict__ W1,   const float* __restrict__ W2,
    const float* __restrict__ csWlin, const float* __restrict__ rvWlin,
    const float* __restrict__ csWupd, const float* __restrict__ rvWupd,
    const float* __restrict__ fuW1,   const float* __restrict__ fuW2,
    unsigned short* __restrict__ wt)
{
    if (blockIdx.x < 102){
        int i = blockIdx.x*256 + threadIdx.x;
        if (i < EC_){
            float gs = sigf(c_gate[0]);
            mw_c[i] = gs*c_ew[i] + (1.f-gs)*sigf(c_lw[i]);
            atomicAdd(&cnt_c[c_dst[i]], 1);
        } else if (i < EC_+ER_){
            int e = i - EC_;
            float gs = sigf(r_gate[0]);
            mw_r[e] = gs*r_ew[e] + (1.f-gs)*sigf(r_lw[e]);
            atomicAdd(&cnt_r[r_dst[e]], 1);
        }
        return;
    }
    int i = (blockIdx.x-102)*256 + threadIdx.x;
    if      (i < 12288){ int n=i>>6, k=i&63; float v = Wqkv[k*192+n]; if (n < 64) v *= 0.25f; wt[i] = f2b(v); }
    else if (i < 16384){ int z=i-12288; int n=z>>6, k=z&63; wt[i] = f2b(Wo[k*64+n]); }
    else if (i < 32768){ int z=i-16384; int n=z>>6, k=z&63; wt[i] = f2b(W1[k*256+n]); }
    else if (i < 49152){ int z=i-32768; int n=z>>8, k=z&255; wt[i] = f2b(W2[k*64+n]); }
    else if (i < 53248){ int z=i-49152; int n=z>>6, k=z&63; wt[i] = f2b(csWlin[k*64+n]); }
    else if (i < 57344){ int z=i-53248; int n=z>>6, k=z&63; wt[i] = f2b(rvWlin[k*64+n]); }
    else if (i < 65536){ int z=i-57344; int n=z>>7, k=z&127; wt[i] = f2b(csWupd[k*64+n]); }
    else if (i < 73728){ int z=i-65536; int n=z>>7, k=z&127; wt[i] = f2b(rvWupd[k*64+n]); }
    else if (i < 81920){ int z=i-73728; int n=z>>7, k=z&127; wt[i] = f2b(fuW1[k*64+n]); }
    else if (i < 86016){ int z=i-81920; int n=z>>6, k=z&63; wt[i] = f2b(fuW2[k*64+n]); }
}

// ---------------------------------------------------------------- CSR build: exclusive scan (parallel Hillis-Steele)
__global__ __launch_bounds__(256) void k_scan(const int* __restrict__ cnt_c, int* __restrict__ off_c, int* __restrict__ cur_c,
                                              const int* __restrict__ cnt_r, int* __restrict__ off_r, int* __restrict__ cur_r){
    const int n = (blockIdx.x==0) ? NF_ : N_;
    const int* cnt = (blockIdx.x==0) ? cnt_c : cnt_r;
    int* off = (blockIdx.x==0) ? off_c : off_r;
    int* cur = (blockIdx.x==0) ? cur_c : cur_r;
    __shared__ int part[256];
    int tid = threadIdx.x;
    int tpt = (n + 255) / 256;
    int i0 = tid * tpt;
    int s = 0;
    for (int i=0;i<tpt;++i){ int idx=i0+i; if (idx<n) s += cnt[idx]; }
    part[tid] = s;
    __syncthreads();
    #pragma unroll
    for (int d=1; d<256; d<<=1){
        int v = (tid >= d) ? part[tid-d] : 0;
        __syncthreads();
        part[tid] += v;
        __syncthreads();
    }
    int run = part[tid] - s;    // exclusive prefix of this chunk
    for (int i=0;i<tpt;++i){
        int idx = i0+i;
        if (idx < n){ off[idx] = run; cur[idx] = run; run += cnt[idx]; }
    }
    if (tid == 255) off[n] = part[255];
}

// ---------------------------------------------------------------- merged: CSR fill (blocks 0..101) + node linear (blocks 102+)
__global__ __launch_bounds__(256) void k_filllin(
    const int* __restrict__ c_src, const int* __restrict__ c_dst,
    const int* __restrict__ r_src, const int* __restrict__ r_dst,
    const float* __restrict__ mw_c, const float* __restrict__ mw_r,
    int* __restrict__ cur_c, int* __restrict__ cur_r,
    int2v* __restrict__ epack_c, int2v* __restrict__ epack_r,
    const float* __restrict__ x,
    const unsigned short* __restrict__ wTc, const float* __restrict__ bc,
    const unsigned short* __restrict__ wTr, const float* __restrict__ br,
    unsigned short* __restrict__ yc, unsigned short* __restrict__ yr,
    unsigned short* __restrict__ xg, unsigned short* __restrict__ wsb)
{
    __shared__ unsigned short XBs[4][16*72];
    __shared__ unsigned short WST[16*72];     // rows 0..7 valid (block's 8 f-means)
    if (blockIdx.x < 102){
        int i = blockIdx.x*256 + threadIdx.x;
        if (i < EC_){
            int p = atomicAdd(&cur_c[c_dst[i]], 1);
            int2v ep; ep[0] = c_src[i]; ep[1] = __float_as_int(mw_c[i]);
            epack_c[p] = ep;
        } else if (i < EC_+ER_){
            int e = i - EC_;
            int p = atomicAdd(&cur_r[r_dst[e]], 1);
            int2v ep; ep[0] = r_src[e]; ep[1] = __float_as_int(mw_r[e]);
            epack_r[p] = ep;
        }
        return;
    }
    int bid = blockIdx.x - 102;               // 0..2999
    int w = threadIdx.x>>6, l = threadIdx.x&63;
    int lr = l&15, lg = l>>4;
    unsigned short* XB = XBs[w];
    int r0 = (bid*4 + w)*16;
    int g  = r0/NF_;
    int j0 = r0%NF_;
    float fsum0 = 0.f, fsum1 = 0.f;
    #pragma unroll
    for (int i=0;i<16;++i){
        int rr = r0+i;
        int j = j0+i;
        int b = g/T_, t = g%T_, n = j/F_, f = j%F_;
        float v = x[((size_t)((b*N_+n)*F_+f)*T_ + t)*64 + l];
        unsigned short us = f2b(v);
        XB[i*72 + l] = us;
        xg[(size_t)rr*64 + l] = us;
        if (i < 8) fsum0 += v; else fsum1 += v;
    }
    {
        int nb = j0/F_;
        unsigned short u0 = f2b(fsum0*0.125f);
        unsigned short u1 = f2b(fsum1*0.125f);
        WST[(w*2+0)*72 + l] = u0;
        WST[(w*2+1)*72 + l] = u1;
        wsb[((size_t)g*N_ + nb    )*64 + l] = u0;
        wsb[((size_t)g*N_ + nb + 1)*64 + l] = u1;
    }
    __syncthreads();
    // causal GEMM (per wave)
    {
        bf16x8 a0 = *(const bf16x8*)&XB[lr*72 + lg*8];
        bf16x8 a1 = *(const bf16x8*)&XB[lr*72 + 32 + lg*8];
        f32x4 acc[4];
        #pragma unroll
        for (int ct=0;ct<4;++ct) acc[ct] = (f32x4){0.f,0.f,0.f,0.f};
        #pragma unroll
        for (int ct=0;ct<4;++ct){
            bf16x8 b0 = *(const bf16x8*)&wTc[(ct*16+lr)*64 + lg*8];
            bf16x8 b1 = *(const bf16x8*)&wTc[(ct*16+lr)*64 + 32 + lg*8];
            acc[ct] = __builtin_amdgcn_mfma_f32_16x16x32_bf16(a0, b0, acc[ct], 0,0,0);
            acc[ct] = __builtin_amdgcn_mfma_f32_16x16x32_bf16(a1, b1, acc[ct], 0,0,0);
        }
        #pragma unroll
        for (int ct=0;ct<4;++ct){
            float bv = bc[ct*16+lr];
            #pragma unroll
            for (int i=0;i<4;++i)
                yc[(size_t)(r0+lg*4+i)*64 + ct*16+lr] = f2b(acc[ct][i] + bv);
        }
    }
    // river GEMM for the block's 8 n-rows (wave 0)
    if (w == 0){
        int nb0 = ((bid*64)%NF_)/F_;
        int gb  = (bid*64)/NF_;
        bf16x8 a0 = *(const bf16x8*)&WST[lr*72 + lg*8];
        bf16x8 a1 = *(const bf16x8*)&WST[lr*72 + 32 + lg*8];
        f32x4 acc[4];
        #pragma unroll
        for (int ct=0;ct<4;++ct) acc[ct] = (f32x4){0.f,0.f,0.f,0.f};
        #pragma unroll
        for (int ct=0;ct<4;++ct){
            bf16x8 b0 = *(const bf16x8*)&wTr[(ct*16+lr)*64 + lg*8];
            bf16x8 b1 = *(const bf16x8*)&wTr[(ct*16+lr)*64 + 32 + lg*8];
            acc[ct] = __builtin_amdgcn_mfma_f32_16x16x32_bf16(a0, b0, acc[ct], 0,0,0);
            acc[ct] = __builtin_amdgcn_mfma_f32_16x16x32_bf16(a1, b1, acc[ct], 0,0,0);
        }
        if (lg < 2){
            #pragma unroll
            for (int ct=0;ct<4;++ct){
                float bv = br[ct*16+lr];
                #pragma unroll
                for (int i=0;i<4;++i)
                    yr[((size_t)gb*N_ + nb0 + lg*4+i)*64 + ct*16+lr] = f2b(acc[ct][i] + bv);
            }
        }
    }
}

// ---------------------------------------------------------------- merged gather-aggregate (bf16), packed edges.
// Pair rows sharing the same destination d across graphs (g0, g0+12): identical edge chains ->
// epack loaded ONCE for both rows, perfectly aligned interleave, zero tail divergence.
__global__ __launch_bounds__(256) void k_gaggr2(const unsigned short* __restrict__ yc,
                                                const int2v* __restrict__ epack_c,
                                                const int* __restrict__ off_c,
                                                unsigned short* __restrict__ ac,
                                                const unsigned short* __restrict__ yr,
                                                const int2v* __restrict__ epack_r,
                                                const int* __restrict__ off_r,
                                                unsigned short* __restrict__ ar){
    int l = threadIdx.x & 63;
    int w = threadIdx.x >> 6;
    const unsigned short* y; const int2v* epack; const int* off;
    unsigned short* aggr; int nseg, pid;
    if (blockIdx.x < 24000){
        int wg = (blockIdx.x & 7)*3000 + (blockIdx.x >> 3);   // XCD-chunked swizzle (24000 % 8 == 0)
        y = yc; epack = epack_c; off = off_c; aggr = ac; nseg = NF_;
        pid = wg*4 + w;                                       // 0..95999
    } else {
        int pb = blockIdx.x - 24000;
        int wg = (pb & 7)*375 + (pb >> 3);                    // 3000 % 8 == 0
        y = yr; epack = epack_r; off = off_r; aggr = ar; nseg = N_;
        pid = wg*4 + w;                                       // 0..11999
    }
    int g0 = pid / nseg;           // 0..11
    int d  = pid % nseg;
    int g1 = g0 + 12;
    int p = off[d], e = off[d+1];
    const unsigned short* yg0 = y + (size_t)g0*nseg*64 + l;
    const unsigned short* yg1 = y + (size_t)g1*nseg*64 + l;
    float acc0 = 0.f, acc1 = 0.f;
    for (; p+1 < e; p += 2){
        int2v ea = epack[p], eb = epack[p+1];
        float wa = __int_as_float(ea[1]), wb = __int_as_float(eb[1]);
        size_t oa = (size_t)ea[0]*64, ob = (size_t)eb[0]*64;
        float va0 = b2f(yg0[oa]);
        float vb0 = b2f(yg0[ob]);
        float va1 = b2f(yg1[oa]);
        float vb1 = b2f(yg1[ob]);
        acc0 += wa*va0 + wb*vb0;
        acc1 += wa*va1 + wb*vb1;
    }
    if (p < e){
        int2v ea = epack[p];
        float wa = __int_as_float(ea[1]);
        size_t oa = (size_t)ea[0]*64;
        acc0 += wa * b2f(yg0[oa]);
        acc1 += wa * b2f(yg1[oa]);
    }
    aggr[((size_t)g0*nseg + d)*64 + l] = f2b(acc0);
    aggr[((size_t)g1*nseg + d)*64 + l] = f2b(acc1);
}

// ---------------------------------------------------------------- river update: u = relu([aggr|ws] @ Wu + b)  (all bf16)
__global__ __launch_bounds__(256) void k_upd16(const unsigned short* __restrict__ aggr,
                                               const unsigned short* __restrict__ xin,
                                               const unsigned short* __restrict__ wT,  // [64 n][128 k]
                                               const float* __restrict__ bu,
                                               unsigned short* __restrict__ u){
    __shared__ unsigned short XBs[4][16*136];
    int w = threadIdx.x>>6, l = threadIdx.x&63;
    int lr = l&15, lg = l>>4;
    int lq = l>>4, lc = (l&15)*4;
    unsigned short* XB = XBs[w];
    int r0 = (blockIdx.x*4 + w)*16;
    #pragma unroll
    for (int v=0; v<4; ++v){
        int row = v*4 + lq;
        int rr = r0 + row;
        *(short4v*)&XB[row*136 + lc]      = *(const short4v*)&aggr[(size_t)rr*64 + lc];
        *(short4v*)&XB[row*136 + 64 + lc] = *(const short4v*)&xin[(size_t)rr*64 + lc];
    }
    LGKM0;
    bf16x8 a[4];
    #pragma unroll
    for (int kk=0;kk<4;++kk) a[kk] = *(const bf16x8*)&XB[lr*136 + kk*32 + lg*8];
    f32x4 acc[4];
    #pragma unroll
    for (int ct=0;ct<4;++ct) acc[ct] = (f32x4){0.f,0.f,0.f,0.f};
    #pragma unroll
    for (int ct=0;ct<4;++ct){
        #pragma unroll
        for (int kk=0;kk<4;++kk){
            bf16x8 b0 = *(const bf16x8*)&wT[(ct*16+lr)*128 + kk*32 + lg*8];
            acc[ct] = __builtin_amdgcn_mfma_f32_16x16x32_bf16(a[kk], b0, acc[ct], 0,0,0);
        }
    }
    #pragma unroll
    for (int ct=0;ct<4;++ct){
        float bv = bu[ct*16+lr];
        #pragma unroll
        for (int i=0;i<4;++i)
            u[(size_t)(r0+lg*4+i)*64 + ct*16+lr] = f2b(fmaxf(acc[ct][i] + bv, 0.f));
    }
}

// ---------------------------------------------------------------- fused causal-update + fusion MLP, 2 tiles/wave (all bf16)
__global__ __launch_bounds__(256) void k_updfus(const unsigned short* __restrict__ aggr,
                                                const unsigned short* __restrict__ xg,
                                                const unsigned short* __restrict__ wuT,  // [64][128]
                                                const float* __restrict__ bu,
                                                const unsigned short* __restrict__ wsu,
                                                const unsigned short* __restrict__ w1T,  // [64][128]
                                                const float* __restrict__ b1,
                                                const unsigned short* __restrict__ w2T,  // [64][64]
                                                const float* __restrict__ b2,
                                                unsigned short* __restrict__ fused){
    __shared__ unsigned short XBs[4][2][16*136];
    __shared__ unsigned short X2s[4][2][16*136];
    int w = threadIdx.x>>6, l = threadIdx.x&63;
    int lr = l&15, lg = l>>4;
    int lq = l>>4, lc = (l&15)*4;
    unsigned short* XB[2] = { XBs[w][0], XBs[w][1] };
    unsigned short* X2[2] = { X2s[w][0], X2s[w][1] };
    int tb = (blockIdx.x*4 + w)*32;      // 32 rows per wave, 32 | 8000 -> no g straddle
    int g  = tb/NF_;
    int n0 = (tb%NF_)/F_;                // octets: tile tt rows 0-7 -> n0+tt*2, rows 8-15 -> n0+tt*2+1
    #pragma unroll
    for (int tt=0;tt<2;++tt){
        int r0 = tb + tt*16;
        #pragma unroll
        for (int v=0; v<4; ++v){
            int row = v*4 + lq;
            int rr = r0 + row;
            *(short4v*)&XB[tt][row*136 + lc]      = *(const short4v*)&aggr[(size_t)rr*64 + lc];
            *(short4v*)&XB[tt][row*136 + 64 + lc] = *(const short4v*)&xg[(size_t)rr*64 + lc];
        }
        unsigned short wv0 = wsu[((size_t)g*N_ + n0 + tt*2    )*64 + l];
        unsigned short wv1 = wsu[((size_t)g*N_ + n0 + tt*2 + 1)*64 + l];
        #pragma unroll
        for (int i=0;i<8;++i){
            X2[tt][i*136 + 64 + l]     = wv0;
            X2[tt][(i+8)*136 + 64 + l] = wv1;
        }
    }
    LGKM0;
    // stage 1: update GEMM k=128 -> relu -> X2 cols 0..63 (both tiles)
    {
        bf16x8 a[2][4];
        #pragma unroll
        for (int tt=0;tt<2;++tt)
            #pragma unroll
            for (int kk=0;kk<4;++kk) a[tt][kk] = *(const bf16x8*)&XB[tt][lr*136 + kk*32 + lg*8];
        f32x4 acc[2][4];
        #pragma unroll
        for (int tt=0;tt<2;++tt)
            #pragma unroll
            for (int ct=0;ct<4;++ct) acc[tt][ct] = (f32x4){0.f,0.f,0.f,0.f};
        #pragma unroll
        for (int ct=0;ct<4;++ct){
            #pragma unroll
            for (int kk=0;kk<4;++kk){
                bf16x8 b0 = *(const bf16x8*)&wuT[(ct*16+lr)*128 + kk*32 + lg*8];
                #pragma unroll
                for (int tt=0;tt<2;++tt)
                    acc[tt][ct] = __builtin_amdgcn_mfma_f32_16x16x32_bf16(a[tt][kk], b0, acc[tt][ct], 0,0,0);
            }
        }
        #pragma unroll
        for (int ct=0;ct<4;++ct){
            float bv = bu[ct*16+lr];
            #pragma unroll
            for (int tt=0;tt<2;++tt)
                #pragma unroll
                for (int i=0;i<4;++i)
                    X2[tt][(lg*4+i)*136 + ct*16+lr] = f2b(fmaxf(acc[tt][ct][i] + bv, 0.f));
        }
    }
    LGKM0;
    // stage 2: fusion GEMM1 k=128 -> relu -> XB cols 0..63 (both tiles)
    {
        bf16x8 a[2][4];
        #pragma unroll
        for (int tt=0;tt<2;++tt)
            #pragma unroll
            for (int kk=0;kk<4;++kk) a[tt][kk] = *(const bf16x8*)&X2[tt][lr*136 + kk*32 + lg*8];
        f32x4 acc[2][4];
        #pragma unroll
        for (int tt=0;tt<2;++tt)
            #pragma unroll
            for (int ct=0;ct<4;++ct) acc[tt][ct] = (f32x4){0.f,0.f,0.f,0.f};
        #pragma unroll
        for (int ct=0;ct<4;++ct){
            #pragma unroll
            for (int kk=0;kk<4;++kk){
                bf16x8 b0 = *(const bf16x8*)&w1T[(ct*16+lr)*128 + kk*32 + lg*8];
                #pragma unroll
                for (int tt=0;tt<2;++tt)
                    acc[tt][ct] = __builtin_amdgcn_mfma_f32_16x16x32_bf16(a[tt][kk], b0, acc[tt][ct], 0,0,0);
            }
        }
        #pragma unroll
        for (int ct=0;ct<4;++ct){
            float bv = b1[ct*16+lr];
            #pragma unroll
            for (int tt=0;tt<2;++tt)
                #pragma unroll
                for (int i=0;i<4;++i)
                    XB[tt][(lg*4+i)*136 + ct*16+lr] = f2b(fmaxf(acc[tt][ct][i] + bv, 0.f));
        }
    }
    LGKM0;
    // stage 3: fusion GEMM2 k=64 -> fused (both tiles)
    {
        bf16x8 h0[2], h1[2];
        #pragma unroll
        for (int tt=0;tt<2;++tt){
            h0[tt] = *(const bf16x8*)&XB[tt][lr*136 + lg*8];
            h1[tt] = *(const bf16x8*)&XB[tt][lr*136 + 32 + lg*8];
        }
        f32x4 acc[2][4];
        #pragma unroll
        for (int tt=0;tt<2;++tt)
            #pragma unroll
            for (int ct=0;ct<4;++ct) acc[tt][ct] = (f32x4){0.f,0.f,0.f,0.f};
        #pragma unroll
        for (int ct=0;ct<4;++ct){
            bf16x8 b0 = *(const bf16x8*)&w2T[(ct*16+lr)*64 + lg*8];
            bf16x8 b1v= *(const bf16x8*)&w2T[(ct*16+lr)*64 + 32 + lg*8];
            #pragma unroll
            for (int tt=0;tt<2;++tt){
                acc[tt][ct] = __builtin_amdgcn_mfma_f32_16x16x32_bf16(h0[tt], b0, acc[tt][ct], 0,0,0);
                acc[tt][ct] = __builtin_amdgcn_mfma_f32_16x16x32_bf16(h1[tt], b1v, acc[tt][ct], 0,0,0);
            }
        }
        #pragma unroll
        for (int ct=0;ct<4;++ct){
            float bv = b2[ct*16+lr];
            #pragma unroll
            for (int tt=0;tt<2;++tt)
                #pragma unroll
                for (int i=0;i<4;++i)
                    fused[(size_t)(tb + tt*16 + lg*4+i)*64 + ct*16+lr] = f2b(acc[tt][ct][i] + bv);
        }
    }
}

// ---------------------------------------------------------------- MFMA temporal transformer: 4 waves, 2 seqs/wave, 12-row SC
// Vectorized staging + cvt_pk conversions (no setprio — measured neutral/negative).
#define XSTR 72    // XB stride (shorts); LN-out / V^T / O staging (16 rows)
#define SSTR 136   // SC stride (shorts): Q 0-63, K 64-127; 12 rows/seq + tail pad; aliased as HID
#define SCSZ (12*SSTR)

__global__ __launch_bounds__(256) void k_xformer(
    const unsigned short* __restrict__ fused,
    const unsigned short* __restrict__ wtq,   // [192][64], Q-part pre-scaled 0.25
    const unsigned short* __restrict__ wto,   // [64][64]
    const unsigned short* __restrict__ wt1,   // [256][64]
    const unsigned short* __restrict__ wt2,   // [64][256]
    const float* __restrict__ bqkv, const float* __restrict__ bo,
    const float* __restrict__ fb1,  const float* __restrict__ fb2,
    const float* __restrict__ ln1g, const float* __restrict__ ln1b,
    const float* __restrict__ ln2g, const float* __restrict__ ln2b,
    float* __restrict__ out)
{
    __shared__ unsigned short XBs[4][2][16*XSTR];
    __shared__ unsigned short SCmem[8*SCSZ + 544];   // 12-row slices + tail pad for benign row-12..15 reads

    int w  = threadIdx.x >> 6;
    int l  = threadIdx.x & 63;
    int lr = l & 15;
    int lg = l >> 4;

    unsigned short* XBp[2] = { XBs[w][0], XBs[w][1] };
    unsigned short* SCp[2] = { &SCmem[(w*2+0)*SCSZ], &SCmem[(w*2+1)*SCSZ] };

    int gbase = (blockIdx.x*4 + w)*2;

    // ---- stage fused rows into SC (vectorized: 3 x 128B row-loads per seq) ----
    #pragma unroll
    for (int sq=0;sq<2;++sq){
        int gs = gbase + sq;
        int bb = gs / NF_, j = gs % NF_;
        const unsigned short* fp = fused + ((size_t)bb*T_*NF_ + j)*64;
        #pragma unroll
        for (int ps=0; ps<3; ++ps){
            int t = ps*4 + lg;
            *(short4v*)&SCp[sq][t*SSTR + lr*4] = *(const short4v*)&fp[(size_t)t*NF_*64 + lr*4];
        }
    }
    LGKM0;

    // ---- read C-layout fragments from LDS ----
    float res[2][4][4];
    #pragma unroll
    for (int sq=0;sq<2;++sq)
        #pragma unroll
        for (int nt=0;nt<4;++nt)
            #pragma unroll
            for (int i=0;i<4;++i){
                int t = lg*4+i;
                res[sq][nt][i] = (t < 12) ? b2f(SCp[sq][t*SSTR + nt*16 + lr]) : 0.f;
            }

    // LN1 -> XB (both seqs), packed conversions
    #pragma unroll
    for (int sq=0;sq<2;++sq){
        float sm[4], sqr[4];
        #pragma unroll
        for (int i=0;i<4;++i){
            sm[i]  = res[sq][0][i]+res[sq][1][i]+res[sq][2][i]+res[sq][3][i];
            sqr[i] = res[sq][0][i]*res[sq][0][i]+res[sq][1][i]*res[sq][1][i]
                   + res[sq][2][i]*res[sq][2][i]+res[sq][3][i]*res[sq][3][i];
        }
        #pragma unroll
        for (int m=1;m<16;m<<=1){
            #pragma unroll
            for (int i=0;i<4;++i){
                sm[i]  += __shfl_xor(sm[i], m, 64);
                sqr[i] += __shfl_xor(sqr[i], m, 64);
            }
        }
        float mnv[4], rsv[4];
        #pragma unroll
        for (int i=0;i<4;++i){
            mnv[i] = sm[i]*(1.0f/64.0f);
            float var = sqr[i]*(1.0f/64.0f) - mnv[i]*mnv[i];
            rsv[i] = rsqrtf(var + 1e-5f);
        }
        #pragma unroll
        for (int nt=0;nt<4;++nt){
            float gg = ln1g[nt*16+lr], oo = ln1b[nt*16+lr];
            float w0 = (res[sq][nt][0]-mnv[0])*rsv[0]*gg + oo;
            float w1 = (res[sq][nt][1]-mnv[1])*rsv[1]*gg + oo;
            float w2 = (res[sq][nt][2]-mnv[2])*rsv[2]*gg + oo;
            float w3 = (res[sq][nt][3]-mnv[3])*rsv[3]*gg + oo;
            unsigned u01 = cpk(w0,w1), u23 = cpk(w2,w3);
            XBp[sq][(lg*4+0)*XSTR + nt*16 + lr] = (unsigned short)u01;
            XBp[sq][(lg*4+1)*XSTR + nt*16 + lr] = (unsigned short)(u01>>16);
            XBp[sq][(lg*4+2)*XSTR + nt*16 + lr] = (unsigned short)u23;
            XBp[sq][(lg*4+3)*XSTR + nt*16 + lr] = (unsigned short)(u23>>16);
        }
    }
    LGKM0;

    // QKV GEMM: Q,K -> SC (rows<12); V^T -> XB (shared weight frags), packed conversions
    {
        bf16x8 a0[2], a1[2];
        #pragma unroll
        for (int sq=0;sq<2;++sq){
            a0[sq] = *(const bf16x8*)&XBp[sq][lr*XSTR + 0*32 + lg*8];
            a1[sq] = *(const bf16x8*)&XBp[sq][lr*XSTR + 1*32 + lg*8];
        }
        LGKM0;   // a-frags in regs before V overwrites XB
        #pragma unroll
        for (int p=0;p<3;++p){
            f32x4 acc[2][4];
            #pragma unroll
            for (int sq=0;sq<2;++sq)
                #pragma unroll
                for (int c=0;c<4;++c) acc[sq][c] = (f32x4){0.f,0.f,0.f,0.f};
            #pragma unroll
            for (int c=0;c<4;++c){
                int ct = p*4 + c;
                bf16x8 b0 = *(const bf16x8*)&wtq[(ct*16+lr)*64 + 0*32 + lg*8];
                bf16x8 b1v= *(const bf16x8*)&wtq[(ct*16+lr)*64 + 1*32 + lg*8];
                #pragma unroll
                for (int sq=0;sq<2;++sq){
                    acc[sq][c] = __builtin_amdgcn_mfma_f32_16x16x32_bf16(a0[sq], b0, acc[sq][c], 0,0,0);
                    acc[sq][c] = __builtin_amdgcn_mfma_f32_16x16x32_bf16(a1[sq], b1v, acc[sq][c], 0,0,0);
                }
            }
            if (p < 2){
                if (lg < 3){
                    #pragma unroll
                    for (int c=0;c<4;++c){
                        int ct = p*4 + c;
                        float bv = bqkv[ct*16+lr];
                        if (p == 0) bv *= 0.25f;
                        #pragma unroll
                        for (int sq=0;sq<2;++sq){
                            unsigned u01 = cpk(acc[sq][c][0]+bv, acc[sq][c][1]+bv);
                            unsigned u23 = cpk(acc[sq][c][2]+bv, acc[sq][c][3]+bv);
                            SCp[sq][(lg*4+0)*SSTR + p*64 + c*16 + lr] = (unsigned short)u01;
                            SCp[sq][(lg*4+1)*SSTR + p*64 + c*16 + lr] = (unsigned short)(u01>>16);
                            SCp[sq][(lg*4+2)*SSTR + p*64 + c*16 + lr] = (unsigned short)u23;
                            SCp[sq][(lg*4+3)*SSTR + p*64 + c*16 + lr] = (unsigned short)(u23>>16);
                        }
                    }
                }
            } else {
                #pragma unroll
                for (int c=0;c<4;++c){
                    float bv = bqkv[128 + c*16 + lr];
                    #pragma unroll
                    for (int sq=0;sq<2;++sq){
                        uint2v vv2;
                        vv2[0] = cpk(acc[sq][c][0]+bv, acc[sq][c][1]+bv);
                        vv2[1] = cpk(acc[sq][c][2]+bv, acc[sq][c][3]+bv);
                        *(uint2v*)&XBp[sq][lr*XSTR + c*16 + lg*4] = vv2;   // VT'[d=c*16+lr][t=lg*4..+3]
                    }
                }
            }
        }
    }
    LGKM0;

    // MFMA attention per head, both seqs (packed P and O conversions)
    {
        const bf16x8 bz = (bf16x8){0,0,0,0,0,0,0,0};
        #pragma unroll
        for (int hd=0; hd<4; ++hd){
            #pragma unroll
            for (int sq=0;sq<2;++sq){
                bf16x8 ak = bz, bq = bz;
                if (lg < 2){
                    ak = *(const bf16x8*)&SCp[sq][lr*SSTR + 64 + hd*16 + lg*8];
                    bq = *(const bf16x8*)&SCp[sq][lr*SSTR +      hd*16 + lg*8];
                }
                f32x4 st = __builtin_amdgcn_mfma_f32_16x16x32_bf16(ak, bq, (f32x4){0.f,0.f,0.f,0.f}, 0,0,0);
                float s0=st[0], s1v=st[1], s2=st[2], s3=st[3];
                if (lg == 3){ s0=s1v=s2=s3=-1e30f; }
                float mx = fmaxf(fmaxf(s0,s1v), fmaxf(s2,s3));
                mx = fmaxf(mx, __shfl_xor(mx, 16, 64));
                mx = fmaxf(mx, __shfl_xor(mx, 32, 64));
                float p0 = __expf(s0-mx), p1 = __expf(s1v-mx), p2 = __expf(s2-mx), p3 = __expf(s3-mx);
                float den = p0+p1+p2+p3;
                den += __shfl_xor(den, 16, 64);
                den += __shfl_xor(den, 32, 64);
                float inv = __builtin_amdgcn_rcpf(den);
                float q0 = __shfl_down(p0, 16, 64), q1 = __shfl_down(p1, 16, 64);
                float q2 = __shfl_down(p2, 16, 64), q3 = __shfl_down(p3, 16, 64);
                union { uint4v u; bf16x8 b; } pu;
                {
                    float lo0 = (lg==0)? p0 : (lg==1)? q0 : 0.f;
                    float lo1 = (lg==0)? p1 : (lg==1)? q1 : 0.f;
                    float lo2 = (lg==0)? p2 : (lg==1)? q2 : 0.f;
                    float lo3 = (lg==0)? p3 : (lg==1)? q3 : 0.f;
                    float hi0 = (lg==0)? q0 : 0.f;
                    float hi1 = (lg==0)? q1 : 0.f;
                    float hi2 = (lg==0)? q2 : 0.f;
                    float hi3 = (lg==0)? q3 : 0.f;
                    pu.u[0] = cpk(lo0, lo1);
                    pu.u[1] = cpk(lo2, lo3);
                    pu.u[2] = cpk(hi0, hi1);
                    pu.u[3] = cpk(hi2, hi3);
                }
                bf16x8 pb = pu.b;
                bf16x8 av = bz;
                if (lg < 2) av = *(const bf16x8*)&XBp[sq][lr*XSTR + hd*16 + lg*8];
                f32x4 ot = __builtin_amdgcn_mfma_f32_16x16x32_bf16(av, pb, (f32x4){0.f,0.f,0.f,0.f}, 0,0,0);
                uint2v ow2;
                ow2[0] = cpk(ot[0]*inv, ot[1]*inv);
                ow2[1] = cpk(ot[2]*inv, ot[3]*inv);
                *(uint2v*)&XBp[sq][lr*XSTR + hd*16 + lg*4] = ow2;
            }
        }
    }
    LGKM0;

    // proj + residual -> s1 (shared weight frags)
    float s1[2][4][4];
    {
        bf16x8 a0[2], a1[2];
        #pragma unroll
        for (int sq=0;sq<2;++sq){
            a0[sq] = *(const bf16x8*)&XBp[sq][lr*XSTR + 0*32 + lg*8];
            a1[sq] = *(const bf16x8*)&XBp[sq][lr*XSTR + 1*32 + lg*8];
        }
        f32x4 pacc[2][4];
        #pragma unroll
        for (int sq=0;sq<2;++sq)
            #pragma unroll
            for (int ct=0;ct<4;++ct) pacc[sq][ct] = (f32x4){0.f,0.f,0.f,0.f};
        #pragma unroll
        for (int ct=0;ct<4;++ct){
            bf16x8 b0 = *(const bf16x8*)&wto[(ct*16+lr)*64 + 0*32 + lg*8];
            bf16x8 b1v= *(const bf16x8*)&wto[(ct*16+lr)*64 + 1*32 + lg*8];
            #pragma unroll
            for (int sq=0;sq<2;++sq){
                pacc[sq][ct] = __builtin_amdgcn_mfma_f32_16x16x32_bf16(a0[sq], b0, pacc[sq][ct], 0,0,0);
                pacc[sq][ct] = __builtin_amdgcn_mfma_f32_16x16x32_bf16(a1[sq], b1v, pacc[sq][ct], 0,0,0);
            }
        }
        #pragma unroll
        for (int sq=0;sq<2;++sq)
            #pragma unroll
            for (int ct=0;ct<4;++ct){
                float bv = bo[ct*16+lr];
                #pragma unroll
                for (int i=0;i<4;++i)
                    s1[sq][ct][i] = res[sq][ct][i] + pacc[sq][ct][i] + bv;
            }
    }

    // LN2 -> XB (both seqs), packed conversions
    #pragma unroll
    for (int sq=0;sq<2;++sq){
        float sm[4], sqr[4];
        #pragma unroll
        for (int i=0;i<4;++i){
            sm[i]  = s1[sq][0][i]+s1[sq][1][i]+s1[sq][2][i]+s1[sq][3][i];
            sqr[i] = s1[sq][0][i]*s1[sq][0][i]+s1[sq][1][i]*s1[sq][1][i]
                   + s1[sq][2][i]*s1[sq][2][i]+s1[sq][3][i]*s1[sq][3][i];
        }
        #pragma unroll
        for (int m=1;m<16;m<<=1){
            #pragma unroll
            for (int i=0;i<4;++i){
                sm[i]  += __shfl_xor(sm[i], m, 64);
                sqr[i] += __shfl_xor(sqr[i], m, 64);
            }
        }
        float mnv[4], rsv[4];
        #pragma unroll
        for (int i=0;i<4;++i){
            mnv[i] = sm[i]*(1.0f/64.0f);
            float var = sqr[i]*(1.0f/64.0f) - mnv[i]*mnv[i];
            rsv[i] = rsqrtf(var + 1e-5f);
        }
        #pragma unroll
        for (int nt=0;nt<4;++nt){
            float gg = ln2g[nt*16+lr], oo = ln2b[nt*16+lr];
            float w0 = (s1[sq][nt][0]-mnv[0])*rsv[0]*gg + oo;
            float w1 = (s1[sq][nt][1]-mnv[1])*rsv[1]*gg + oo;
            float w2 = (s1[sq][nt][2]-mnv[2])*rsv[2]*gg + oo;
            float w3 = (s1[sq][nt][3]-mnv[3])*rsv[3]*gg + oo;
            unsigned u01 = cpk(w0,w1), u23 = cpk(w2,w3);
            XBp[sq][(lg*4+0)*XSTR + nt*16 + lr] = (unsigned short)u01;
            XBp[sq][(lg*4+1)*XSTR + nt*16 + lr] = (unsigned short)(u01>>16);
            XBp[sq][(lg*4+2)*XSTR + nt*16 + lr] = (unsigned short)u23;
            XBp[sq][(lg*4+3)*XSTR + nt*16 + lr] = (unsigned short)(u23>>16);
        }
    }
    LGKM0;

    // FFN: two 128-wide halves; HID stores guarded rows<12; packed conversions
    f32x4 oacc[2][4];
    #pragma unroll
    for (int sq=0;sq<2;++sq)
        #pragma unroll
        for (int ct=0;ct<4;++ct) oacc[sq][ct] = (f32x4){0.f,0.f,0.f,0.f};
    {
        bf16x8 a0[2], a1[2];
        #pragma unroll
        for (int sq=0;sq<2;++sq){
            a0[sq] = *(const bf16x8*)&XBp[sq][lr*XSTR + 0*32 + lg*8];
            a1[sq] = *(const bf16x8*)&XBp[sq][lr*XSTR + 1*32 + lg*8];
        }
        #pragma unroll
        for (int half=0; half<2; ++half){
            LGKM0;   // HID region reuse guard
            #pragma unroll
            for (int q=0; q<2; ++q){
                f32x4 facc[2][4];
                #pragma unroll
                for (int sq=0;sq<2;++sq)
                    #pragma unroll
                    for (int c=0;c<4;++c) facc[sq][c] = (f32x4){0.f,0.f,0.f,0.f};
                #pragma unroll
                for (int c=0;c<4;++c){
                    int ct = half*8 + q*4 + c;
                    bf16x8 b0 = *(const bf16x8*)&wt1[(ct*16+lr)*64 + 0*32 + lg*8];
                    bf16x8 b1v= *(const bf16x8*)&wt1[(ct*16+lr)*64 + 1*32 + lg*8];
                    #pragma unroll
                    for (int sq=0;sq<2;++sq){
                        facc[sq][c] = __builtin_amdgcn_mfma_f32_16x16x32_bf16(a0[sq], b0, facc[sq][c], 0,0,0);
                        facc[sq][c] = __builtin_amdgcn_mfma_f32_16x16x32_bf16(a1[sq], b1v, facc[sq][c], 0,0,0);
                    }
                }
                if (lg < 3){
                    #pragma unroll
                    for (int c=0;c<4;++c){
                        int ct = half*8 + q*4 + c;
                        float bv = fb1[ct*16+lr];
                        #pragma unroll
                        for (int sq=0;sq<2;++sq){
                            float hv[4];
                            #pragma unroll
                            for (int i=0;i<4;++i){
                                float xv = facc[sq][c][i] + bv;
                                float x2 = xv*xv;
                                float z  = xv*(1.5957691216f + 0.0713548162f*x2);
                                float ez = __expf(-z);
                                hv[i] = xv * __builtin_amdgcn_rcpf(1.0f + ez);
                            }
                            unsigned u01 = cpk(hv[0],hv[1]), u23 = cpk(hv[2],hv[3]);
                            SCp[sq][(lg*4+0)*SSTR + (q*4+c)*16 + lr] = (unsigned short)u01;
                            SCp[sq][(lg*4+1)*SSTR + (q*4+c)*16 + lr] = (unsigned short)(u01>>16);
                            SCp[sq][(lg*4+2)*SSTR + (q*4+c)*16 + lr] = (unsigned short)u23;
                            SCp[sq][(lg*4+3)*SSTR + (q*4+c)*16 + lr] = (unsigned short)(u23>>16);
                        }
                    }
                }
            }
            LGKM0;
            #pragma unroll
            for (int ks=0;ks<4;++ks){
                bf16x8 af[2];
                #pragma unroll
                for (int sq=0;sq<2;++sq)
                    af[sq] = *(const bf16x8*)&SCp[sq][lr*SSTR + ks*32 + lg*8];
                #pragma unroll
                for (int ct=0;ct<4;++ct){
                    bf16x8 bfr = *(const bf16x8*)&wt2[(ct*16+lr)*256 + half*128 + ks*32 + lg*8];
                    #pragma unroll
                    for (int sq=0;sq<2;++sq)
                        oacc[sq][ct] = __builtin_amdgcn_mfma_f32_16x16x32_bf16(af[sq], bfr, oacc[sq][ct], 0,0,0);
                }
            }
        }
    }

    // residual + mean over t (both seqs)
    #pragma unroll
    for (int sq=0;sq<2;++sq)
        #pragma unroll
        for (int ct=0;ct<4;++ct){
            float bv = fb2[ct*16+lr];
            float part = 0.f;
            #pragma unroll
            for (int i=0;i<4;++i){
                if (lg*4+i < 12) part += s1[sq][ct][i] + oacc[sq][ct][i] + bv;
            }
            part += __shfl_xor(part, 16, 64);
            part += __shfl_xor(part, 32, 64);
            if (lg == 0) out[(size_t)(gbase+sq)*64 + ct*16 + lr] = part*(1.0f/12.0f);
        }
}

// ----------------------------------------------------------------
extern "C" void kernel_launch(void* const* d_in, const int* in_sizes, int n_in,
                              void* d_out, int out_size, void* d_ws, size_t ws_size,
                              hipStream_t stream) {
    const float* x      = (const float*)d_in[0];
    const int*   r_ei   = (const int*)  d_in[1];
    const float* r_ea   = (const float*)d_in[2];
    const int*   c_ei   = (const int*)  d_in[3];
    const float* c_ew   = (const float*)d_in[4];
    const float* rvWlin = (const float*)d_in[5];
    const float* rvblin = (const float*)d_in[6];
    const float* rvWupd = (const float*)d_in[7];
    const float* rvbupd = (const float*)d_in[8];
    const float* rvgate = (const float*)d_in[9];
    const float* rvlw   = (const float*)d_in[10];
    const float* csWlin = (const float*)d_in[11];
    const float* csblin = (const float*)d_in[12];
    const float* csWupd = (const float*)d_in[13];
    const float* csbupd = (const float*)d_in[14];
    const float* csgate = (const float*)d_in[15];
    const float* cslw   = (const float*)d_in[16];
    const float* fuW1   = (const float*)d_in[17];
    const float* fub1   = (const float*)d_in[18];
    const float* fuW2   = (const float*)d_in[19];
    const float* fub2   = (const float*)d_in[20];
    const float* ln1g   = (const float*)d_in[21];
    const float* ln1b   = (const float*)d_in[22];
    const float* ln2g   = (const float*)d_in[23];
    const float* ln2b   = (const float*)d_in[24];
    const float* Wqkv   = (const float*)d_in[25];
    const float* bqkv   = (const float*)d_in[26];
    const float* Wo     = (const float*)d_in[27];
    const float* bo     = (const float*)d_in[28];
    const float* ffW1   = (const float*)d_in[29];
    const float* ffb1   = (const float*)d_in[30];
    const float* ffW2   = (const float*)d_in[31];
    const float* ffb2   = (const float*)d_in[32];

    float* wsp  = (float*)d_ws;
    unsigned short* FNY_b = (unsigned short*)wsp;                    // causal y bf16, then FUSED bf16
    unsigned short* FNA_b = (unsigned short*)(wsp + 12288000);       // causal aggr bf16
    unsigned short* XG_b  = (unsigned short*)(wsp + 12288000 + 6144000); // gathered x bf16
    unsigned short* WS_b  = (unsigned short*)(wsp + 24576000);       // watershed mean bf16
    unsigned short* WSY_b = (unsigned short*)(wsp + 26112000);       // river y bf16
    unsigned short* WSA_b = (unsigned short*)(wsp + 27648000);       // river aggr bf16
    float* WSU  = wsp + 29184000;                                    // CSR scratch, then river u bf16
    unsigned short* WSU_b = (unsigned short*)WSU;
    unsigned short* wt = (unsigned short*)(wsp + 30720000);
    float* outp = (float*)d_out;

    int* ibase  = (int*)WSU;
    int* cnt_c  = ibase;
    int* cnt_r  = ibase + 8000;
    int* off_c  = ibase + 9000;
    int* off_r  = ibase + 17001;
    int* cur_c  = ibase + 18002;
    int* cur_r  = ibase + 26002;
    float* mw_c = (float*)(ibase + 53002);
    float* mw_r = (float*)(ibase + 77002);
    int2v* epack_c = (int2v*)(ibase + 80000);   // 24000 x 8B
    int2v* epack_r = (int2v*)(ibase + 128000);  //  2000 x 8B (clobbered later by river u -> OK, consumers done)

    const int* c_src = c_ei;
    const int* c_dst = c_ei + EC_;
    const int* r_src = r_ei;
    const int* r_dst = r_ei + ER_;

    hipMemsetAsync(cnt_c, 0, 9000*sizeof(int), stream);

    // merged: mw+histogram (102 blocks) + bf16 weight panels (336 blocks)
    k_prephist<<<438, 256, 0, stream>>>(c_dst, r_dst, c_ew, cslw, csgate,
                                        r_ea, rvlw, rvgate, mw_c, mw_r, cnt_c, cnt_r,
                                        Wqkv, Wo, ffW1, ffW2, csWlin, rvWlin, csWupd, rvWupd,
                                        fuW1, fuW2, wt);
    k_scan<<<2, 256, 0, stream>>>(cnt_c, off_c, cur_c, cnt_r, off_r, cur_r);

    // merged: CSR fill (102 blocks) + node linear (3000 blocks)
    k_filllin<<<3102, 256, 0, stream>>>(c_src, c_dst, r_src, r_dst, mw_c, mw_r,
                                        cur_c, cur_r, epack_c, epack_r,
                                        x, wt+49152, csblin, wt+53248, rvblin,
                                        FNY_b, WSY_b, XG_b, WS_b);

    // merged gather-aggregation (same-d cross-graph pairing: shared epack, aligned chains)
    k_gaggr2<<<27000, 256, 0, stream>>>(FNY_b, epack_c, off_c, FNA_b,
                                        WSY_b, epack_r, off_r, WSA_b);

    // river update (clobbers CSR scratch -> OK, consumers done)
    k_upd16<<<375, 256, 0, stream>>>(WSA_b, WS_b, wt+65536, rvbupd, WSU_b);

    // fused causal update + fusion MLP, 2 tiles/wave -> FUSED bf16 (into FNY region)
    k_updfus<<<1500, 256, 0, stream>>>(FNA_b, XG_b, wt+57344, csbupd, WSU_b,
                                       wt+73728, fub1, wt+81920, fub2, FNY_b);

    // 2-seq-per-wave MFMA transformer (cvt_pk, no setprio)
    k_xformer<<<2000, 256, 0, stream>>>(FNY_b,
                                        wt, wt+12288, wt+16384, wt+32768,
                                        bqkv, bo, ffb1, ffb2,
                                        ln1g, ln1b, ln2g, ln2b,
                                        outp);
}

// Round 24
// 255.033 us; speedup vs baseline: 1.0908x; 1.0397x over previous
//
#include <hip/hip_runtime.h>
#include <math.h>

#define B_ 2
#define N_ 1000
#define F_ 8
#define T_ 12
#define H_ 64
#define G_ 24      // B*T
#define NF_ 8000   // N*F
#define ER_ 2000
#define EC_ 24000

typedef short bf16x8 __attribute__((ext_vector_type(8)));
typedef short short4v __attribute__((ext_vector_type(4)));
typedef float f32x4 __attribute__((ext_vector_type(4)));
typedef unsigned int uint2v __attribute__((ext_vector_type(2)));
typedef unsigned int uint4v __attribute__((ext_vector_type(4)));
typedef int int2v __attribute__((ext_vector_type(2)));

#define LGKM0 do { asm volatile("s_waitcnt lgkmcnt(0)" ::: "memory"); __builtin_amdgcn_sched_barrier(0); } while(0)

__device__ __forceinline__ float sigf(float x){ return 1.0f/(1.0f+__expf(-x)); }

// f32 -> bf16 (RNE)
__device__ __forceinline__ unsigned short f2b(float f){
    unsigned u = __float_as_uint(f);
    unsigned r = (u + 0x7FFFu + ((u >> 16) & 1u)) >> 16;
    return (unsigned short)r;
}
__device__ __forceinline__ float b2f(unsigned short u){
    return __uint_as_float(((unsigned)u) << 16);
}
// packed 2xf32 -> 2xbf16 in one VALU op (gfx950)
__device__ __forceinline__ unsigned cpk(float lo, float hi){
    unsigned r;
    asm("v_cvt_pk_bf16_f32 %0, %1, %2" : "=v"(r) : "v"(lo), "v"(hi));
    return r;
}

// ---------------------------------------------------------------- merged: mw+histogram (blocks 0..101) + weight prep (blocks 102+)
__global__ __launch_bounds__(256) void k_prephist(
    const int* __restrict__ c_dst, const int* __restrict__ r_dst,
    const float* __restrict__ c_ew, const float* __restrict__ c_lw, const float* __restrict__ c_gate,
    const float* __restrict__ r_ew, const float* __restrict__ r_lw, const float* __restrict__ r_gate,
    float* __restrict__ mw_c, float* __restrict__ mw_r,
    int* __restrict__ cnt_c, int* __restrict__ cnt_r,
    const float* __restrict__ Wqkv, const float* __restrict__ Wo,
    const float* __restrict__ W1,   const float* __restrict__ W2,
    const float* __restrict__ csWlin, const float* __restrict__ rvWlin,
    const float* __restrict__ csWupd, const float* __restrict__ rvWupd,
    const float* __restrict__ fuW1,   const float* __restrict__ fuW2,
    unsigned short* __restrict__ wt)
{
    if (blockIdx.x < 102){
        int i = blockIdx.x*256 + threadIdx.x;
        if (i < EC_){
            float gs = sigf(c_gate[0]);
            mw_c[i] = gs*c_ew[i] + (1.f-gs)*sigf(c_lw[i]);
            atomicAdd(&cnt_c[c_dst[i]], 1);
        } else if (i < EC_+ER_){
            int e = i - EC_;
            float gs = sigf(r_gate[0]);
            mw_r[e] = gs*r_ew[e] + (1.f-gs)*sigf(r_lw[e]);
            atomicAdd(&cnt_r[r_dst[e]], 1);
        }
        return;
    }
    int i = (blockIdx.x-102)*256 + threadIdx.x;
    if      (i < 12288){ int n=i>>6, k=i&63; float v = Wqkv[k*192+n]; if (n < 64) v *= 0.25f; wt[i] = f2b(v); }
    else if (i < 16384){ int z=i-12288; int n=z>>6, k=z&63; wt[i] = f2b(Wo[k*64+n]); }
    else if (i < 32768){ int z=i-16384; int n=z>>6, k=z&63; wt[i] = f2b(W1[k*256+n]); }
    else if (i < 49152){ int z=i-32768; int n=z>>8, k=z&255; wt[i] = f2b(W2[k*64+n]); }
    else if (i < 53248){ int z=i-49152; int n=z>>6, k=z&63; wt[i] = f2b(csWlin[k*64+n]); }
    else if (i < 57344){ int z=i-53248; int n=z>>6, k=z&63; wt[i] = f2b(rvWlin[k*64+n]); }
    else if (i < 65536){ int z=i-57344; int n=z>>7, k=z&127; wt[i] = f2b(csWupd[k*64+n]); }
    else if (i < 73728){ int z=i-65536; int n=z>>7, k=z&127; wt[i] = f2b(rvWupd[k*64+n]); }
    else if (i < 81920){ int z=i-73728; int n=z>>7, k=z&127; wt[i] = f2b(fuW1[k*64+n]); }
    else if (i < 86016){ int z=i-81920; int n=z>>6, k=z&63; wt[i] = f2b(fuW2[k*64+n]); }
}

// ---------------------------------------------------------------- CSR build: exclusive scan (parallel Hillis-Steele)
__global__ __launch_bounds__(256) void k_scan(const int* __restrict__ cnt_c, int* __restrict__ off_c, int* __restrict__ cur_c,
                                              const int* __restrict__ cnt_r, int* __restrict__ off_r, int* __restrict__ cur_r){
    const int n = (blockIdx.x==0) ? NF_ : N_;
    const int* cnt = (blockIdx.x==0) ? cnt_c : cnt_r;
    int* off = (blockIdx.x==0) ? off_c : off_r;
    int* cur = (blockIdx.x==0) ? cur_c : cur_r;
    __shared__ int part[256];
    int tid = threadIdx.x;
    int tpt = (n + 255) / 256;
    int i0 = tid * tpt;
    int s = 0;
    for (int i=0;i<tpt;++i){ int idx=i0+i; if (idx<n) s += cnt[idx]; }
    part[tid] = s;
    __syncthreads();
    #pragma unroll
    for (int d=1; d<256; d<<=1){
        int v = (tid >= d) ? part[tid-d] : 0;
        __syncthreads();
        part[tid] += v;
        __syncthreads();
    }
    int run = part[tid] - s;    // exclusive prefix of this chunk
    for (int i=0;i<tpt;++i){
        int idx = i0+i;
        if (idx < n){ off[idx] = run; cur[idx] = run; run += cnt[idx]; }
    }
    if (tid == 255) off[n] = part[255];
}

// ---------------------------------------------------------------- merged: CSR fill (blocks 0..101) + node linear (blocks 102+)
__global__ __launch_bounds__(256) void k_filllin(
    const int* __restrict__ c_src, const int* __restrict__ c_dst,
    const int* __restrict__ r_src, const int* __restrict__ r_dst,
    const float* __restrict__ mw_c, const float* __restrict__ mw_r,
    int* __restrict__ cur_c, int* __restrict__ cur_r,
    int2v* __restrict__ epack_c, int2v* __restrict__ epack_r,
    const float* __restrict__ x,
    const unsigned short* __restrict__ wTc, const float* __restrict__ bc,
    const unsigned short* __restrict__ wTr, const float* __restrict__ br,
    unsigned short* __restrict__ yc, unsigned short* __restrict__ yr,
    unsigned short* __restrict__ xg, unsigned short* __restrict__ wsb)
{
    __shared__ unsigned short XBs[4][16*72];
    __shared__ unsigned short WST[16*72];     // rows 0..7 valid (block's 8 f-means)
    if (blockIdx.x < 102){
        int i = blockIdx.x*256 + threadIdx.x;
        if (i < EC_){
            int p = atomicAdd(&cur_c[c_dst[i]], 1);
            int2v ep; ep[0] = c_src[i]; ep[1] = __float_as_int(mw_c[i]);
            epack_c[p] = ep;
        } else if (i < EC_+ER_){
            int e = i - EC_;
            int p = atomicAdd(&cur_r[r_dst[e]], 1);
            int2v ep; ep[0] = r_src[e]; ep[1] = __float_as_int(mw_r[e]);
            epack_r[p] = ep;
        }
        return;
    }
    int bid = blockIdx.x - 102;               // 0..2999
    int w = threadIdx.x>>6, l = threadIdx.x&63;
    int lr = l&15, lg = l>>4;
    unsigned short* XB = XBs[w];
    int r0 = (bid*4 + w)*16;
    int g  = r0/NF_;
    int j0 = r0%NF_;
    float fsum0 = 0.f, fsum1 = 0.f;
    #pragma unroll
    for (int i=0;i<16;++i){
        int rr = r0+i;
        int j = j0+i;
        int b = g/T_, t = g%T_, n = j/F_, f = j%F_;
        float v = x[((size_t)((b*N_+n)*F_+f)*T_ + t)*64 + l];
        unsigned short us = f2b(v);
        XB[i*72 + l] = us;
        xg[(size_t)rr*64 + l] = us;
        if (i < 8) fsum0 += v; else fsum1 += v;
    }
    {
        int nb = j0/F_;
        unsigned short u0 = f2b(fsum0*0.125f);
        unsigned short u1 = f2b(fsum1*0.125f);
        WST[(w*2+0)*72 + l] = u0;
        WST[(w*2+1)*72 + l] = u1;
        wsb[((size_t)g*N_ + nb    )*64 + l] = u0;
        wsb[((size_t)g*N_ + nb + 1)*64 + l] = u1;
    }
    __syncthreads();
    // causal GEMM (per wave)
    {
        bf16x8 a0 = *(const bf16x8*)&XB[lr*72 + lg*8];
        bf16x8 a1 = *(const bf16x8*)&XB[lr*72 + 32 + lg*8];
        f32x4 acc[4];
        #pragma unroll
        for (int ct=0;ct<4;++ct) acc[ct] = (f32x4){0.f,0.f,0.f,0.f};
        #pragma unroll
        for (int ct=0;ct<4;++ct){
            bf16x8 b0 = *(const bf16x8*)&wTc[(ct*16+lr)*64 + lg*8];
            bf16x8 b1 = *(const bf16x8*)&wTc[(ct*16+lr)*64 + 32 + lg*8];
            acc[ct] = __builtin_amdgcn_mfma_f32_16x16x32_bf16(a0, b0, acc[ct], 0,0,0);
            acc[ct] = __builtin_amdgcn_mfma_f32_16x16x32_bf16(a1, b1, acc[ct], 0,0,0);
        }
        #pragma unroll
        for (int ct=0;ct<4;++ct){
            float bv = bc[ct*16+lr];
            #pragma unroll
            for (int i=0;i<4;++i)
                yc[(size_t)(r0+lg*4+i)*64 + ct*16+lr] = f2b(acc[ct][i] + bv);
        }
    }
    // river GEMM for the block's 8 n-rows (wave 0)
    if (w == 0){
        int nb0 = ((bid*64)%NF_)/F_;
        int gb  = (bid*64)/NF_;
        bf16x8 a0 = *(const bf16x8*)&WST[lr*72 + lg*8];
        bf16x8 a1 = *(const bf16x8*)&WST[lr*72 + 32 + lg*8];
        f32x4 acc[4];
        #pragma unroll
        for (int ct=0;ct<4;++ct) acc[ct] = (f32x4){0.f,0.f,0.f,0.f};
        #pragma unroll
        for (int ct=0;ct<4;++ct){
            bf16x8 b0 = *(const bf16x8*)&wTr[(ct*16+lr)*64 + lg*8];
            bf16x8 b1 = *(const bf16x8*)&wTr[(ct*16+lr)*64 + 32 + lg*8];
            acc[ct] = __builtin_amdgcn_mfma_f32_16x16x32_bf16(a0, b0, acc[ct], 0,0,0);
            acc[ct] = __builtin_amdgcn_mfma_f32_16x16x32_bf16(a1, b1, acc[ct], 0,0,0);
        }
        if (lg < 2){
            #pragma unroll
            for (int ct=0;ct<4;++ct){
                float bv = br[ct*16+lr];
                #pragma unroll
                for (int i=0;i<4;++i)
                    yr[((size_t)gb*N_ + nb0 + lg*4+i)*64 + ct*16+lr] = f2b(acc[ct][i] + bv);
            }
        }
    }
}

// ---------------------------------------------------------------- merged gather-aggregate (bf16), packed edges.
// 4 rows/wave sharing destination d across graphs (g0, g0+6, g0+12, g0+18): identical edge chains ->
// epack loaded ONCE for all four rows, 8 independent gathers in flight, zero divergence.
__global__ __launch_bounds__(256) void k_gaggr4(const unsigned short* __restrict__ yc,
                                                const int2v* __restrict__ epack_c,
                                                const int* __restrict__ off_c,
                                                unsigned short* __restrict__ ac,
                                                const unsigned short* __restrict__ yr,
                                                const int2v* __restrict__ epack_r,
                                                const int* __restrict__ off_r,
                                                unsigned short* __restrict__ ar){
    int l = threadIdx.x & 63;
    int w = threadIdx.x >> 6;
    const unsigned short* y; const int2v* epack; const int* off;
    unsigned short* aggr; int nseg, pid;
    if (blockIdx.x < 12000){
        int wg = (blockIdx.x & 7)*1500 + (blockIdx.x >> 3);   // XCD-chunked swizzle (12000 % 8 == 0)
        y = yc; epack = epack_c; off = off_c; aggr = ac; nseg = NF_;
        pid = wg*4 + w;                                       // 0..47999
    } else {
        int pb = blockIdx.x - 12000;                          // 0..1499 (small; no swizzle)
        y = yr; epack = epack_r; off = off_r; aggr = ar; nseg = N_;
        pid = pb*4 + w;                                       // 0..5999
    }
    int g0 = pid / nseg;           // 0..5
    int d  = pid % nseg;
    int p = off[d], e = off[d+1];
    const unsigned short* yg0 = y + (size_t)(g0     )*nseg*64 + l;
    const unsigned short* yg1 = y + (size_t)(g0 +  6)*nseg*64 + l;
    const unsigned short* yg2 = y + (size_t)(g0 + 12)*nseg*64 + l;
    const unsigned short* yg3 = y + (size_t)(g0 + 18)*nseg*64 + l;
    float acc0 = 0.f, acc1 = 0.f, acc2 = 0.f, acc3 = 0.f;
    for (; p+1 < e; p += 2){
        int2v ea = epack[p], eb = epack[p+1];
        float wa = __int_as_float(ea[1]), wb = __int_as_float(eb[1]);
        size_t oa = (size_t)ea[0]*64, ob = (size_t)eb[0]*64;
        float va0 = b2f(yg0[oa]), vb0 = b2f(yg0[ob]);
        float va1 = b2f(yg1[oa]), vb1 = b2f(yg1[ob]);
        float va2 = b2f(yg2[oa]), vb2 = b2f(yg2[ob]);
        float va3 = b2f(yg3[oa]), vb3 = b2f(yg3[ob]);
        acc0 += wa*va0 + wb*vb0;
        acc1 += wa*va1 + wb*vb1;
        acc2 += wa*va2 + wb*vb2;
        acc3 += wa*va3 + wb*vb3;
    }
    if (p < e){
        int2v ea = epack[p];
        float wa = __int_as_float(ea[1]);
        size_t oa = (size_t)ea[0]*64;
        acc0 += wa * b2f(yg0[oa]);
        acc1 += wa * b2f(yg1[oa]);
        acc2 += wa * b2f(yg2[oa]);
        acc3 += wa * b2f(yg3[oa]);
    }
    aggr[((size_t)(g0     )*nseg + d)*64 + l] = f2b(acc0);
    aggr[((size_t)(g0 +  6)*nseg + d)*64 + l] = f2b(acc1);
    aggr[((size_t)(g0 + 12)*nseg + d)*64 + l] = f2b(acc2);
    aggr[((size_t)(g0 + 18)*nseg + d)*64 + l] = f2b(acc3);
}

// ---------------------------------------------------------------- river update: u = relu([aggr|ws] @ Wu + b)  (all bf16)
__global__ __launch_bounds__(256) void k_upd16(const unsigned short* __restrict__ aggr,
                                               const unsigned short* __restrict__ xin,
                                               const unsigned short* __restrict__ wT,  // [64 n][128 k]
                                               const float* __restrict__ bu,
                                               unsigned short* __restrict__ u){
    __shared__ unsigned short XBs[4][16*136];
    int w = threadIdx.x>>6, l = threadIdx.x&63;
    int lr = l&15, lg = l>>4;
    int lq = l>>4, lc = (l&15)*4;
    unsigned short* XB = XBs[w];
    int r0 = (blockIdx.x*4 + w)*16;
    #pragma unroll
    for (int v=0; v<4; ++v){
        int row = v*4 + lq;
        int rr = r0 + row;
        *(short4v*)&XB[row*136 + lc]      = *(const short4v*)&aggr[(size_t)rr*64 + lc];
        *(short4v*)&XB[row*136 + 64 + lc] = *(const short4v*)&xin[(size_t)rr*64 + lc];
    }
    LGKM0;
    bf16x8 a[4];
    #pragma unroll
    for (int kk=0;kk<4;++kk) a[kk] = *(const bf16x8*)&XB[lr*136 + kk*32 + lg*8];
    f32x4 acc[4];
    #pragma unroll
    for (int ct=0;ct<4;++ct) acc[ct] = (f32x4){0.f,0.f,0.f,0.f};
    #pragma unroll
    for (int ct=0;ct<4;++ct){
        #pragma unroll
        for (int kk=0;kk<4;++kk){
            bf16x8 b0 = *(const bf16x8*)&wT[(ct*16+lr)*128 + kk*32 + lg*8];
            acc[ct] = __builtin_amdgcn_mfma_f32_16x16x32_bf16(a[kk], b0, acc[ct], 0,0,0);
        }
    }
    #pragma unroll
    for (int ct=0;ct<4;++ct){
        float bv = bu[ct*16+lr];
        #pragma unroll
        for (int i=0;i<4;++i)
            u[(size_t)(r0+lg*4+i)*64 + ct*16+lr] = f2b(fmaxf(acc[ct][i] + bv, 0.f));
    }
}

// ---------------------------------------------------------------- fused causal-update + fusion MLP, 2 tiles/wave (all bf16)
__global__ __launch_bounds__(256) void k_updfus(const unsigned short* __restrict__ aggr,
                                                const unsigned short* __restrict__ xg,
                                                const unsigned short* __restrict__ wuT,  // [64][128]
                                                const float* __restrict__ bu,
                                                const unsigned short* __restrict__ wsu,
                                                const unsigned short* __restrict__ w1T,  // [64][128]
                                                const float* __restrict__ b1,
                                                const unsigned short* __restrict__ w2T,  // [64][64]
                                                const float* __restrict__ b2,
                                                unsigned short* __restrict__ fused){
    __shared__ unsigned short XBs[4][2][16*136];
    __shared__ unsigned short X2s[4][2][16*136];
    int w = threadIdx.x>>6, l = threadIdx.x&63;
    int lr = l&15, lg = l>>4;
    int lq = l>>4, lc = (l&15)*4;
    unsigned short* XB[2] = { XBs[w][0], XBs[w][1] };
    unsigned short* X2[2] = { X2s[w][0], X2s[w][1] };
    int tb = (blockIdx.x*4 + w)*32;      // 32 rows per wave, 32 | 8000 -> no g straddle
    int g  = tb/NF_;
    int n0 = (tb%NF_)/F_;                // octets: tile tt rows 0-7 -> n0+tt*2, rows 8-15 -> n0+tt*2+1
    #pragma unroll
    for (int tt=0;tt<2;++tt){
        int r0 = tb + tt*16;
        #pragma unroll
        for (int v=0; v<4; ++v){
            int row = v*4 + lq;
            int rr = r0 + row;
            *(short4v*)&XB[tt][row*136 + lc]      = *(const short4v*)&aggr[(size_t)rr*64 + lc];
            *(short4v*)&XB[tt][row*136 + 64 + lc] = *(const short4v*)&xg[(size_t)rr*64 + lc];
        }
        unsigned short wv0 = wsu[((size_t)g*N_ + n0 + tt*2    )*64 + l];
        unsigned short wv1 = wsu[((size_t)g*N_ + n0 + tt*2 + 1)*64 + l];
        #pragma unroll
        for (int i=0;i<8;++i){
            X2[tt][i*136 + 64 + l]     = wv0;
            X2[tt][(i+8)*136 + 64 + l] = wv1;
        }
    }
    LGKM0;
    // stage 1: update GEMM k=128 -> relu -> X2 cols 0..63 (both tiles)
    {
        bf16x8 a[2][4];
        #pragma unroll
        for (int tt=0;tt<2;++tt)
            #pragma unroll
            for (int kk=0;kk<4;++kk) a[tt][kk] = *(const bf16x8*)&XB[tt][lr*136 + kk*32 + lg*8];
        f32x4 acc[2][4];
        #pragma unroll
        for (int tt=0;tt<2;++tt)
            #pragma unroll
            for (int ct=0;ct<4;++ct) acc[tt][ct] = (f32x4){0.f,0.f,0.f,0.f};
        #pragma unroll
        for (int ct=0;ct<4;++ct){
            #pragma unroll
            for (int kk=0;kk<4;++kk){
                bf16x8 b0 = *(const bf16x8*)&wuT[(ct*16+lr)*128 + kk*32 + lg*8];
                #pragma unroll
                for (int tt=0;tt<2;++tt)
                    acc[tt][ct] = __builtin_amdgcn_mfma_f32_16x16x32_bf16(a[tt][kk], b0, acc[tt][ct], 0,0,0);
            }
        }
        #pragma unroll
        for (int ct=0;ct<4;++ct){
            float bv = bu[ct*16+lr];
            #pragma unroll
            for (int tt=0;tt<2;++tt)
                #pragma unroll
                for (int i=0;i<4;++i)
                    X2[tt][(lg*4+i)*136 + ct*16+lr] = f2b(fmaxf(acc[tt][ct][i] + bv, 0.f));
        }
    }
    LGKM0;
    // stage 2: fusion GEMM1 k=128 -> relu -> XB cols 0..63 (both tiles)
    {
        bf16x8 a[2][4];
        #pragma unroll
        for (int tt=0;tt<2;++tt)
            #pragma unroll
            for (int kk=0;kk<4;++kk) a[tt][kk] = *(const bf16x8*)&X2[tt][lr*136 + kk*32 + lg*8];
        f32x4 acc[2][4];
        #pragma unroll
        for (int tt=0;tt<2;++tt)
            #pragma unroll
            for (int ct=0;ct<4;++ct) acc[tt][ct] = (f32x4){0.f,0.f,0.f,0.f};
        #pragma unroll
        for (int ct=0;ct<4;++ct){
            #pragma unroll
            for (int kk=0;kk<4;++kk){
                bf16x8 b0 = *(const bf16x8*)&w1T[(ct*16+lr)*128 + kk*32 + lg*8];
                #pragma unroll
                for (int tt=0;tt<2;++tt)
                    acc[tt][ct] = __builtin_amdgcn_mfma_f32_16x16x32_bf16(a[tt][kk], b0, acc[tt][ct], 0,0,0);
            }
        }
        #pragma unroll
        for (int ct=0;ct<4;++ct){
            float bv = b1[ct*16+lr];
            #pragma unroll
            for (int tt=0;tt<2;++tt)
                #pragma unroll
                for (int i=0;i<4;++i)
                    XB[tt][(lg*4+i)*136 + ct*16+lr] = f2b(fmaxf(acc[tt][ct][i] + bv, 0.f));
        }
    }
    LGKM0;
    // stage 3: fusion GEMM2 k=64 -> fused (both tiles)
    {
        bf16x8 h0[2], h1[2];
        #pragma unroll
        for (int tt=0;tt<2;++tt){
            h0[tt] = *(const bf16x8*)&XB[tt][lr*136 + lg*8];
            h1[tt] = *(const bf16x8*)&XB[tt][lr*136 + 32 + lg*8];
        }
        f32x4 acc[2][4];
        #pragma unroll
        for (int tt=0;tt<2;++tt)
            #pragma unroll
            for (int ct=0;ct<4;++ct) acc[tt][ct] = (f32x4){0.f,0.f,0.f,0.f};
        #pragma unroll
        for (int ct=0;ct<4;++ct){
            bf16x8 b0 = *(const bf16x8*)&w2T[(ct*16+lr)*64 + lg*8];
            bf16x8 b1v= *(const bf16x8*)&w2T[(ct*16+lr)*64 + 32 + lg*8];
            #pragma unroll
            for (int tt=0;tt<2;++tt){
                acc[tt][ct] = __builtin_amdgcn_mfma_f32_16x16x32_bf16(h0[tt], b0, acc[tt][ct], 0,0,0);
                acc[tt][ct] = __builtin_amdgcn_mfma_f32_16x16x32_bf16(h1[tt], b1v, acc[tt][ct], 0,0,0);
            }
        }
        #pragma unroll
        for (int ct=0;ct<4;++ct){
            float bv = b2[ct*16+lr];
            #pragma unroll
            for (int tt=0;tt<2;++tt)
                #pragma unroll
                for (int i=0;i<4;++i)
                    fused[(size_t)(tb + tt*16 + lg*4+i)*64 + ct*16+lr] = f2b(acc[tt][ct][i] + bv);
        }
    }
}

// ---------------------------------------------------------------- MFMA temporal transformer: 4 waves, 2 seqs/wave, 12-row SC
// Vectorized staging + cvt_pk conversions (no setprio — measured neutral/negative).
#define XSTR 72    // XB stride (shorts); LN-out / V^T / O staging (16 rows)
#define SSTR 136   // SC stride (shorts): Q 0-63, K 64-127; 12 rows/seq + tail pad; aliased as HID
#define SCSZ (12*SSTR)

__global__ __launch_bounds__(256) void k_xformer(
    const unsigned short* __restrict__ fused,
    const unsigned short* __restrict__ wtq,   // [192][64], Q-part pre-scaled 0.25
    const unsigned short* __restrict__ wto,   // [64][64]
    const unsigned short* __restrict__ wt1,   // [256][64]
    const unsigned short* __restrict__ wt2,   // [64][256]
    const float* __restrict__ bqkv, const float* __restrict__ bo,
    const float* __restrict__ fb1,  const float* __restrict__ fb2,
    const float* __restrict__ ln1g, const float* __restrict__ ln1b,
    const float* __restrict__ ln2g, const float* __restrict__ ln2b,
    float* __restrict__ out)
{
    __shared__ unsigned short XBs[4][2][16*XSTR];
    __shared__ unsigned short SCmem[8*SCSZ + 544];   // 12-row slices + tail pad for benign row-12..15 reads

    int w  = threadIdx.x >> 6;
    int l  = threadIdx.x & 63;
    int lr = l & 15;
    int lg = l >> 4;

    unsigned short* XBp[2] = { XBs[w][0], XBs[w][1] };
    unsigned short* SCp[2] = { &SCmem[(w*2+0)*SCSZ], &SCmem[(w*2+1)*SCSZ] };

    int gbase = (blockIdx.x*4 + w)*2;

    // ---- stage fused rows into SC (vectorized: 3 x 128B row-loads per seq) ----
    #pragma unroll
    for (int sq=0;sq<2;++sq){
        int gs = gbase + sq;
        int bb = gs / NF_, j = gs % NF_;
        const unsigned short* fp = fused + ((size_t)bb*T_*NF_ + j)*64;
        #pragma unroll
        for (int ps=0; ps<3; ++ps){
            int t = ps*4 + lg;
            *(short4v*)&SCp[sq][t*SSTR + lr*4] = *(const short4v*)&fp[(size_t)t*NF_*64 + lr*4];
        }
    }
    LGKM0;

    // ---- read C-layout fragments from LDS ----
    float res[2][4][4];
    #pragma unroll
    for (int sq=0;sq<2;++sq)
        #pragma unroll
        for (int nt=0;nt<4;++nt)
            #pragma unroll
            for (int i=0;i<4;++i){
                int t = lg*4+i;
                res[sq][nt][i] = (t < 12) ? b2f(SCp[sq][t*SSTR + nt*16 + lr]) : 0.f;
            }

    // LN1 -> XB (both seqs), packed conversions
    #pragma unroll
    for (int sq=0;sq<2;++sq){
        float sm[4], sqr[4];
        #pragma unroll
        for (int i=0;i<4;++i){
            sm[i]  = res[sq][0][i]+res[sq][1][i]+res[sq][2][i]+res[sq][3][i];
            sqr[i] = res[sq][0][i]*res[sq][0][i]+res[sq][1][i]*res[sq][1][i]
                   + res[sq][2][i]*res[sq][2][i]+res[sq][3][i]*res[sq][3][i];
        }
        #pragma unroll
        for (int m=1;m<16;m<<=1){
            #pragma unroll
            for (int i=0;i<4;++i){
                sm[i]  += __shfl_xor(sm[i], m, 64);
                sqr[i] += __shfl_xor(sqr[i], m, 64);
            }
        }
        float mnv[4], rsv[4];
        #pragma unroll
        for (int i=0;i<4;++i){
            mnv[i] = sm[i]*(1.0f/64.0f);
            float var = sqr[i]*(1.0f/64.0f) - mnv[i]*mnv[i];
            rsv[i] = rsqrtf(var + 1e-5f);
        }
        #pragma unroll
        for (int nt=0;nt<4;++nt){
            float gg = ln1g[nt*16+lr], oo = ln1b[nt*16+lr];
            float w0 = (res[sq][nt][0]-mnv[0])*rsv[0]*gg + oo;
            float w1 = (res[sq][nt][1]-mnv[1])*rsv[1]*gg + oo;
            float w2 = (res[sq][nt][2]-mnv[2])*rsv[2]*gg + oo;
            float w3 = (res[sq][nt][3]-mnv[3])*rsv[3]*gg + oo;
            unsigned u01 = cpk(w0,w1), u23 = cpk(w2,w3);
            XBp[sq][(lg*4+0)*XSTR + nt*16 + lr] = (unsigned short)u01;
            XBp[sq][(lg*4+1)*XSTR + nt*16 + lr] = (unsigned short)(u01>>16);
            XBp[sq][(lg*4+2)*XSTR + nt*16 + lr] = (unsigned short)u23;
            XBp[sq][(lg*4+3)*XSTR + nt*16 + lr] = (unsigned short)(u23>>16);
        }
    }
    LGKM0;

    // QKV GEMM: Q,K -> SC (rows<12); V^T -> XB (shared weight frags), packed conversions
    {
        bf16x8 a0[2], a1[2];
        #pragma unroll
        for (int sq=0;sq<2;++sq){
            a0[sq] = *(const bf16x8*)&XBp[sq][lr*XSTR + 0*32 + lg*8];
            a1[sq] = *(const bf16x8*)&XBp[sq][lr*XSTR + 1*32 + lg*8];
        }
        LGKM0;   // a-frags in regs before V overwrites XB
        #pragma unroll
        for (int p=0;p<3;++p){
            f32x4 acc[2][4];
            #pragma unroll
            for (int sq=0;sq<2;++sq)
                #pragma unroll
                for (int c=0;c<4;++c) acc[sq][c] = (f32x4){0.f,0.f,0.f,0.f};
            #pragma unroll
            for (int c=0;c<4;++c){
                int ct = p*4 + c;
                bf16x8 b0 = *(const bf16x8*)&wtq[(ct*16+lr)*64 + 0*32 + lg*8];
                bf16x8 b1v= *(const bf16x8*)&wtq[(ct*16+lr)*64 + 1*32 + lg*8];
                #pragma unroll
                for (int sq=0;sq<2;++sq){
                    acc[sq][c] = __builtin_amdgcn_mfma_f32_16x16x32_bf16(a0[sq], b0, acc[sq][c], 0,0,0);
                    acc[sq][c] = __builtin_amdgcn_mfma_f32_16x16x32_bf16(a1[sq], b1v, acc[sq][c], 0,0,0);
                }
            }
            if (p < 2){
                if (lg < 3){
                    #pragma unroll
                    for (int c=0;c<4;++c){
                        int ct = p*4 + c;
                        float bv = bqkv[ct*16+lr];
                        if (p == 0) bv *= 0.25f;
                        #pragma unroll
                        for (int sq=0;sq<2;++sq){
                            unsigned u01 = cpk(acc[sq][c][0]+bv, acc[sq][c][1]+bv);
                            unsigned u23 = cpk(acc[sq][c][2]+bv, acc[sq][c][3]+bv);
                            SCp[sq][(lg*4+0)*SSTR + p*64 + c*16 + lr] = (unsigned short)u01;
                            SCp[sq][(lg*4+1)*SSTR + p*64 + c*16 + lr] = (unsigned short)(u01>>16);
                            SCp[sq][(lg*4+2)*SSTR + p*64 + c*16 + lr] = (unsigned short)u23;
                            SCp[sq][(lg*4+3)*SSTR + p*64 + c*16 + lr] = (unsigned short)(u23>>16);
                        }
                    }
                }
            } else {
                #pragma unroll
                for (int c=0;c<4;++c){
                    float bv = bqkv[128 + c*16 + lr];
                    #pragma unroll
                    for (int sq=0;sq<2;++sq){
                        uint2v vv2;
                        vv2[0] = cpk(acc[sq][c][0]+bv, acc[sq][c][1]+bv);
                        vv2[1] = cpk(acc[sq][c][2]+bv, acc[sq][c][3]+bv);
                        *(uint2v*)&XBp[sq][lr*XSTR + c*16 + lg*4] = vv2;   // VT'[d=c*16+lr][t=lg*4..+3]
                    }
                }
            }
        }
    }
    LGKM0;

    // MFMA attention per head, both seqs (packed P and O conversions)
    {
        const bf16x8 bz = (bf16x8){0,0,0,0,0,0,0,0};
        #pragma unroll
        for (int hd=0; hd<4; ++hd){
            #pragma unroll
            for (int sq=0;sq<2;++sq){
                bf16x8 ak = bz, bq = bz;
                if (lg < 2){
                    ak = *(const bf16x8*)&SCp[sq][lr*SSTR + 64 + hd*16 + lg*8];
                    bq = *(const bf16x8*)&SCp[sq][lr*SSTR +      hd*16 + lg*8];
                }
                f32x4 st = __builtin_amdgcn_mfma_f32_16x16x32_bf16(ak, bq, (f32x4){0.f,0.f,0.f,0.f}, 0,0,0);
                float s0=st[0], s1v=st[1], s2=st[2], s3=st[3];
                if (lg == 3){ s0=s1v=s2=s3=-1e30f; }
                float mx = fmaxf(fmaxf(s0,s1v), fmaxf(s2,s3));
                mx = fmaxf(mx, __shfl_xor(mx, 16, 64));
                mx = fmaxf(mx, __shfl_xor(mx, 32, 64));
                float p0 = __expf(s0-mx), p1 = __expf(s1v-mx), p2 = __expf(s2-mx), p3 = __expf(s3-mx);
                float den = p0+p1+p2+p3;
                den += __shfl_xor(den, 16, 64);
                den += __shfl_xor(den, 32, 64);
                float inv = __builtin_amdgcn_rcpf(den);
                float q0 = __shfl_down(p0, 16, 64), q1 = __shfl_down(p1, 16, 64);
                float q2 = __shfl_down(p2, 16, 64), q3 = __shfl_down(p3, 16, 64);
                union { uint4v u; bf16x8 b; } pu;
                {
                    float lo0 = (lg==0)? p0 : (lg==1)? q0 : 0.f;
                    float lo1 = (lg==0)? p1 : (lg==1)? q1 : 0.f;
                    float lo2 = (lg==0)? p2 : (lg==1)? q2 : 0.f;
                    float lo3 = (lg==0)? p3 : (lg==1)? q3 : 0.f;
                    float hi0 = (lg==0)? q0 : 0.f;
                    float hi1 = (lg==0)? q1 : 0.f;
                    float hi2 = (lg==0)? q2 : 0.f;
                    float hi3 = (lg==0)? q3 : 0.f;
                    pu.u[0] = cpk(lo0, lo1);
                    pu.u[1] = cpk(lo2, lo3);
                    pu.u[2] = cpk(hi0, hi1);
                    pu.u[3] = cpk(hi2, hi3);
                }
                bf16x8 pb = pu.b;
                bf16x8 av = bz;
                if (lg < 2) av = *(const bf16x8*)&XBp[sq][lr*XSTR + hd*16 + lg*8];
                f32x4 ot = __builtin_amdgcn_mfma_f32_16x16x32_bf16(av, pb, (f32x4){0.f,0.f,0.f,0.f}, 0,0,0);
                uint2v ow2;
                ow2[0] = cpk(ot[0]*inv, ot[1]*inv);
                ow2[1] = cpk(ot[2]*inv, ot[3]*inv);
                *(uint2v*)&XBp[sq][lr*XSTR + hd*16 + lg*4] = ow2;
            }
        }
    }
    LGKM0;

    // proj + residual -> s1 (shared weight frags)
    float s1[2][4][4];
    {
        bf16x8 a0[2], a1[2];
        #pragma unroll
        for (int sq=0;sq<2;++sq){
            a0[sq] = *(const bf16x8*)&XBp[sq][lr*XSTR + 0*32 + lg*8];
            a1[sq] = *(const bf16x8*)&XBp[sq][lr*XSTR + 1*32 + lg*8];
        }
        f32x4 pacc[2][4];
        #pragma unroll
        for (int sq=0;sq<2;++sq)
            #pragma unroll
            for (int ct=0;ct<4;++ct) pacc[sq][ct] = (f32x4){0.f,0.f,0.f,0.f};
        #pragma unroll
        for (int ct=0;ct<4;++ct){
            bf16x8 b0 = *(const bf16x8*)&wto[(ct*16+lr)*64 + 0*32 + lg*8];
            bf16x8 b1v= *(const bf16x8*)&wto[(ct*16+lr)*64 + 1*32 + lg*8];
            #pragma unroll
            for (int sq=0;sq<2;++sq){
                pacc[sq][ct] = __builtin_amdgcn_mfma_f32_16x16x32_bf16(a0[sq], b0, pacc[sq][ct], 0,0,0);
                pacc[sq][ct] = __builtin_amdgcn_mfma_f32_16x16x32_bf16(a1[sq], b1v, pacc[sq][ct], 0,0,0);
            }
        }
        #pragma unroll
        for (int sq=0;sq<2;++sq)
            #pragma unroll
            for (int ct=0;ct<4;++ct){
                float bv = bo[ct*16+lr];
                #pragma unroll
                for (int i=0;i<4;++i)
                    s1[sq][ct][i] = res[sq][ct][i] + pacc[sq][ct][i] + bv;
            }
    }

    // LN2 -> XB (both seqs), packed conversions
    #pragma unroll
    for (int sq=0;sq<2;++sq){
        float sm[4], sqr[4];
        #pragma unroll
        for (int i=0;i<4;++i){
            sm[i]  = s1[sq][0][i]+s1[sq][1][i]+s1[sq][2][i]+s1[sq][3][i];
            sqr[i] = s1[sq][0][i]*s1[sq][0][i]+s1[sq][1][i]*s1[sq][1][i]
                   + s1[sq][2][i]*s1[sq][2][i]+s1[sq][3][i]*s1[sq][3][i];
        }
        #pragma unroll
        for (int m=1;m<16;m<<=1){
            #pragma unroll
            for (int i=0;i<4;++i){
                sm[i]  += __shfl_xor(sm[i], m, 64);
                sqr[i] += __shfl_xor(sqr[i], m, 64);
            }
        }
        float mnv[4], rsv[4];
        #pragma unroll
        for (int i=0;i<4;++i){
            mnv[i] = sm[i]*(1.0f/64.0f);
            float var = sqr[i]*(1.0f/64.0f) - mnv[i]*mnv[i];
            rsv[i] = rsqrtf(var + 1e-5f);
        }
        #pragma unroll
        for (int nt=0;nt<4;++nt){
            float gg = ln2g[nt*16+lr], oo = ln2b[nt*16+lr];
            float w0 = (s1[sq][nt][0]-mnv[0])*rsv[0]*gg + oo;
            float w1 = (s1[sq][nt][1]-mnv[1])*rsv[1]*gg + oo;
            float w2 = (s1[sq][nt][2]-mnv[2])*rsv[2]*gg + oo;
            float w3 = (s1[sq][nt][3]-mnv[3])*rsv[3]*gg + oo;
            unsigned u01 = cpk(w0,w1), u23 = cpk(w2,w3);
            XBp[sq][(lg*4+0)*XSTR + nt*16 + lr] = (unsigned short)u01;
            XBp[sq][(lg*4+1)*XSTR + nt*16 + lr] = (unsigned short)(u01>>16);
            XBp[sq][(lg*4+2)*XSTR + nt*16 + lr] = (unsigned short)u23;
            XBp[sq][(lg*4+3)*XSTR + nt*16 + lr] = (unsigned short)(u23>>16);
        }
    }
    LGKM0;

    // FFN: two 128-wide halves; HID stores guarded rows<12; packed conversions
    f32x4 oacc[2][4];
    #pragma unroll
    for (int sq=0;sq<2;++sq)
        #pragma unroll
        for (int ct=0;ct<4;++ct) oacc[sq][ct] = (f32x4){0.f,0.f,0.f,0.f};
    {
        bf16x8 a0[2], a1[2];
        #pragma unroll
        for (int sq=0;sq<2;++sq){
            a0[sq] = *(const bf16x8*)&XBp[sq][lr*XSTR + 0*32 + lg*8];
            a1[sq] = *(const bf16x8*)&XBp[sq][lr*XSTR + 1*32 + lg*8];
        }
        #pragma unroll
        for (int half=0; half<2; ++half){
            LGKM0;   // HID region reuse guard
            #pragma unroll
            for (int q=0; q<2; ++q){
                f32x4 facc[2][4];
                #pragma unroll
                for (int sq=0;sq<2;++sq)
                    #pragma unroll
                    for (int c=0;c<4;++c) facc[sq][c] = (f32x4){0.f,0.f,0.f,0.f};
                #pragma unroll
                for (int c=0;c<4;++c){
                    int ct = half*8 + q*4 + c;
                    bf16x8 b0 = *(const bf16x8*)&wt1[(ct*16+lr)*64 + 0*32 + lg*8];
                    bf16x8 b1v= *(const bf16x8*)&wt1[(ct*16+lr)*64 + 1*32 + lg*8];
                    #pragma unroll
                    for (int sq=0;sq<2;++sq){
                        facc[sq][c] = __builtin_amdgcn_mfma_f32_16x16x32_bf16(a0[sq], b0, facc[sq][c], 0,0,0);
                        facc[sq][c] = __builtin_amdgcn_mfma_f32_16x16x32_bf16(a1[sq], b1v, facc[sq][c], 0,0,0);
                    }
                }
                if (lg < 3){
                    #pragma unroll
                    for (int c=0;c<4;++c){
                        int ct = half*8 + q*4 + c;
                        float bv = fb1[ct*16+lr];
                        #pragma unroll
                        for (int sq=0;sq<2;++sq){
                            float hv[4];
                            #pragma unroll
                            for (int i=0;i<4;++i){
                                float xv = facc[sq][c][i] + bv;
                                float x2 = xv*xv;
                                float z  = xv*(1.5957691216f + 0.0713548162f*x2);
                                float ez = __expf(-z);
                                hv[i] = xv * __builtin_amdgcn_rcpf(1.0f + ez);
                            }
                            unsigned u01 = cpk(hv[0],hv[1]), u23 = cpk(hv[2],hv[3]);
                            SCp[sq][(lg*4+0)*SSTR + (q*4+c)*16 + lr] = (unsigned short)u01;
                            SCp[sq][(lg*4+1)*SSTR + (q*4+c)*16 + lr] = (unsigned short)(u01>>16);
                            SCp[sq][(lg*4+2)*SSTR + (q*4+c)*16 + lr] = (unsigned short)u23;
                            SCp[sq][(lg*4+3)*SSTR + (q*4+c)*16 + lr] = (unsigned short)(u23>>16);
                        }
                    }
                }
            }
            LGKM0;
            #pragma unroll
            for (int ks=0;ks<4;++ks){
                bf16x8 af[2];
                #pragma unroll
                for (int sq=0;sq<2;++sq)
                    af[sq] = *(const bf16x8*)&SCp[sq][lr*SSTR + ks*32 + lg*8];
                #pragma unroll
                for (int ct=0;ct<4;++ct){
                    bf16x8 bfr = *(const bf16x8*)&wt2[(ct*16+lr)*256 + half*128 + ks*32 + lg*8];
                    #pragma unroll
                    for (int sq=0;sq<2;++sq)
                        oacc[sq][ct] = __builtin_amdgcn_mfma_f32_16x16x32_bf16(af[sq], bfr, oacc[sq][ct], 0,0,0);
                }
            }
        }
    }

    // residual + mean over t (both seqs)
    #pragma unroll
    for (int sq=0;sq<2;++sq)
        #pragma unroll
        for (int ct=0;ct<4;++ct){
            float bv = fb2[ct*16+lr];
            float part = 0.f;
            #pragma unroll
            for (int i=0;i<4;++i){
                if (lg*4+i < 12) part += s1[sq][ct][i] + oacc[sq][ct][i] + bv;
            }
            part += __shfl_xor(part, 16, 64);
            part += __shfl_xor(part, 32, 64);
            if (lg == 0) out[(size_t)(gbase+sq)*64 + ct*16 + lr] = part*(1.0f/12.0f);
        }
}

// ----------------------------------------------------------------
extern "C" void kernel_launch(void* const* d_in, const int* in_sizes, int n_in,
                              void* d_out, int out_size, void* d_ws, size_t ws_size,
                              hipStream_t stream) {
    const float* x      = (const float*)d_in[0];
    const int*   r_ei   = (const int*)  d_in[1];
    const float* r_ea   = (const float*)d_in[2];
    const int*   c_ei   = (const int*)  d_in[3];
    const float* c_ew   = (const float*)d_in[4];
    const float* rvWlin = (const float*)d_in[5];
    const float* rvblin = (const float*)d_in[6];
    const float* rvWupd = (const float*)d_in[7];
    const float* rvbupd = (const float*)d_in[8];
    const float* rvgate = (const float*)d_in[9];
    const float* rvlw   = (const float*)d_in[10];
    const float* csWlin = (const float*)d_in[11];
    const float* csblin = (const float*)d_in[12];
    const float* csWupd = (const float*)d_in[13];
    const float* csbupd = (const float*)d_in[14];
    const float* csgate = (const float*)d_in[15];
    const float* cslw   = (const float*)d_in[16];
    const float* fuW1   = (const float*)d_in[17];
    const float* fub1   = (const float*)d_in[18];
    const float* fuW2   = (const float*)d_in[19];
    const float* fub2   = (const float*)d_in[20];
    const float* ln1g   = (const float*)d_in[21];
    const float* ln1b   = (const float*)d_in[22];
    const float* ln2g   = (const float*)d_in[23];
    const float* ln2b   = (const float*)d_in[24];
    const float* Wqkv   = (const float*)d_in[25];
    const float* bqkv   = (const float*)d_in[26];
    const float* Wo     = (const float*)d_in[27];
    const float* bo     = (const float*)d_in[28];
    const float* ffW1   = (const float*)d_in[29];
    const float* ffb1   = (const float*)d_in[30];
    const float* ffW2   = (const float*)d_in[31];
    const float* ffb2   = (const float*)d_in[32];

    float* wsp  = (float*)d_ws;
    unsigned short* FNY_b = (unsigned short*)wsp;                    // causal y bf16, then FUSED bf16
    unsigned short* FNA_b = (unsigned short*)(wsp + 12288000);       // causal aggr bf16
    unsigned short* XG_b  = (unsigned short*)(wsp + 12288000 + 6144000); // gathered x bf16
    unsigned short* WS_b  = (unsigned short*)(wsp + 24576000);       // watershed mean bf16
    unsigned short* WSY_b = (unsigned short*)(wsp + 26112000);       // river y bf16
    unsigned short* WSA_b = (unsigned short*)(wsp + 27648000);       // river aggr bf16
    float* WSU  = wsp + 29184000;                                    // CSR scratch, then river u bf16
    unsigned short* WSU_b = (unsigned short*)WSU;
    unsigned short* wt = (unsigned short*)(wsp + 30720000);
    float* outp = (float*)d_out;

    int* ibase  = (int*)WSU;
    int* cnt_c  = ibase;
    int* cnt_r  = ibase + 8000;
    int* off_c  = ibase + 9000;
    int* off_r  = ibase + 17001;
    int* cur_c  = ibase + 18002;
    int* cur_r  = ibase + 26002;
    float* mw_c = (float*)(ibase + 53002);
    float* mw_r = (float*)(ibase + 77002);
    int2v* epack_c = (int2v*)(ibase + 80000);   // 24000 x 8B
    int2v* epack_r = (int2v*)(ibase + 128000);  //  2000 x 8B (clobbered later by river u -> OK, consumers done)

    const int* c_src = c_ei;
    const int* c_dst = c_ei + EC_;
    const int* r_src = r_ei;
    const int* r_dst = r_ei + ER_;

    hipMemsetAsync(cnt_c, 0, 9000*sizeof(int), stream);

    // merged: mw+histogram (102 blocks) + bf16 weight panels (336 blocks)
    k_prephist<<<438, 256, 0, stream>>>(c_dst, r_dst, c_ew, cslw, csgate,
                                        r_ea, rvlw, rvgate, mw_c, mw_r, cnt_c, cnt_r,
                                        Wqkv, Wo, ffW1, ffW2, csWlin, rvWlin, csWupd, rvWupd,
                                        fuW1, fuW2, wt);
    k_scan<<<2, 256, 0, stream>>>(cnt_c, off_c, cur_c, cnt_r, off_r, cur_r);

    // merged: CSR fill (102 blocks) + node linear (3000 blocks)
    k_filllin<<<3102, 256, 0, stream>>>(c_src, c_dst, r_src, r_dst, mw_c, mw_r,
                                        cur_c, cur_r, epack_c, epack_r,
                                        x, wt+49152, csblin, wt+53248, rvblin,
                                        FNY_b, WSY_b, XG_b, WS_b);

    // merged gather-aggregation (4-way cross-graph pairing: shared epack, 8 gathers in flight)
    k_gaggr4<<<13500, 256, 0, stream>>>(FNY_b, epack_c, off_c, FNA_b,
                                        WSY_b, epack_r, off_r, WSA_b);

    // river update (clobbers CSR scratch -> OK, consumers done)
    k_upd16<<<375, 256, 0, stream>>>(WSA_b, WS_b, wt+65536, rvbupd, WSU_b);

    // fused causal update + fusion MLP, 2 tiles/wave -> FUSED bf16 (into FNY region)
    k_updfus<<<1500, 256, 0, stream>>>(FNA_b, XG_b, wt+57344, csbupd, WSU_b,
                                       wt+73728, fub1, wt+81920, fub2, FNY_b);

    // 2-seq-per-wave MFMA transformer (cvt_pk, no setprio)
    k_xformer<<<2000, 256, 0, stream>>>(FNY_b,
                                        wt, wt+12288, wt+16384, wt+32768,
                                        bqkv, bo, ffb1, ffb2,
                                        ln1g, ln1b, ln2g, ln2b,
                                        outp);
}

// Round 25
// 250.432 us; speedup vs baseline: 1.1108x; 1.0184x over previous
//
#include <hip/hip_runtime.h>
#include <math.h>

#define B_ 2
#define N_ 1000
#define F_ 8
#define T_ 12
#define H_ 64
#define G_ 24      // B*T
#define NF_ 8000   // N*F
#define ER_ 2000
#define EC_ 24000

typedef short bf16x8 __attribute__((ext_vector_type(8)));
typedef short short4v __attribute__((ext_vector_type(4)));
typedef float f32x4 __attribute__((ext_vector_type(4)));
typedef unsigned int uint2v __attribute__((ext_vector_type(2)));
typedef unsigned int uint4v __attribute__((ext_vector_type(4)));
typedef int int2v __attribute__((ext_vector_type(2)));

#define LGKM0 do { asm volatile("s_waitcnt lgkmcnt(0)" ::: "memory"); __builtin_amdgcn_sched_barrier(0); } while(0)

__device__ __forceinline__ float sigf(float x){ return 1.0f/(1.0f+__expf(-x)); }

// f32 -> bf16 (RNE)
__device__ __forceinline__ unsigned short f2b(float f){
    unsigned u = __float_as_uint(f);
    unsigned r = (u + 0x7FFFu + ((u >> 16) & 1u)) >> 16;
    return (unsigned short)r;
}
__device__ __forceinline__ float b2f(unsigned short u){
    return __uint_as_float(((unsigned)u) << 16);
}
// packed 2xf32 -> 2xbf16 in one VALU op (gfx950)
__device__ __forceinline__ unsigned cpk(float lo, float hi){
    unsigned r;
    asm("v_cvt_pk_bf16_f32 %0, %1, %2" : "=v"(r) : "v"(lo), "v"(hi));
    return r;
}

// ---------------------------------------------------------------- merged: mw+histogram (blocks 0..101) + weight prep (blocks 102+)
__global__ __launch_bounds__(256) void k_prephist(
    const int* __restrict__ c_dst, const int* __restrict__ r_dst,
    const float* __restrict__ c_ew, const float* __restrict__ c_lw, const float* __restrict__ c_gate,
    const float* __restrict__ r_ew, const float* __restrict__ r_lw, const float* __restrict__ r_gate,
    float* __restrict__ mw_c, float* __restrict__ mw_r,
    int* __restrict__ cnt_c, int* __restrict__ cnt_r,
    const float* __restrict__ Wqkv, const float* __restrict__ Wo,
    const float* __restrict__ W1,   const float* __restrict__ W2,
    const float* __restrict__ csWlin, const float* __restrict__ rvWlin,
    const float* __restrict__ csWupd, const float* __restrict__ rvWupd,
    const float* __restrict__ fuW1,   const float* __restrict__ fuW2,
    unsigned short* __restrict__ wt)
{
    if (blockIdx.x < 102){
        int i = blockIdx.x*256 + threadIdx.x;
        if (i < EC_){
            float gs = sigf(c_gate[0]);
            mw_c[i] = gs*c_ew[i] + (1.f-gs)*sigf(c_lw[i]);
            atomicAdd(&cnt_c[c_dst[i]], 1);
        } else if (i < EC_+ER_){
            int e = i - EC_;
            float gs = sigf(r_gate[0]);
            mw_r[e] = gs*r_ew[e] + (1.f-gs)*sigf(r_lw[e]);
            atomicAdd(&cnt_r[r_dst[e]], 1);
        }
        return;
    }
    int i = (blockIdx.x-102)*256 + threadIdx.x;
    if      (i < 12288){ int n=i>>6, k=i&63; float v = Wqkv[k*192+n]; if (n < 64) v *= 0.25f; wt[i] = f2b(v); }
    else if (i < 16384){ int z=i-12288; int n=z>>6, k=z&63; wt[i] = f2b(Wo[k*64+n]); }
    else if (i < 32768){ int z=i-16384; int n=z>>6, k=z&63; wt[i] = f2b(W1[k*256+n]); }
    else if (i < 49152){ int z=i-32768; int n=z>>8, k=z&255; wt[i] = f2b(W2[k*64+n]); }
    else if (i < 53248){ int z=i-49152; int n=z>>6, k=z&63; wt[i] = f2b(csWlin[k*64+n]); }
    else if (i < 57344){ int z=i-53248; int n=z>>6, k=z&63; wt[i] = f2b(rvWlin[k*64+n]); }
    else if (i < 65536){ int z=i-57344; int n=z>>7, k=z&127; wt[i] = f2b(csWupd[k*64+n]); }
    else if (i < 73728){ int z=i-65536; int n=z>>7, k=z&127; wt[i] = f2b(rvWupd[k*64+n]); }
    else if (i < 81920){ int z=i-73728; int n=z>>7, k=z&127; wt[i] = f2b(fuW1[k*64+n]); }
    else if (i < 86016){ int z=i-81920; int n=z>>6, k=z&63; wt[i] = f2b(fuW2[k*64+n]); }
}

// ---------------------------------------------------------------- CSR build: exclusive scan (parallel Hillis-Steele)
__global__ __launch_bounds__(256) void k_scan(const int* __restrict__ cnt_c, int* __restrict__ off_c, int* __restrict__ cur_c,
                                              const int* __restrict__ cnt_r, int* __restrict__ off_r, int* __restrict__ cur_r){
    const int n = (blockIdx.x==0) ? NF_ : N_;
    const int* cnt = (blockIdx.x==0) ? cnt_c : cnt_r;
    int* off = (blockIdx.x==0) ? off_c : off_r;
    int* cur = (blockIdx.x==0) ? cur_c : cur_r;
    __shared__ int part[256];
    int tid = threadIdx.x;
    int tpt = (n + 255) / 256;
    int i0 = tid * tpt;
    int s = 0;
    for (int i=0;i<tpt;++i){ int idx=i0+i; if (idx<n) s += cnt[idx]; }
    part[tid] = s;
    __syncthreads();
    #pragma unroll
    for (int d=1; d<256; d<<=1){
        int v = (tid >= d) ? part[tid-d] : 0;
        __syncthreads();
        part[tid] += v;
        __syncthreads();
    }
    int run = part[tid] - s;    // exclusive prefix of this chunk
    for (int i=0;i<tpt;++i){
        int idx = i0+i;
        if (idx < n){ off[idx] = run; cur[idx] = run; run += cnt[idx]; }
    }
    if (tid == 255) off[n] = part[255];
}

// ---------------------------------------------------------------- merged: CSR fill (blocks 0..101) + node linear (blocks 102+)
__global__ __launch_bounds__(256) void k_filllin(
    const int* __restrict__ c_src, const int* __restrict__ c_dst,
    const int* __restrict__ r_src, const int* __restrict__ r_dst,
    const float* __restrict__ mw_c, const float* __restrict__ mw_r,
    int* __restrict__ cur_c, int* __restrict__ cur_r,
    int2v* __restrict__ epack_c, int2v* __restrict__ epack_r,
    const float* __restrict__ x,
    const unsigned short* __restrict__ wTc, const float* __restrict__ bc,
    const unsigned short* __restrict__ wTr, const float* __restrict__ br,
    unsigned short* __restrict__ yc, unsigned short* __restrict__ yr,
    unsigned short* __restrict__ xg, unsigned short* __restrict__ wsb)
{
    __shared__ unsigned short XBs[4][16*72];
    __shared__ unsigned short WST[16*72];     // rows 0..7 valid (block's 8 f-means)
    if (blockIdx.x < 102){
        int i = blockIdx.x*256 + threadIdx.x;
        if (i < EC_){
            int p = atomicAdd(&cur_c[c_dst[i]], 1);
            int2v ep; ep[0] = c_src[i]; ep[1] = __float_as_int(mw_c[i]);
            epack_c[p] = ep;
        } else if (i < EC_+ER_){
            int e = i - EC_;
            int p = atomicAdd(&cur_r[r_dst[e]], 1);
            int2v ep; ep[0] = r_src[e]; ep[1] = __float_as_int(mw_r[e]);
            epack_r[p] = ep;
        }
        return;
    }
    int bid = blockIdx.x - 102;               // 0..2999
    int w = threadIdx.x>>6, l = threadIdx.x&63;
    int lr = l&15, lg = l>>4;
    unsigned short* XB = XBs[w];
    int r0 = (bid*4 + w)*16;
    int g  = r0/NF_;
    int j0 = r0%NF_;
    float fsum0 = 0.f, fsum1 = 0.f;
    #pragma unroll
    for (int i=0;i<16;++i){
        int rr = r0+i;
        int j = j0+i;
        int b = g/T_, t = g%T_, n = j/F_, f = j%F_;
        float v = x[((size_t)((b*N_+n)*F_+f)*T_ + t)*64 + l];
        unsigned short us = f2b(v);
        XB[i*72 + l] = us;
        xg[(size_t)rr*64 + l] = us;
        if (i < 8) fsum0 += v; else fsum1 += v;
    }
    {
        int nb = j0/F_;
        unsigned short u0 = f2b(fsum0*0.125f);
        unsigned short u1 = f2b(fsum1*0.125f);
        WST[(w*2+0)*72 + l] = u0;
        WST[(w*2+1)*72 + l] = u1;
        wsb[((size_t)g*N_ + nb    )*64 + l] = u0;
        wsb[((size_t)g*N_ + nb + 1)*64 + l] = u1;
    }
    __syncthreads();
    // causal GEMM (per wave)
    {
        bf16x8 a0 = *(const bf16x8*)&XB[lr*72 + lg*8];
        bf16x8 a1 = *(const bf16x8*)&XB[lr*72 + 32 + lg*8];
        f32x4 acc[4];
        #pragma unroll
        for (int ct=0;ct<4;++ct) acc[ct] = (f32x4){0.f,0.f,0.f,0.f};
        #pragma unroll
        for (int ct=0;ct<4;++ct){
            bf16x8 b0 = *(const bf16x8*)&wTc[(ct*16+lr)*64 + lg*8];
            bf16x8 b1 = *(const bf16x8*)&wTc[(ct*16+lr)*64 + 32 + lg*8];
            acc[ct] = __builtin_amdgcn_mfma_f32_16x16x32_bf16(a0, b0, acc[ct], 0,0,0);
            acc[ct] = __builtin_amdgcn_mfma_f32_16x16x32_bf16(a1, b1, acc[ct], 0,0,0);
        }
        #pragma unroll
        for (int ct=0;ct<4;++ct){
            float bv = bc[ct*16+lr];
            #pragma unroll
            for (int i=0;i<4;++i)
                yc[(size_t)(r0+lg*4+i)*64 + ct*16+lr] = f2b(acc[ct][i] + bv);
        }
    }
    // river GEMM for the block's 8 n-rows (wave 0)
    if (w == 0){
        int nb0 = ((bid*64)%NF_)/F_;
        int gb  = (bid*64)/NF_;
        bf16x8 a0 = *(const bf16x8*)&WST[lr*72 + lg*8];
        bf16x8 a1 = *(const bf16x8*)&WST[lr*72 + 32 + lg*8];
        f32x4 acc[4];
        #pragma unroll
        for (int ct=0;ct<4;++ct) acc[ct] = (f32x4){0.f,0.f,0.f,0.f};
        #pragma unroll
        for (int ct=0;ct<4;++ct){
            bf16x8 b0 = *(const bf16x8*)&wTr[(ct*16+lr)*64 + lg*8];
            bf16x8 b1 = *(const bf16x8*)&wTr[(ct*16+lr)*64 + 32 + lg*8];
            acc[ct] = __builtin_amdgcn_mfma_f32_16x16x32_bf16(a0, b0, acc[ct], 0,0,0);
            acc[ct] = __builtin_amdgcn_mfma_f32_16x16x32_bf16(a1, b1, acc[ct], 0,0,0);
        }
        if (lg < 2){
            #pragma unroll
            for (int ct=0;ct<4;++ct){
                float bv = br[ct*16+lr];
                #pragma unroll
                for (int i=0;i<4;++i)
                    yr[((size_t)gb*N_ + nb0 + lg*4+i)*64 + ct*16+lr] = f2b(acc[ct][i] + bv);
            }
        }
    }
}

// ---------------------------------------------------------------- merged gather-aggregate (bf16), packed edges.
// 8 rows/wave sharing destination d across graphs (g0, g0+3, ..., g0+21): identical edge chains ->
// epack loaded ONCE for all eight rows, 16 independent gathers in flight, zero divergence.
__global__ __launch_bounds__(256) void k_gaggr8(const unsigned short* __restrict__ yc,
                                                const int2v* __restrict__ epack_c,
                                                const int* __restrict__ off_c,
                                                unsigned short* __restrict__ ac,
                                                const unsigned short* __restrict__ yr,
                                                const int2v* __restrict__ epack_r,
                                                const int* __restrict__ off_r,
                                                unsigned short* __restrict__ ar){
    int l = threadIdx.x & 63;
    int w = threadIdx.x >> 6;
    const unsigned short* y; const int2v* epack; const int* off;
    unsigned short* aggr; int nseg, pid;
    if (blockIdx.x < 6000){
        int wg = (blockIdx.x & 7)*750 + (blockIdx.x >> 3);    // XCD-chunked swizzle (6000 % 8 == 0)
        y = yc; epack = epack_c; off = off_c; aggr = ac; nseg = NF_;
        pid = wg*4 + w;                                       // 0..23999
    } else {
        int pb = blockIdx.x - 6000;                           // 0..749 (small; no swizzle)
        y = yr; epack = epack_r; off = off_r; aggr = ar; nseg = N_;
        pid = pb*4 + w;                                       // 0..2999
    }
    int g0 = pid / nseg;           // 0..2
    int d  = pid % nseg;
    int p = off[d], e = off[d+1];
    const unsigned short* yg[8];
    #pragma unroll
    for (int k=0;k<8;++k) yg[k] = y + (size_t)(g0 + k*3)*nseg*64 + l;
    float acc[8];
    #pragma unroll
    for (int k=0;k<8;++k) acc[k] = 0.f;
    for (; p+1 < e; p += 2){
        int2v ea = epack[p], eb = epack[p+1];
        float wa = __int_as_float(ea[1]), wb = __int_as_float(eb[1]);
        size_t oa = (size_t)ea[0]*64, ob = (size_t)eb[0]*64;
        float va[8], vb[8];
        #pragma unroll
        for (int k=0;k<8;++k){ va[k] = b2f(yg[k][oa]); vb[k] = b2f(yg[k][ob]); }
        #pragma unroll
        for (int k=0;k<8;++k) acc[k] += wa*va[k] + wb*vb[k];
    }
    if (p < e){
        int2v ea = epack[p];
        float wa = __int_as_float(ea[1]);
        size_t oa = (size_t)ea[0]*64;
        #pragma unroll
        for (int k=0;k<8;++k) acc[k] += wa * b2f(yg[k][oa]);
    }
    #pragma unroll
    for (int k=0;k<8;++k)
        aggr[((size_t)(g0 + k*3)*nseg + d)*64 + l] = f2b(acc[k]);
}

// ---------------------------------------------------------------- river update: u = relu([aggr|ws] @ Wu + b)  (all bf16)
__global__ __launch_bounds__(256) void k_upd16(const unsigned short* __restrict__ aggr,
                                               const unsigned short* __restrict__ xin,
                                               const unsigned short* __restrict__ wT,  // [64 n][128 k]
                                               const float* __restrict__ bu,
                                               unsigned short* __restrict__ u){
    __shared__ unsigned short XBs[4][16*136];
    int w = threadIdx.x>>6, l = threadIdx.x&63;
    int lr = l&15, lg = l>>4;
    int lq = l>>4, lc = (l&15)*4;
    unsigned short* XB = XBs[w];
    int r0 = (blockIdx.x*4 + w)*16;
    #pragma unroll
    for (int v=0; v<4; ++v){
        int row = v*4 + lq;
        int rr = r0 + row;
        *(short4v*)&XB[row*136 + lc]      = *(const short4v*)&aggr[(size_t)rr*64 + lc];
        *(short4v*)&XB[row*136 + 64 + lc] = *(const short4v*)&xin[(size_t)rr*64 + lc];
    }
    LGKM0;
    bf16x8 a[4];
    #pragma unroll
    for (int kk=0;kk<4;++kk) a[kk] = *(const bf16x8*)&XB[lr*136 + kk*32 + lg*8];
    f32x4 acc[4];
    #pragma unroll
    for (int ct=0;ct<4;++ct) acc[ct] = (f32x4){0.f,0.f,0.f,0.f};
    #pragma unroll
    for (int ct=0;ct<4;++ct){
        #pragma unroll
        for (int kk=0;kk<4;++kk){
            bf16x8 b0 = *(const bf16x8*)&wT[(ct*16+lr)*128 + kk*32 + lg*8];
            acc[ct] = __builtin_amdgcn_mfma_f32_16x16x32_bf16(a[kk], b0, acc[ct], 0,0,0);
        }
    }
    #pragma unroll
    for (int ct=0;ct<4;++ct){
        float bv = bu[ct*16+lr];
        #pragma unroll
        for (int i=0;i<4;++i)
            u[(size_t)(r0+lg*4+i)*64 + ct*16+lr] = f2b(fmaxf(acc[ct][i] + bv, 0.f));
    }
}

// ---------------------------------------------------------------- fused causal-update + fusion MLP, 2 tiles/wave (all bf16)
__global__ __launch_bounds__(256) void k_updfus(const unsigned short* __restrict__ aggr,
                                                const unsigned short* __restrict__ xg,
                                                const unsigned short* __restrict__ wuT,  // [64][128]
                                                const float* __restrict__ bu,
                                                const unsigned short* __restrict__ wsu,
                                                const unsigned short* __restrict__ w1T,  // [64][128]
                                                const float* __restrict__ b1,
                                                const unsigned short* __restrict__ w2T,  // [64][64]
                                                const float* __restrict__ b2,
                                                unsigned short* __restrict__ fused){
    __shared__ unsigned short XBs[4][2][16*136];
    __shared__ unsigned short X2s[4][2][16*136];
    int w = threadIdx.x>>6, l = threadIdx.x&63;
    int lr = l&15, lg = l>>4;
    int lq = l>>4, lc = (l&15)*4;
    unsigned short* XB[2] = { XBs[w][0], XBs[w][1] };
    unsigned short* X2[2] = { X2s[w][0], X2s[w][1] };
    int tb = (blockIdx.x*4 + w)*32;      // 32 rows per wave, 32 | 8000 -> no g straddle
    int g  = tb/NF_;
    int n0 = (tb%NF_)/F_;                // octets: tile tt rows 0-7 -> n0+tt*2, rows 8-15 -> n0+tt*2+1
    #pragma unroll
    for (int tt=0;tt<2;++tt){
        int r0 = tb + tt*16;
        #pragma unroll
        for (int v=0; v<4; ++v){
            int row = v*4 + lq;
            int rr = r0 + row;
            *(short4v*)&XB[tt][row*136 + lc]      = *(const short4v*)&aggr[(size_t)rr*64 + lc];
            *(short4v*)&XB[tt][row*136 + 64 + lc] = *(const short4v*)&xg[(size_t)rr*64 + lc];
        }
        unsigned short wv0 = wsu[((size_t)g*N_ + n0 + tt*2    )*64 + l];
        unsigned short wv1 = wsu[((size_t)g*N_ + n0 + tt*2 + 1)*64 + l];
        #pragma unroll
        for (int i=0;i<8;++i){
            X2[tt][i*136 + 64 + l]     = wv0;
            X2[tt][(i+8)*136 + 64 + l] = wv1;
        }
    }
    LGKM0;
    // stage 1: update GEMM k=128 -> relu -> X2 cols 0..63 (both tiles)
    {
        bf16x8 a[2][4];
        #pragma unroll
        for (int tt=0;tt<2;++tt)
            #pragma unroll
            for (int kk=0;kk<4;++kk) a[tt][kk] = *(const bf16x8*)&XB[tt][lr*136 + kk*32 + lg*8];
        f32x4 acc[2][4];
        #pragma unroll
        for (int tt=0;tt<2;++tt)
            #pragma unroll
            for (int ct=0;ct<4;++ct) acc[tt][ct] = (f32x4){0.f,0.f,0.f,0.f};
        #pragma unroll
        for (int ct=0;ct<4;++ct){
            #pragma unroll
            for (int kk=0;kk<4;++kk){
                bf16x8 b0 = *(const bf16x8*)&wuT[(ct*16+lr)*128 + kk*32 + lg*8];
                #pragma unroll
                for (int tt=0;tt<2;++tt)
                    acc[tt][ct] = __builtin_amdgcn_mfma_f32_16x16x32_bf16(a[tt][kk], b0, acc[tt][ct], 0,0,0);
            }
        }
        #pragma unroll
        for (int ct=0;ct<4;++ct){
            float bv = bu[ct*16+lr];
            #pragma unroll
            for (int tt=0;tt<2;++tt)
                #pragma unroll
                for (int i=0;i<4;++i)
                    X2[tt][(lg*4+i)*136 + ct*16+lr] = f2b(fmaxf(acc[tt][ct][i] + bv, 0.f));
        }
    }
    LGKM0;
    // stage 2: fusion GEMM1 k=128 -> relu -> XB cols 0..63 (both tiles)
    {
        bf16x8 a[2][4];
        #pragma unroll
        for (int tt=0;tt<2;++tt)
            #pragma unroll
            for (int kk=0;kk<4;++kk) a[tt][kk] = *(const bf16x8*)&X2[tt][lr*136 + kk*32 + lg*8];
        f32x4 acc[2][4];
        #pragma unroll
        for (int tt=0;tt<2;++tt)
            #pragma unroll
            for (int ct=0;ct<4;++ct) acc[tt][ct] = (f32x4){0.f,0.f,0.f,0.f};
        #pragma unroll
        for (int ct=0;ct<4;++ct){
            #pragma unroll
            for (int kk=0;kk<4;++kk){
                bf16x8 b0 = *(const bf16x8*)&w1T[(ct*16+lr)*128 + kk*32 + lg*8];
                #pragma unroll
                for (int tt=0;tt<2;++tt)
                    acc[tt][ct] = __builtin_amdgcn_mfma_f32_16x16x32_bf16(a[tt][kk], b0, acc[tt][ct], 0,0,0);
            }
        }
        #pragma unroll
        for (int ct=0;ct<4;++ct){
            float bv = b1[ct*16+lr];
            #pragma unroll
            for (int tt=0;tt<2;++tt)
                #pragma unroll
                for (int i=0;i<4;++i)
                    XB[tt][(lg*4+i)*136 + ct*16+lr] = f2b(fmaxf(acc[tt][ct][i] + bv, 0.f));
        }
    }
    LGKM0;
    // stage 3: fusion GEMM2 k=64 -> fused (both tiles)
    {
        bf16x8 h0[2], h1[2];
        #pragma unroll
        for (int tt=0;tt<2;++tt){
            h0[tt] = *(const bf16x8*)&XB[tt][lr*136 + lg*8];
            h1[tt] = *(const bf16x8*)&XB[tt][lr*136 + 32 + lg*8];
        }
        f32x4 acc[2][4];
        #pragma unroll
        for (int tt=0;tt<2;++tt)
            #pragma unroll
            for (int ct=0;ct<4;++ct) acc[tt][ct] = (f32x4){0.f,0.f,0.f,0.f};
        #pragma unroll
        for (int ct=0;ct<4;++ct){
            bf16x8 b0 = *(const bf16x8*)&w2T[(ct*16+lr)*64 + lg*8];
            bf16x8 b1v= *(const bf16x8*)&w2T[(ct*16+lr)*64 + 32 + lg*8];
            #pragma unroll
            for (int tt=0;tt<2;++tt){
                acc[tt][ct] = __builtin_amdgcn_mfma_f32_16x16x32_bf16(h0[tt], b0, acc[tt][ct], 0,0,0);
                acc[tt][ct] = __builtin_amdgcn_mfma_f32_16x16x32_bf16(h1[tt], b1v, acc[tt][ct], 0,0,0);
            }
        }
        #pragma unroll
        for (int ct=0;ct<4;++ct){
            float bv = b2[ct*16+lr];
            #pragma unroll
            for (int tt=0;tt<2;++tt)
                #pragma unroll
                for (int i=0;i<4;++i)
                    fused[(size_t)(tb + tt*16 + lg*4+i)*64 + ct*16+lr] = f2b(acc[tt][ct][i] + bv);
        }
    }
}

// ---------------------------------------------------------------- MFMA temporal transformer: 4 waves, 2 seqs/wave, 12-row SC
// Vectorized staging + cvt_pk conversions (no setprio — measured neutral/negative).
#define XSTR 72    // XB stride (shorts); LN-out / V^T / O staging (16 rows)
#define SSTR 136   // SC stride (shorts): Q 0-63, K 64-127; 12 rows/seq + tail pad; aliased as HID
#define SCSZ (12*SSTR)

__global__ __launch_bounds__(256) void k_xformer(
    const unsigned short* __restrict__ fused,
    const unsigned short* __restrict__ wtq,   // [192][64], Q-part pre-scaled 0.25
    const unsigned short* __restrict__ wto,   // [64][64]
    const unsigned short* __restrict__ wt1,   // [256][64]
    const unsigned short* __restrict__ wt2,   // [64][256]
    const float* __restrict__ bqkv, const float* __restrict__ bo,
    const float* __restrict__ fb1,  const float* __restrict__ fb2,
    const float* __restrict__ ln1g, const float* __restrict__ ln1b,
    const float* __restrict__ ln2g, const float* __restrict__ ln2b,
    float* __restrict__ out)
{
    __shared__ unsigned short XBs[4][2][16*XSTR];
    __shared__ unsigned short SCmem[8*SCSZ + 544];   // 12-row slices + tail pad for benign row-12..15 reads

    int w  = threadIdx.x >> 6;
    int l  = threadIdx.x & 63;
    int lr = l & 15;
    int lg = l >> 4;

    unsigned short* XBp[2] = { XBs[w][0], XBs[w][1] };
    unsigned short* SCp[2] = { &SCmem[(w*2+0)*SCSZ], &SCmem[(w*2+1)*SCSZ] };

    int gbase = (blockIdx.x*4 + w)*2;

    // ---- stage fused rows into SC (vectorized: 3 x 128B row-loads per seq) ----
    #pragma unroll
    for (int sq=0;sq<2;++sq){
        int gs = gbase + sq;
        int bb = gs / NF_, j = gs % NF_;
        const unsigned short* fp = fused + ((size_t)bb*T_*NF_ + j)*64;
        #pragma unroll
        for (int ps=0; ps<3; ++ps){
            int t = ps*4 + lg;
            *(short4v*)&SCp[sq][t*SSTR + lr*4] = *(const short4v*)&fp[(size_t)t*NF_*64 + lr*4];
        }
    }
    LGKM0;

    // ---- read C-layout fragments from LDS ----
    float res[2][4][4];
    #pragma unroll
    for (int sq=0;sq<2;++sq)
        #pragma unroll
        for (int nt=0;nt<4;++nt)
            #pragma unroll
            for (int i=0;i<4;++i){
                int t = lg*4+i;
                res[sq][nt][i] = (t < 12) ? b2f(SCp[sq][t*SSTR + nt*16 + lr]) : 0.f;
            }

    // LN1 -> XB (both seqs), packed conversions
    #pragma unroll
    for (int sq=0;sq<2;++sq){
        float sm[4], sqr[4];
        #pragma unroll
        for (int i=0;i<4;++i){
            sm[i]  = res[sq][0][i]+res[sq][1][i]+res[sq][2][i]+res[sq][3][i];
            sqr[i] = res[sq][0][i]*res[sq][0][i]+res[sq][1][i]*res[sq][1][i]
                   + res[sq][2][i]*res[sq][2][i]+res[sq][3][i]*res[sq][3][i];
        }
        #pragma unroll
        for (int m=1;m<16;m<<=1){
            #pragma unroll
            for (int i=0;i<4;++i){
                sm[i]  += __shfl_xor(sm[i], m, 64);
                sqr[i] += __shfl_xor(sqr[i], m, 64);
            }
        }
        float mnv[4], rsv[4];
        #pragma unroll
        for (int i=0;i<4;++i){
            mnv[i] = sm[i]*(1.0f/64.0f);
            float var = sqr[i]*(1.0f/64.0f) - mnv[i]*mnv[i];
            rsv[i] = rsqrtf(var + 1e-5f);
        }
        #pragma unroll
        for (int nt=0;nt<4;++nt){
            float gg = ln1g[nt*16+lr], oo = ln1b[nt*16+lr];
            float w0 = (res[sq][nt][0]-mnv[0])*rsv[0]*gg + oo;
            float w1 = (res[sq][nt][1]-mnv[1])*rsv[1]*gg + oo;
            float w2 = (res[sq][nt][2]-mnv[2])*rsv[2]*gg + oo;
            float w3 = (res[sq][nt][3]-mnv[3])*rsv[3]*gg + oo;
            unsigned u01 = cpk(w0,w1), u23 = cpk(w2,w3);
            XBp[sq][(lg*4+0)*XSTR + nt*16 + lr] = (unsigned short)u01;
            XBp[sq][(lg*4+1)*XSTR + nt*16 + lr] = (unsigned short)(u01>>16);
            XBp[sq][(lg*4+2)*XSTR + nt*16 + lr] = (unsigned short)u23;
            XBp[sq][(lg*4+3)*XSTR + nt*16 + lr] = (unsigned short)(u23>>16);
        }
    }
    LGKM0;

    // QKV GEMM: Q,K -> SC (rows<12); V^T -> XB (shared weight frags), packed conversions
    {
        bf16x8 a0[2], a1[2];
        #pragma unroll
        for (int sq=0;sq<2;++sq){
            a0[sq] = *(const bf16x8*)&XBp[sq][lr*XSTR + 0*32 + lg*8];
            a1[sq] = *(const bf16x8*)&XBp[sq][lr*XSTR + 1*32 + lg*8];
        }
        LGKM0;   // a-frags in regs before V overwrites XB
        #pragma unroll
        for (int p=0;p<3;++p){
            f32x4 acc[2][4];
            #pragma unroll
            for (int sq=0;sq<2;++sq)
                #pragma unroll
                for (int c=0;c<4;++c) acc[sq][c] = (f32x4){0.f,0.f,0.f,0.f};
            #pragma unroll
            for (int c=0;c<4;++c){
                int ct = p*4 + c;
                bf16x8 b0 = *(const bf16x8*)&wtq[(ct*16+lr)*64 + 0*32 + lg*8];
                bf16x8 b1v= *(const bf16x8*)&wtq[(ct*16+lr)*64 + 1*32 + lg*8];
                #pragma unroll
                for (int sq=0;sq<2;++sq){
                    acc[sq][c] = __builtin_amdgcn_mfma_f32_16x16x32_bf16(a0[sq], b0, acc[sq][c], 0,0,0);
                    acc[sq][c] = __builtin_amdgcn_mfma_f32_16x16x32_bf16(a1[sq], b1v, acc[sq][c], 0,0,0);
                }
            }
            if (p < 2){
                if (lg < 3){
                    #pragma unroll
                    for (int c=0;c<4;++c){
                        int ct = p*4 + c;
                        float bv = bqkv[ct*16+lr];
                        if (p == 0) bv *= 0.25f;
                        #pragma unroll
                        for (int sq=0;sq<2;++sq){
                            unsigned u01 = cpk(acc[sq][c][0]+bv, acc[sq][c][1]+bv);
                            unsigned u23 = cpk(acc[sq][c][2]+bv, acc[sq][c][3]+bv);
                            SCp[sq][(lg*4+0)*SSTR + p*64 + c*16 + lr] = (unsigned short)u01;
                            SCp[sq][(lg*4+1)*SSTR + p*64 + c*16 + lr] = (unsigned short)(u01>>16);
                            SCp[sq][(lg*4+2)*SSTR + p*64 + c*16 + lr] = (unsigned short)u23;
                            SCp[sq][(lg*4+3)*SSTR + p*64 + c*16 + lr] = (unsigned short)(u23>>16);
                        }
                    }
                }
            } else {
                #pragma unroll
                for (int c=0;c<4;++c){
                    float bv = bqkv[128 + c*16 + lr];
                    #pragma unroll
                    for (int sq=0;sq<2;++sq){
                        uint2v vv2;
                        vv2[0] = cpk(acc[sq][c][0]+bv, acc[sq][c][1]+bv);
                        vv2[1] = cpk(acc[sq][c][2]+bv, acc[sq][c][3]+bv);
                        *(uint2v*)&XBp[sq][lr*XSTR + c*16 + lg*4] = vv2;   // VT'[d=c*16+lr][t=lg*4..+3]
                    }
                }
            }
        }
    }
    LGKM0;

    // MFMA attention per head, both seqs (packed P and O conversions)
    {
        const bf16x8 bz = (bf16x8){0,0,0,0,0,0,0,0};
        #pragma unroll
        for (int hd=0; hd<4; ++hd){
            #pragma unroll
            for (int sq=0;sq<2;++sq){
                bf16x8 ak = bz, bq = bz;
                if (lg < 2){
                    ak = *(const bf16x8*)&SCp[sq][lr*SSTR + 64 + hd*16 + lg*8];
                    bq = *(const bf16x8*)&SCp[sq][lr*SSTR +      hd*16 + lg*8];
                }
                f32x4 st = __builtin_amdgcn_mfma_f32_16x16x32_bf16(ak, bq, (f32x4){0.f,0.f,0.f,0.f}, 0,0,0);
                float s0=st[0], s1v=st[1], s2=st[2], s3=st[3];
                if (lg == 3){ s0=s1v=s2=s3=-1e30f; }
                float mx = fmaxf(fmaxf(s0,s1v), fmaxf(s2,s3));
                mx = fmaxf(mx, __shfl_xor(mx, 16, 64));
                mx = fmaxf(mx, __shfl_xor(mx, 32, 64));
                float p0 = __expf(s0-mx), p1 = __expf(s1v-mx), p2 = __expf(s2-mx), p3 = __expf(s3-mx);
                float den = p0+p1+p2+p3;
                den += __shfl_xor(den, 16, 64);
                den += __shfl_xor(den, 32, 64);
                float inv = __builtin_amdgcn_rcpf(den);
                float q0 = __shfl_down(p0, 16, 64), q1 = __shfl_down(p1, 16, 64);
                float q2 = __shfl_down(p2, 16, 64), q3 = __shfl_down(p3, 16, 64);
                union { uint4v u; bf16x8 b; } pu;
                {
                    float lo0 = (lg==0)? p0 : (lg==1)? q0 : 0.f;
                    float lo1 = (lg==0)? p1 : (lg==1)? q1 : 0.f;
                    float lo2 = (lg==0)? p2 : (lg==1)? q2 : 0.f;
                    float lo3 = (lg==0)? p3 : (lg==1)? q3 : 0.f;
                    float hi0 = (lg==0)? q0 : 0.f;
                    float hi1 = (lg==0)? q1 : 0.f;
                    float hi2 = (lg==0)? q2 : 0.f;
                    float hi3 = (lg==0)? q3 : 0.f;
                    pu.u[0] = cpk(lo0, lo1);
                    pu.u[1] = cpk(lo2, lo3);
                    pu.u[2] = cpk(hi0, hi1);
                    pu.u[3] = cpk(hi2, hi3);
                }
                bf16x8 pb = pu.b;
                bf16x8 av = bz;
                if (lg < 2) av = *(const bf16x8*)&XBp[sq][lr*XSTR + hd*16 + lg*8];
                f32x4 ot = __builtin_amdgcn_mfma_f32_16x16x32_bf16(av, pb, (f32x4){0.f,0.f,0.f,0.f}, 0,0,0);
                uint2v ow2;
                ow2[0] = cpk(ot[0]*inv, ot[1]*inv);
                ow2[1] = cpk(ot[2]*inv, ot[3]*inv);
                *(uint2v*)&XBp[sq][lr*XSTR + hd*16 + lg*4] = ow2;
            }
        }
    }
    LGKM0;

    // proj + residual -> s1 (shared weight frags)
    float s1[2][4][4];
    {
        bf16x8 a0[2], a1[2];
        #pragma unroll
        for (int sq=0;sq<2;++sq){
            a0[sq] = *(const bf16x8*)&XBp[sq][lr*XSTR + 0*32 + lg*8];
            a1[sq] = *(const bf16x8*)&XBp[sq][lr*XSTR + 1*32 + lg*8];
        }
        f32x4 pacc[2][4];
        #pragma unroll
        for (int sq=0;sq<2;++sq)
            #pragma unroll
            for (int ct=0;ct<4;++ct) pacc[sq][ct] = (f32x4){0.f,0.f,0.f,0.f};
        #pragma unroll
        for (int ct=0;ct<4;++ct){
            bf16x8 b0 = *(const bf16x8*)&wto[(ct*16+lr)*64 + 0*32 + lg*8];
            bf16x8 b1v= *(const bf16x8*)&wto[(ct*16+lr)*64 + 1*32 + lg*8];
            #pragma unroll
            for (int sq=0;sq<2;++sq){
                pacc[sq][ct] = __builtin_amdgcn_mfma_f32_16x16x32_bf16(a0[sq], b0, pacc[sq][ct], 0,0,0);
                pacc[sq][ct] = __builtin_amdgcn_mfma_f32_16x16x32_bf16(a1[sq], b1v, pacc[sq][ct], 0,0,0);
            }
        }
        #pragma unroll
        for (int sq=0;sq<2;++sq)
            #pragma unroll
            for (int ct=0;ct<4;++ct){
                float bv = bo[ct*16+lr];
                #pragma unroll
                for (int i=0;i<4;++i)
                    s1[sq][ct][i] = res[sq][ct][i] + pacc[sq][ct][i] + bv;
            }
    }

    // LN2 -> XB (both seqs), packed conversions
    #pragma unroll
    for (int sq=0;sq<2;++sq){
        float sm[4], sqr[4];
        #pragma unroll
        for (int i=0;i<4;++i){
            sm[i]  = s1[sq][0][i]+s1[sq][1][i]+s1[sq][2][i]+s1[sq][3][i];
            sqr[i] = s1[sq][0][i]*s1[sq][0][i]+s1[sq][1][i]*s1[sq][1][i]
                   + s1[sq][2][i]*s1[sq][2][i]+s1[sq][3][i]*s1[sq][3][i];
        }
        #pragma unroll
        for (int m=1;m<16;m<<=1){
            #pragma unroll
            for (int i=0;i<4;++i){
                sm[i]  += __shfl_xor(sm[i], m, 64);
                sqr[i] += __shfl_xor(sqr[i], m, 64);
            }
        }
        float mnv[4], rsv[4];
        #pragma unroll
        for (int i=0;i<4;++i){
            mnv[i] = sm[i]*(1.0f/64.0f);
            float var = sqr[i]*(1.0f/64.0f) - mnv[i]*mnv[i];
            rsv[i] = rsqrtf(var + 1e-5f);
        }
        #pragma unroll
        for (int nt=0;nt<4;++nt){
            float gg = ln2g[nt*16+lr], oo = ln2b[nt*16+lr];
            float w0 = (s1[sq][nt][0]-mnv[0])*rsv[0]*gg + oo;
            float w1 = (s1[sq][nt][1]-mnv[1])*rsv[1]*gg + oo;
            float w2 = (s1[sq][nt][2]-mnv[2])*rsv[2]*gg + oo;
            float w3 = (s1[sq][nt][3]-mnv[3])*rsv[3]*gg + oo;
            unsigned u01 = cpk(w0,w1), u23 = cpk(w2,w3);
            XBp[sq][(lg*4+0)*XSTR + nt*16 + lr] = (unsigned short)u01;
            XBp[sq][(lg*4+1)*XSTR + nt*16 + lr] = (unsigned short)(u01>>16);
            XBp[sq][(lg*4+2)*XSTR + nt*16 + lr] = (unsigned short)u23;
            XBp[sq][(lg*4+3)*XSTR + nt*16 + lr] = (unsigned short)(u23>>16);
        }
    }
    LGKM0;

    // FFN: two 128-wide halves; HID stores guarded rows<12; packed conversions
    f32x4 oacc[2][4];
    #pragma unroll
    for (int sq=0;sq<2;++sq)
        #pragma unroll
        for (int ct=0;ct<4;++ct) oacc[sq][ct] = (f32x4){0.f,0.f,0.f,0.f};
    {
        bf16x8 a0[2], a1[2];
        #pragma unroll
        for (int sq=0;sq<2;++sq){
            a0[sq] = *(const bf16x8*)&XBp[sq][lr*XSTR + 0*32 + lg*8];
            a1[sq] = *(const bf16x8*)&XBp[sq][lr*XSTR + 1*32 + lg*8];
        }
        #pragma unroll
        for (int half=0; half<2; ++half){
            LGKM0;   // HID region reuse guard
            #pragma unroll
            for (int q=0; q<2; ++q){
                f32x4 facc[2][4];
                #pragma unroll
                for (int sq=0;sq<2;++sq)
                    #pragma unroll
                    for (int c=0;c<4;++c) facc[sq][c] = (f32x4){0.f,0.f,0.f,0.f};
                #pragma unroll
                for (int c=0;c<4;++c){
                    int ct = half*8 + q*4 + c;
                    bf16x8 b0 = *(const bf16x8*)&wt1[(ct*16+lr)*64 + 0*32 + lg*8];
                    bf16x8 b1v= *(const bf16x8*)&wt1[(ct*16+lr)*64 + 1*32 + lg*8];
                    #pragma unroll
                    for (int sq=0;sq<2;++sq){
                        facc[sq][c] = __builtin_amdgcn_mfma_f32_16x16x32_bf16(a0[sq], b0, facc[sq][c], 0,0,0);
                        facc[sq][c] = __builtin_amdgcn_mfma_f32_16x16x32_bf16(a1[sq], b1v, facc[sq][c], 0,0,0);
                    }
                }
                if (lg < 3){
                    #pragma unroll
                    for (int c=0;c<4;++c){
                        int ct = half*8 + q*4 + c;
                        float bv = fb1[ct*16+lr];
                        #pragma unroll
                        for (int sq=0;sq<2;++sq){
                            float hv[4];
                            #pragma unroll
                            for (int i=0;i<4;++i){
                                float xv = facc[sq][c][i] + bv;
                                float x2 = xv*xv;
                                float z  = xv*(1.5957691216f + 0.0713548162f*x2);
                                float ez = __expf(-z);
                                hv[i] = xv * __builtin_amdgcn_rcpf(1.0f + ez);
                            }
                            unsigned u01 = cpk(hv[0],hv[1]), u23 = cpk(hv[2],hv[3]);
                            SCp[sq][(lg*4+0)*SSTR + (q*4+c)*16 + lr] = (unsigned short)u01;
                            SCp[sq][(lg*4+1)*SSTR + (q*4+c)*16 + lr] = (unsigned short)(u01>>16);
                            SCp[sq][(lg*4+2)*SSTR + (q*4+c)*16 + lr] = (unsigned short)u23;
                            SCp[sq][(lg*4+3)*SSTR + (q*4+c)*16 + lr] = (unsigned short)(u23>>16);
                        }
                    }
                }
            }
            LGKM0;
            #pragma unroll
            for (int ks=0;ks<4;++ks){
                bf16x8 af[2];
                #pragma unroll
                for (int sq=0;sq<2;++sq)
                    af[sq] = *(const bf16x8*)&SCp[sq][lr*SSTR + ks*32 + lg*8];
                #pragma unroll
                for (int ct=0;ct<4;++ct){
                    bf16x8 bfr = *(const bf16x8*)&wt2[(ct*16+lr)*256 + half*128 + ks*32 + lg*8];
                    #pragma unroll
                    for (int sq=0;sq<2;++sq)
                        oacc[sq][ct] = __builtin_amdgcn_mfma_f32_16x16x32_bf16(af[sq], bfr, oacc[sq][ct], 0,0,0);
                }
            }
        }
    }

    // residual + mean over t (both seqs)
    #pragma unroll
    for (int sq=0;sq<2;++sq)
        #pragma unroll
        for (int ct=0;ct<4;++ct){
            float bv = fb2[ct*16+lr];
            float part = 0.f;
            #pragma unroll
            for (int i=0;i<4;++i){
                if (lg*4+i < 12) part += s1[sq][ct][i] + oacc[sq][ct][i] + bv;
            }
            part += __shfl_xor(part, 16, 64);
            part += __shfl_xor(part, 32, 64);
            if (lg == 0) out[(size_t)(gbase+sq)*64 + ct*16 + lr] = part*(1.0f/12.0f);
        }
}

// ----------------------------------------------------------------
extern "C" void kernel_launch(void* const* d_in, const int* in_sizes, int n_in,
                              void* d_out, int out_size, void* d_ws, size_t ws_size,
                              hipStream_t stream) {
    const float* x      = (const float*)d_in[0];
    const int*   r_ei   = (const int*)  d_in[1];
    const float* r_ea   = (const float*)d_in[2];
    const int*   c_ei   = (const int*)  d_in[3];
    const float* c_ew   = (const float*)d_in[4];
    const float* rvWlin = (const float*)d_in[5];
    const float* rvblin = (const float*)d_in[6];
    const float* rvWupd = (const float*)d_in[7];
    const float* rvbupd = (const float*)d_in[8];
    const float* rvgate = (const float*)d_in[9];
    const float* rvlw   = (const float*)d_in[10];
    const float* csWlin = (const float*)d_in[11];
    const float* csblin = (const float*)d_in[12];
    const float* csWupd = (const float*)d_in[13];
    const float* csbupd = (const float*)d_in[14];
    const float* csgate = (const float*)d_in[15];
    const float* cslw   = (const float*)d_in[16];
    const float* fuW1   = (const float*)d_in[17];
    const float* fub1   = (const float*)d_in[18];
    const float* fuW2   = (const float*)d_in[19];
    const float* fub2   = (const float*)d_in[20];
    const float* ln1g   = (const float*)d_in[21];
    const float* ln1b   = (const float*)d_in[22];
    const float* ln2g   = (const float*)d_in[23];
    const float* ln2b   = (const float*)d_in[24];
    const float* Wqkv   = (const float*)d_in[25];
    const float* bqkv   = (const float*)d_in[26];
    const float* Wo     = (const float*)d_in[27];
    const float* bo     = (const float*)d_in[28];
    const float* ffW1   = (const float*)d_in[29];
    const float* ffb1   = (const float*)d_in[30];
    const float* ffW2   = (const float*)d_in[31];
    const float* ffb2   = (const float*)d_in[32];

    float* wsp  = (float*)d_ws;
    unsigned short* FNY_b = (unsigned short*)wsp;                    // causal y bf16, then FUSED bf16
    unsigned short* FNA_b = (unsigned short*)(wsp + 12288000);       // causal aggr bf16
    unsigned short* XG_b  = (unsigned short*)(wsp + 12288000 + 6144000); // gathered x bf16
    unsigned short* WS_b  = (unsigned short*)(wsp + 24576000);       // watershed mean bf16
    unsigned short* WSY_b = (unsigned short*)(wsp + 26112000);       // river y bf16
    unsigned short* WSA_b = (unsigned short*)(wsp + 27648000);       // river aggr bf16
    float* WSU  = wsp + 29184000;                                    // CSR scratch, then river u bf16
    unsigned short* WSU_b = (unsigned short*)WSU;
    unsigned short* wt = (unsigned short*)(wsp + 30720000);
    float* outp = (float*)d_out;

    int* ibase  = (int*)WSU;
    int* cnt_c  = ibase;
    int* cnt_r  = ibase + 8000;
    int* off_c  = ibase + 9000;
    int* off_r  = ibase + 17001;
    int* cur_c  = ibase + 18002;
    int* cur_r  = ibase + 26002;
    float* mw_c = (float*)(ibase + 53002);
    float* mw_r = (float*)(ibase + 77002);
    int2v* epack_c = (int2v*)(ibase + 80000);   // 24000 x 8B
    int2v* epack_r = (int2v*)(ibase + 128000);  //  2000 x 8B (clobbered later by river u -> OK, consumers done)

    const int* c_src = c_ei;
    const int* c_dst = c_ei + EC_;
    const int* r_src = r_ei;
    const int* r_dst = r_ei + ER_;

    hipMemsetAsync(cnt_c, 0, 9000*sizeof(int), stream);

    // merged: mw+histogram (102 blocks) + bf16 weight panels (336 blocks)
    k_prephist<<<438, 256, 0, stream>>>(c_dst, r_dst, c_ew, cslw, csgate,
                                        r_ea, rvlw, rvgate, mw_c, mw_r, cnt_c, cnt_r,
                                        Wqkv, Wo, ffW1, ffW2, csWlin, rvWlin, csWupd, rvWupd,
                                        fuW1, fuW2, wt);
    k_scan<<<2, 256, 0, stream>>>(cnt_c, off_c, cur_c, cnt_r, off_r, cur_r);

    // merged: CSR fill (102 blocks) + node linear (3000 blocks)
    k_filllin<<<3102, 256, 0, stream>>>(c_src, c_dst, r_src, r_dst, mw_c, mw_r,
                                        cur_c, cur_r, epack_c, epack_r,
                                        x, wt+49152, csblin, wt+53248, rvblin,
                                        FNY_b, WSY_b, XG_b, WS_b);

    // merged gather-aggregation (8-way cross-graph pairing: shared epack, 16 gathers in flight)
    k_gaggr8<<<6750, 256, 0, stream>>>(FNY_b, epack_c, off_c, FNA_b,
                                       WSY_b, epack_r, off_r, WSA_b);

    // river update (clobbers CSR scratch -> OK, consumers done)
    k_upd16<<<375, 256, 0, stream>>>(WSA_b, WS_b, wt+65536, rvbupd, WSU_b);

    // fused causal update + fusion MLP, 2 tiles/wave -> FUSED bf16 (into FNY region)
    k_updfus<<<1500, 256, 0, stream>>>(FNA_b, XG_b, wt+57344, csbupd, WSU_b,
                                       wt+73728, fub1, wt+81920, fub2, FNY_b);

    // 2-seq-per-wave MFMA transformer (cvt_pk, no setprio)
    k_xformer<<<2000, 256, 0, stream>>>(FNY_b,
                                        wt, wt+12288, wt+16384, wt+32768,
                                        bqkv, bo, ffb1, ffb2,
                                        ln1g, ln1b, ln2g, ln2b,
                                        outp);
}